// Round 4
// baseline (1163.603 us; speedup 1.0000x reference)
//
#include <hip/hip_runtime.h>
#include <math.h>
#include <float.h>

#define T_SEQ  2048
#define DMODEL 512
#define NHEAD  8
#define DHEAD  64
#define FDIM   2048
#define NLAYER 4
#define NB     2
#define MROWS  (NB*T_SEQ)   // 4096

typedef _Float16 f16x8 __attribute__((ext_vector_type(8)));
typedef float    f32x4 __attribute__((ext_vector_type(4)));

// async 16B global -> LDS (wave-uniform LDS base, lane x 16B dest)
__device__ __forceinline__ void async16(const _Float16* g, _Float16* l) {
    __builtin_amdgcn_global_load_lds(
        (const __attribute__((address_space(1))) unsigned int*)g,
        (__attribute__((address_space(3))) unsigned int*)l, 16, 0, 0);
}

// ---------------------------------------------------------------------------
// fp32 vector GEMM — embedding only (K=128)
// ---------------------------------------------------------------------------
template<int BN, int EPI>
__global__ __launch_bounds__(256) void gemm_k(
    const float* __restrict__ A, const float* __restrict__ W,
    const float* __restrict__ bias, const float* __restrict__ pos,
    float* __restrict__ C, int M, int N, int K)
{
    constexpr int BM = 128;
    constexpr int BK = 32;
    constexpr int MN = BN / 16;
    __shared__ float As[BK][BM + 4];
    __shared__ float Ws[BK][BN + 4];
    const int tid = threadIdx.x;
    const int n0 = blockIdx.x * BN;
    const int m0 = blockIdx.y * BM;
    const int tx = tid & 15;
    const int ty = tid >> 4;

    float acc[8][MN];
    #pragma unroll
    for (int i = 0; i < 8; ++i)
        #pragma unroll
        for (int j = 0; j < MN; ++j) acc[i][j] = 0.f;

    for (int k0 = 0; k0 < K; k0 += BK) {
        #pragma unroll
        for (int it = 0; it < 4; ++it) {
            int qq = tid + 256 * it;
            int m = qq >> 3, kq = qq & 7;
            float4 v4 = *(const float4*)(A + (size_t)(m0 + m) * K + k0 + kq * 4);
            As[kq*4+0][m] = v4.x; As[kq*4+1][m] = v4.y;
            As[kq*4+2][m] = v4.z; As[kq*4+3][m] = v4.w;
        }
        #pragma unroll
        for (int it = 0; it < BN/32; ++it) {
            int qq = tid + 256 * it;
            int n = qq >> 3, kq = qq & 7;
            float4 v4 = *(const float4*)(W + (size_t)(n0 + n) * K + k0 + kq * 4);
            Ws[kq*4+0][n] = v4.x; Ws[kq*4+1][n] = v4.y;
            Ws[kq*4+2][n] = v4.z; Ws[kq*4+3][n] = v4.w;
        }
        __syncthreads();
        for (int kk = 0; kk < BK; ++kk) {
            float a[8], b[MN];
            float4 a0 = *(const float4*)&As[kk][ty*8];
            float4 a1 = *(const float4*)&As[kk][ty*8+4];
            a[0]=a0.x; a[1]=a0.y; a[2]=a0.z; a[3]=a0.w;
            a[4]=a1.x; a[5]=a1.y; a[6]=a1.z; a[7]=a1.w;
            float4 b0 = *(const float4*)&Ws[kk][tx*4];
            b[0]=b0.x; b[1]=b0.y; b[2]=b0.z; b[3]=b0.w;
            if constexpr (MN == 8) {
                float4 b1 = *(const float4*)&Ws[kk][64 + tx*4];
                b[4]=b1.x; b[5]=b1.y; b[6]=b1.z; b[7]=b1.w;
            }
            #pragma unroll
            for (int i = 0; i < 8; ++i)
                #pragma unroll
                for (int j = 0; j < MN; ++j)
                    acc[i][j] = fmaf(a[i], b[j], acc[i][j]);
        }
        __syncthreads();
    }

    #pragma unroll
    for (int i = 0; i < 8; ++i) {
        int m = m0 + ty*8 + i;
        #pragma unroll
        for (int jb = 0; jb < MN/4; ++jb) {
            int nn = n0 + jb*64 + tx*4;
            float4 r;
            r.x = acc[i][jb*4+0] + bias[nn+0];
            r.y = acc[i][jb*4+1] + bias[nn+1];
            r.z = acc[i][jb*4+2] + bias[nn+2];
            r.w = acc[i][jb*4+3] + bias[nn+3];
            if constexpr (EPI == 1) {
                const float* pp = pos + (size_t)(m & (T_SEQ-1)) * DMODEL + nn;
                r.x += pp[0]; r.y += pp[1]; r.z += pp[2]; r.w += pp[3];
            }
            *(float4*)(C + (size_t)m * N + nn) = r;
        }
    }
}

// ---------------------------------------------------------------------------
// f16-split MFMA GEMM: C = (1/1024)·A'[M,K]·W'[N,K]^T + bias
// (reg-staged LDS: 64B-granule coalesced global loads -> ds_write)
// BM: 128 (4 m-frags/wave) or 64 (2 m-frags/wave)
// BM==64 -> __launch_bounds__(256,3): LDS 24.6KB allows 3 blocks/CU; makes
// QKV's 768 blocks exactly one round (256x3) and adds overlap for the
// 256-block N=512 GEMMs. BM==128 keeps (256,2): 512 blocks = one round.
// ASRC: 0 = dual-plane A; 1 = single-plane A (exact spikes)
// EPI:  0 = fp32; 2 = spike->fp32; 3 = spike->f16 plane (x16)
// LAYOUT: 0 = [M,N]; 2 = fused QKV (q,k f16 planes head layout; v fp32)
// ---------------------------------------------------------------------------
template<int BM, int ASRC, int EPI, int LAYOUT>
__global__ __launch_bounds__(256, (BM == 64) ? 3 : 2) void mgemm_k(
    const _Float16* __restrict__ AH, const _Float16* __restrict__ AL,
    const _Float16* __restrict__ WH, const _Float16* __restrict__ WL,
    const float* __restrict__ bias,
    float* __restrict__ O0, float* __restrict__ O1, float* __restrict__ O2,
    float* __restrict__ O3, float* __restrict__ O4,
    int M, int N, int K)
{
    constexpr int MI = BM / 32;
    __shared__ _Float16 AsH[4][BM][8];
    __shared__ _Float16 AsL[4][BM][8];
    __shared__ _Float16 WsH[4][128][8];
    __shared__ _Float16 WsL[4][128][8];

    const int tid = threadIdx.x;
    const int n0 = blockIdx.x * 128;
    const int m0 = blockIdx.y * BM;
    const int wv = tid >> 6, lane = tid & 63;
    const int mw = (wv >> 1) * (BM/2), nw = (wv & 1) * 64;
    const int fr = lane & 15;
    const int kb = lane >> 4;

    const int wsrow = tid >> 1;
    const int wskb  = (tid & 1) * 2;
    const int wkoff = (tid & 1) * 16;

    f32x4 acc[MI][4];
    #pragma unroll
    for (int i = 0; i < MI; ++i)
        #pragma unroll
        for (int j = 0; j < 4; ++j) acc[i][j] = (f32x4)(0.f);

    for (int k0 = 0; k0 < K; k0 += 32) {
        if constexpr (BM == 128) {
            const _Float16* ap = AH + (size_t)(m0 + wsrow) * K + k0 + wkoff;
            *(f16x8*)&AsH[wskb  ][wsrow][0] = *(const f16x8*)ap;
            *(f16x8*)&AsH[wskb+1][wsrow][0] = *(const f16x8*)(ap + 8);
            if constexpr (ASRC == 0) {
                const _Float16* alp = AL + (size_t)(m0 + wsrow) * K + k0 + wkoff;
                *(f16x8*)&AsL[wskb  ][wsrow][0] = *(const f16x8*)alp;
                *(f16x8*)&AsL[wskb+1][wsrow][0] = *(const f16x8*)(alp + 8);
            }
        } else {
            const int arow = tid >> 2, akb = tid & 3;
            *(f16x8*)&AsH[akb][arow][0] =
                *(const f16x8*)(AH + (size_t)(m0 + arow) * K + k0 + akb*8);
            if constexpr (ASRC == 0)
                *(f16x8*)&AsL[akb][arow][0] =
                    *(const f16x8*)(AL + (size_t)(m0 + arow) * K + k0 + akb*8);
        }
        {
            const _Float16* wp = WH + (size_t)(n0 + wsrow) * K + k0 + wkoff;
            *(f16x8*)&WsH[wskb  ][wsrow][0] = *(const f16x8*)wp;
            *(f16x8*)&WsH[wskb+1][wsrow][0] = *(const f16x8*)(wp + 8);
            const _Float16* wlp = WL + (size_t)(n0 + wsrow) * K + k0 + wkoff;
            *(f16x8*)&WsL[wskb  ][wsrow][0] = *(const f16x8*)wlp;
            *(f16x8*)&WsL[wskb+1][wsrow][0] = *(const f16x8*)(wlp + 8);
        }
        __syncthreads();

        f16x8 aH[MI], aL[MI], bH[4], bL[4];
        #pragma unroll
        for (int i = 0; i < MI; ++i) {
            aH[i] = *(const f16x8*)&AsH[kb][mw + i*16 + fr][0];
            if constexpr (ASRC == 0) aL[i] = *(const f16x8*)&AsL[kb][mw + i*16 + fr][0];
        }
        #pragma unroll
        for (int j = 0; j < 4; ++j) {
            bH[j] = *(const f16x8*)&WsH[kb][nw + j*16 + fr][0];
            bL[j] = *(const f16x8*)&WsL[kb][nw + j*16 + fr][0];
        }
        #pragma unroll
        for (int i = 0; i < MI; ++i)
            #pragma unroll
            for (int j = 0; j < 4; ++j) {
                acc[i][j] = __builtin_amdgcn_mfma_f32_16x16x32_f16(aH[i], bH[j], acc[i][j], 0, 0, 0);
                acc[i][j] = __builtin_amdgcn_mfma_f32_16x16x32_f16(aH[i], bL[j], acc[i][j], 0, 0, 0);
                if constexpr (ASRC == 0)
                    acc[i][j] = __builtin_amdgcn_mfma_f32_16x16x32_f16(aL[i], bH[j], acc[i][j], 0, 0, 0);
            }
        __syncthreads();
    }

    const int qq = lane >> 4;
    #pragma unroll
    for (int j = 0; j < 4; ++j) {
        int n = n0 + nw + j*16 + fr;
        float bv = bias[n];
        #pragma unroll
        for (int i = 0; i < MI; ++i) {
            #pragma unroll
            for (int r = 0; r < 4; ++r) {
                int m = m0 + mw + i*16 + qq*4 + r;
                float val = acc[i][j][r] * (1.f/1024.f) + bv;
                if constexpr (EPI == 2) val = val > 0.5f ? 1.f : 0.f;
                if constexpr (EPI == 3) {
                    ((_Float16*)O0)[(size_t)m * N + n] = (val > 0.5f) ? (_Float16)16.f : (_Float16)0.f;
                } else if constexpr (LAYOUT == 0) {
                    O0[(size_t)m * N + n] = val;
                } else {
                    int b_ = m >> 11, t_ = m & (T_SEQ-1);
                    if (n < 512) {
                        size_t hl = (((size_t)(b_*NHEAD + (n>>6))*T_SEQ + t_) << 6) + (n & 63);
                        float s16 = 16.f * val;
                        _Float16 hh = (_Float16)s16;
                        ((_Float16*)O0)[hl] = hh;
                        ((_Float16*)O1)[hl] = (_Float16)(s16 - (float)hh);
                    } else if (n < 1024) {
                        int nn = n - 512;
                        size_t hl = (((size_t)(b_*NHEAD + (nn>>6))*T_SEQ + t_) << 6) + (nn & 63);
                        float s16 = 16.f * val;
                        _Float16 hh = (_Float16)s16;
                        ((_Float16*)O2)[hl] = hh;
                        ((_Float16*)O3)[hl] = (_Float16)(s16 - (float)hh);
                    } else {
                        int nn = n - 1024;
                        O4[(((size_t)(b_*NHEAD + (nn>>6))*T_SEQ + t_) << 6) + (nn & 63)] = val;
                    }
                }
            }
        }
    }
}

// ---------------------------------------------------------------------------
// h-split (embedding output -> x16 planes)
// ---------------------------------------------------------------------------
__global__ __launch_bounds__(256) void cvtw_k(
    const float* __restrict__ w, _Float16* __restrict__ H, _Float16* __restrict__ L,
    int n, float scale)
{
    int i = blockIdx.x * 256 + threadIdx.x;
    if (i < n) {
        float s = scale * w[i];
        _Float16 h = (_Float16)s;
        H[i] = h;
        L[i] = (_Float16)(s - (float)h);
    }
}

// all of one layer's weight conversions fused (x64 split), one launch
__global__ __launch_bounds__(256) void cvtlayer_k(
    const float* __restrict__ wq, const float* __restrict__ wk, const float* __restrict__ wv,
    const float* __restrict__ bq, const float* __restrict__ bk, const float* __restrict__ bv,
    const float* __restrict__ wo, const float* __restrict__ f1w, const float* __restrict__ f2w,
    _Float16* __restrict__ WcatH, _Float16* __restrict__ WcatL, float* __restrict__ bcat,
    _Float16* __restrict__ WoH, _Float16* __restrict__ WoL,
    _Float16* __restrict__ W1H, _Float16* __restrict__ W1L,
    _Float16* __restrict__ W2H, _Float16* __restrict__ W2L)
{
    int i = blockIdx.x * 256 + threadIdx.x;
    float w;
    _Float16 *H, *L;
    int off;
    if (i < 786432) {
        int src = i >> 18, o = i & 262143;
        w = (src == 0 ? wq : (src == 1 ? wk : wv))[o];
        H = WcatH; L = WcatL; off = i;
    } else if (i < 1048576) {
        off = i - 786432;  w = wo[off];  H = WoH; L = WoL;
    } else if (i < 2097152) {
        off = i - 1048576; w = f1w[off]; H = W1H; L = W1L;
    } else if (i < 3145728) {
        off = i - 2097152; w = f2w[off]; H = W2H; L = W2L;
    } else if (i < 3145728 + 1536) {
        int j = i - 3145728;
        int src = j >> 9, o = j & 511;
        bcat[j] = (src == 0 ? bq : (src == 1 ? bk : bv))[o];
        return;
    } else return;
    float s = 64.f * w;
    _Float16 h = (_Float16)s;
    H[off] = h;
    L[off] = (_Float16)(s - (float)h);
}

// ---------------------------------------------------------------------------
// Fused sparse attention v8 — v7 (512 thr / 64 q-rows, 512 blocks = 2/CU
// exactly) + ss pad restored to [64][132] (v7's [64][128] made row stride
// = 0 mod 32 banks -> conflicts rose 2.1M->3.15M) + sort-16 CE rewritten
// as explicit min/max (was cmp+2 cndmask through shared bool, vcc-chained).
// LDS: ks 32KB + ss[64][132] 33792B = 66560 -> 2 blocks/CU (133KB < 160KB).
// ---------------------------------------------------------------------------
__global__ __launch_bounds__(512, 4) void attn_k(
    const _Float16* __restrict__ qH, const _Float16* __restrict__ qL,
    const _Float16* __restrict__ kH, const _Float16* __restrict__ kL,
    const float* __restrict__ v,
    _Float16* __restrict__ outH, _Float16* __restrict__ outL)
{
    // ksH [128*64] @0 (16384) | ksL @16384 | ss[64][132] f32 @32768 (33792)
    // -> total 66560; wrow/irow alias ss
    __shared__ unsigned char lds[66560];
    _Float16* ksH = (_Float16*)(lds);
    _Float16* ksL = (_Float16*)(lds + 16384);
    float    (*ss)[132] = (float(*)[132])(lds + 32768);
    float*   wrow       = (float*)(lds + 32768);
    int*     irow       = (int*)(lds + 32768 + 8448);

    const int tid = threadIdx.x;
    const int bh  = blockIdx.y;
    const int t0  = blockIdx.x * 64;
    const _Float16* qHb = qH + ((size_t)bh * T_SEQ + t0) * DHEAD;
    const _Float16* qLb = qL + ((size_t)bh * T_SEQ + t0) * DHEAD;
    const _Float16* kHb = kH + (size_t)bh * T_SEQ * DHEAD;
    const _Float16* kLb = kL + (size_t)bh * T_SEQ * DHEAD;
    const float*    vb  = v  + (size_t)bh * T_SEQ * DHEAD;

    unsigned kreg[32];
    #pragma unroll
    for (int i = 0; i < 32; ++i) kreg[i] = 0u;

    const int wv = tid >> 6, lane = tid & 63;
    const int fr = lane & 15, q4 = lane >> 4;
    const int mh  = (wv >> 2) * 32;      // q-row half owned by this wave
    const int c0w = (wv & 3) * 32;       // col strip owned by this wave
    const int srow = tid >> 3;           // 0..63
    const int ssub = tid & 7;

    // Q fragments in registers: loop-invariant across all K tiles.
    // [ks][mi]: row = mh + mi*16 + fr; doff = ks*32 + q4*8
    f16x8 qaH[2][2], qaL[2][2];
    #pragma unroll
    for (int ks = 0; ks < 2; ++ks) {
        const int doff = ks*32 + q4*8;
        qaH[ks][0] = *(const f16x8*)(qHb + (mh + fr)*DHEAD + doff);
        qaH[ks][1] = *(const f16x8*)(qHb + (mh + 16 + fr)*DHEAD + doff);
        qaL[ks][0] = *(const f16x8*)(qLb + (mh + fr)*DHEAD + doff);
        qaL[ks][1] = *(const f16x8*)(qLb + (mh + 16 + fr)*DHEAD + doff);
    }

    // async stage of one K tile: 8 waves x 16 rows -> 2 instrs/plane/wave
    auto stage = [&](int jt) {
        const int j0 = jt * 128;
        #pragma unroll
        for (int i = 0; i < 2; ++i) {
            const int r0 = wv*16 + i*8;                 // wave-uniform
            const int cc = r0 + (lane >> 3);
            const int ch = (lane & 7) ^ (cc & 7);       // swizzled source chunk
            const size_t goff = (size_t)(j0 + cc) * DHEAD + ch*8;
            async16(kHb + goff, ksH + r0*64);
            async16(kLb + goff, ksL + r0*64);
        }
    };

    stage(0);
    __syncthreads();                     // ks(0) ready (drains vmcnt)

    for (int jt = 0; jt < 16; ++jt) {
        const int j0 = jt * 128;

        // QK^T: 2 m-frags x 2 n-frags x 2 k-steps x 3 split passes
        f32x4 acc[2][2];
        acc[0][0] = (f32x4)(0.f); acc[0][1] = (f32x4)(0.f);
        acc[1][0] = (f32x4)(0.f); acc[1][1] = (f32x4)(0.f);
        #pragma unroll
        for (int ks = 0; ks < 2; ++ks) {
            const int chq  = ks*4 + q4;                 // chunk index of doff
            #pragma unroll
            for (int nj = 0; nj < 2; ++nj) {
                const int cc = c0w + nj*16 + fr;
                const int sl = cc*64 + (chq ^ (cc & 7))*8;
                f16x8 bHf = *(const f16x8*)&ksH[sl];
                f16x8 bLf = *(const f16x8*)&ksL[sl];
                acc[0][nj] = __builtin_amdgcn_mfma_f32_16x16x32_f16(qaH[ks][0], bHf, acc[0][nj], 0, 0, 0);
                acc[0][nj] = __builtin_amdgcn_mfma_f32_16x16x32_f16(qaH[ks][0], bLf, acc[0][nj], 0, 0, 0);
                acc[0][nj] = __builtin_amdgcn_mfma_f32_16x16x32_f16(qaL[ks][0], bHf, acc[0][nj], 0, 0, 0);
                acc[1][nj] = __builtin_amdgcn_mfma_f32_16x16x32_f16(qaH[ks][1], bHf, acc[1][nj], 0, 0, 0);
                acc[1][nj] = __builtin_amdgcn_mfma_f32_16x16x32_f16(qaH[ks][1], bLf, acc[1][nj], 0, 0, 0);
                acc[1][nj] = __builtin_amdgcn_mfma_f32_16x16x32_f16(qaL[ks][1], bHf, acc[1][nj], 0, 0, 0);
            }
        }
        // scores to LDS (row = mh + mi*16 + q4*4 + r, col = c0w + nj*16 + fr)
        #pragma unroll
        for (int mi = 0; mi < 2; ++mi)
            #pragma unroll
            for (int nj = 0; nj < 2; ++nj)
                #pragma unroll
                for (int r = 0; r < 4; ++r)
                    ss[mh + mi*16 + q4*4 + r][c0w + nj*16 + fr] = acc[mi][nj][r] * (1.f/2048.f);
        __syncthreads();                 // C: ss visible; all ks reads done

        if (jt < 15) stage(jt + 1);      // async; hides under select

        // branch-free select: 16 candidates / thread, u32 packed keys
        float4 c4[4];
        {
            const float* ssr = &ss[srow][0] + ssub*4;
            #pragma unroll
            for (int g = 0; g < 4; ++g) c4[g] = *(const float4*)(ssr + g*32);
        }
        unsigned cand[16];
        #pragma unroll
        for (int g = 0; g < 4; ++g) {
            float vg[4] = {c4[g].x, c4[g].y, c4[g].z, c4[g].w};
            #pragma unroll
            for (int r = 0; r < 4; ++r) {
                unsigned u = __float_as_uint(vg[r]);
                u ^= (unsigned)((int)u >> 31) | 0x80000000u;
                int col = ssub*4 + g*32 + r;
                cand[g*4+r] = (u & 0xFFFFF800u) | (unsigned)(2047 - (j0 + col));
            }
        }
        // bitonic sort-16 descending; CE as explicit min/max (v_min/max_u32)
        #pragma unroll
        for (int k2 = 2; k2 <= 16; k2 <<= 1) {
            #pragma unroll
            for (int j2 = k2 >> 1; j2 > 0; j2 >>= 1) {
                #pragma unroll
                for (int i2 = 0; i2 < 16; ++i2) {
                    int l2 = i2 ^ j2;
                    if (l2 > i2) {
                        unsigned a = cand[i2], b = cand[l2];
                        unsigned mn = a < b ? a : b;
                        unsigned mx = a < b ? b : a;
                        if ((i2 & k2) == 0) { cand[i2] = mx; cand[l2] = mn; }
                        else                { cand[i2] = mn; cand[l2] = mx; }
                    }
                }
            }
        }
        #pragma unroll
        for (int j2 = 0; j2 < 16; ++j2) {
            unsigned b = cand[15 - j2];
            if (kreg[16 + j2] < b) kreg[16 + j2] = b;
        }
        #pragma unroll
        for (int st = 16; st >= 1; st >>= 1) {
            #pragma unroll
            for (int i2 = 0; i2 < 32; ++i2) {
                if ((i2 & st) == 0) {
                    unsigned lo = kreg[i2], hi = kreg[i2 | st];
                    kreg[i2]      = lo < hi ? hi : lo;
                    kreg[i2 | st] = lo < hi ? lo : hi;
                }
            }
        }
        __syncthreads();                 // A: ks(t+1) ready; ss reads done
    }

    // merge 8 per-sub lists (lane^1,2,4)
    #pragma unroll
    for (int s = 1; s <= 4; s <<= 1) {
        #pragma unroll
        for (int i = 0; i < 16; ++i) {
            unsigned pa = (unsigned)__shfl_xor((int)kreg[31-i], s, 64);
            unsigned pb = (unsigned)__shfl_xor((int)kreg[i],    s, 64);
            if (pa > kreg[i])    kreg[i]    = pa;
            if (pb > kreg[31-i]) kreg[31-i] = pb;
        }
        #pragma unroll
        for (int st = 16; st >= 1; st >>= 1) {
            #pragma unroll
            for (int i2 = 0; i2 < 32; ++i2) {
                if ((i2 & st) == 0) {
                    unsigned lo = kreg[i2], hi = kreg[i2 | st];
                    kreg[i2]      = lo < hi ? hi : lo;
                    kreg[i2 | st] = lo < hi ? lo : hi;
                }
            }
        }
    }

    // softmax over kept 32
    if (ssub == 0) {
        float w[32];
        #pragma unroll
        for (int i = 0; i < 32; ++i) {
            unsigned um = kreg[i] & 0xFFFFF800u;
            unsigned ub = (um & 0x80000000u) ? (um ^ 0x80000000u) : ~um;
            w[i] = __uint_as_float(ub);
        }
        float m = w[0];
        float s = 0.f;
        #pragma unroll
        for (int i = 0; i < 32; ++i) { w[i] = expf(w[i] - m); s += w[i]; }
        float inv = 1.f / s;
        #pragma unroll
        for (int i = 0; i < 32; ++i) {
            wrow[srow*33 + i] = w[i] * inv;
            irow[srow*33 + i] = 2047 - (int)(kreg[i] & 0x7FFu);
        }
    }
    __syncthreads();

    // AV: wave per row-group, lane = head dim; 4 partial accumulators
    const int wid = tid >> 6, lane2 = tid & 63;
    const int b = bh >> 3, h = bh & 7;
    for (int rr = wid; rr < 64; rr += 8) {
        float a0 = 0.f, a1 = 0.f, a2 = 0.f, a3 = 0.f;
        #pragma unroll
        for (int i = 0; i < 8; ++i) {
            a0 = fmaf(wrow[rr*33 + i],      vb[(size_t)irow[rr*33 + i]      * DHEAD + lane2], a0);
            a1 = fmaf(wrow[rr*33 + 8 + i],  vb[(size_t)irow[rr*33 + 8 + i]  * DHEAD + lane2], a1);
            a2 = fmaf(wrow[rr*33 + 16 + i], vb[(size_t)irow[rr*33 + 16 + i] * DHEAD + lane2], a2);
            a3 = fmaf(wrow[rr*33 + 24 + i], vb[(size_t)irow[rr*33 + 24 + i] * DHEAD + lane2], a3);
        }
        float accv = (a0 + a1) + (a2 + a3);
        size_t oi = ((size_t)(b * T_SEQ + t0 + rr)) * DMODEL + h * DHEAD + lane2;
        float s16 = 16.f * accv;
        _Float16 hh = (_Float16)s16;
        outH[oi] = hh;
        outL[oi] = (_Float16)(s16 - (float)hh);
    }
}

// ---------------------------------------------------------------------------
// LayerNorm (+residual); also emits x16 f16 hi/lo planes of the output
// ---------------------------------------------------------------------------
__global__ __launch_bounds__(256) void ln_k(
    const float* __restrict__ x, const float* __restrict__ res,
    const float* __restrict__ g, const float* __restrict__ bb,
    float* __restrict__ out, _Float16* __restrict__ oH, _Float16* __restrict__ oL)
{
    __shared__ float red[8];
    const int row = blockIdx.x;
    const int tid = threadIdx.x;
    const float* xr = x + (size_t)row * DMODEL;
    float v0 = xr[tid], v1 = xr[tid + 256];
    if (res) {
        const float* rr = res + (size_t)row * DMODEL;
        v0 += rr[tid]; v1 += rr[tid + 256];
    }
    float s = v0 + v1;
    #pragma unroll
    for (int o = 1; o < 64; o <<= 1) s += __shfl_xor(s, o);
    const int wid = tid >> 6, lane = tid & 63;
    if (lane == 0) red[wid] = s;
    __syncthreads();
    float mean = (red[0] + red[1] + red[2] + red[3]) * (1.f / DMODEL);
    float d0 = v0 - mean, d1 = v1 - mean;
    float qs = d0*d0 + d1*d1;
    #pragma unroll
    for (int o = 1; o < 64; o <<= 1) qs += __shfl_xor(qs, o);
    if (lane == 0) red[4 + wid] = qs;
    __syncthreads();
    float var = (red[4] + red[5] + red[6] + red[7]) * (1.f / DMODEL);
    float rs = rsqrtf(var + 1e-5f);
    float o0 = d0 * rs * g[tid]       + bb[tid];
    float o1 = d1 * rs * g[tid + 256] + bb[tid + 256];
    size_t base = (size_t)row * DMODEL;
    out[base + tid]       = o0;
    out[base + tid + 256] = o1;
    float s0 = 16.f * o0, s1 = 16.f * o1;
    _Float16 h0 = (_Float16)s0, h1 = (_Float16)s1;
    oH[base + tid]       = h0;
    oH[base + tid + 256] = h1;
    oL[base + tid]       = (_Float16)(s0 - (float)h0);
    oL[base + tid + 256] = (_Float16)(s1 - (float)h1);
}

// ---------------------------------------------------------------------------
__global__ __launch_bounds__(256) void pool_k(
    const float* __restrict__ h, float* __restrict__ part)
{
    const int chunk = blockIdx.x & 15;
    const int idx = (blockIdx.x >> 4) * 256 + threadIdx.x;
    const int b = idx >> 9, d = idx & 511;
    const float* p = h + ((size_t)b * T_SEQ + chunk * 128) * DMODEL + d;
    float s = 0.f;
    for (int t = 0; t < 128; ++t) s += p[(size_t)t * DMODEL];
    part[chunk * 1024 + idx] = s;
}

__global__ __launch_bounds__(256) void poolsum_k(
    const float* __restrict__ part, float* __restrict__ pooled)
{
    int idx = blockIdx.x * 256 + threadIdx.x;
    float s = 0.f;
    #pragma unroll
    for (int c = 0; c < 16; ++c) s += part[c * 1024 + idx];
    pooled[idx] = s * (1.f / T_SEQ);
}

__global__ __launch_bounds__(256) void cls_k(
    const float* __restrict__ pooled, const float* __restrict__ w,
    const float* __restrict__ bias, float* __restrict__ out)
{
    const int wid = threadIdx.x >> 6, lane = threadIdx.x & 63;
    const int oi = blockIdx.x * 4 + wid;
    const int b = oi >> 8, o = oi & 255;
    const float* pr = pooled + b * DMODEL;
    const float* wr = w + (size_t)o * DMODEL;
    float s = 0.f;
    for (int d = lane; d < DMODEL; d += 64) s = fmaf(pr[d], wr[d], s);
    #pragma unroll
    for (int off = 1; off < 64; off <<= 1) s += __shfl_xor(s, off);
    if (lane == 0) out[oi] = s + bias[o];
}

// ---------------------------------------------------------------------------
extern "C" void kernel_launch(void* const* d_in, const int* in_sizes, int n_in,
                              void* d_out, int out_size, void* d_ws, size_t ws_size,
                              hipStream_t stream)
{
    const float* x     = (const float*)d_in[0];
    const float* emb_w = (const float*)d_in[1];
    const float* emb_b = (const float*)d_in[2];
    const float* pos   = (const float*)d_in[3];
    const float* wq    = (const float*)d_in[4];
    const float* bq    = (const float*)d_in[5];
    const float* wk    = (const float*)d_in[6];
    const float* bk    = (const float*)d_in[7];
    const float* wv    = (const float*)d_in[8];
    const float* bv    = (const float*)d_in[9];
    const float* wo    = (const float*)d_in[10];
    const float* bo    = (const float*)d_in[11];
    const float* ln1g  = (const float*)d_in[12];
    const float* ln1b  = (const float*)d_in[13];
    const float* fc1w  = (const float*)d_in[14];
    const float* fc1b  = (const float*)d_in[15];
    const float* fc2w  = (const float*)d_in[16];
    const float* fc2b  = (const float*)d_in[17];
    const float* ln2g  = (const float*)d_in[18];
    const float* ln2b  = (const float*)d_in[19];
    const float* fng   = (const float*)d_in[20];
    const float* fnb   = (const float*)d_in[21];
    const float* clsw  = (const float*)d_in[22];
    const float* clsb  = (const float*)d_in[23];

    float* ws = (float*)d_ws;
    const size_t SZ  = (size_t)MROWS * DMODEL;   // 2,097,152 floats
    const size_t HP  = SZ / 2;
    float*     h     = ws;
    float*     t1    = ws + 1*SZ;
    _Float16*  hH    = (_Float16*)(ws + 2*SZ);
    _Float16*  hL    = (_Float16*)(ws + 2*SZ + HP);
    _Float16*  aoH   = (_Float16*)(ws + 3*SZ);
    _Float16*  aoL   = (_Float16*)(ws + 3*SZ + HP);
    _Float16*  qbH   = (_Float16*)(ws + 4*SZ);
    _Float16*  qbL   = (_Float16*)(ws + 4*SZ + HP);
    _Float16*  kbH   = (_Float16*)(ws + 5*SZ);
    _Float16*  kbL   = (_Float16*)(ws + 5*SZ + HP);
    float*     vbuf  = ws + 6*SZ;
    _Float16*  WcatH = (_Float16*)(ws + 7*SZ);
    _Float16*  WcatL = (_Float16*)(ws + 7*SZ + 393216);
    _Float16*  WoH   = (_Float16*)(ws + 7*SZ + 786432);
    _Float16*  WoL   = (_Float16*)(ws + 7*SZ + 917504);
    _Float16*  W1H   = (_Float16*)(ws + 7*SZ + 1048576);
    _Float16*  W1L   = (_Float16*)(ws + 7*SZ + 1572864);
    _Float16*  W2H   = (_Float16*)(ws + 7*SZ + 2097152);
    _Float16*  W2L   = (_Float16*)(ws + 7*SZ + 2621440);
    float*     bcat  = ws + 7*SZ + 3145728;
    float*     pooled= ws + 7*SZ + 3145728 + 1536;
    float*     part  = ws + 7*SZ + 3145728 + 1536 + 1024;
    _Float16*  hid   = (_Float16*)(ws + 4*SZ);   // aliases q/k planes (dead then)
    const size_t needed = (7*SZ + 3145728 + 1536 + 1024 + 16384) * sizeof(float);
    if (ws_size < needed) return;

    dim3 blk(256);

    gemm_k<64,1><<<dim3(DMODEL/64, MROWS/128), blk, 0, stream>>>(
        x, emb_w, emb_b, pos, h, MROWS, DMODEL, 128);
    cvtw_k<<<dim3((int)(SZ/256)), blk, 0, stream>>>(h, hH, hL, (int)SZ, 16.f);

    for (int l = 0; l < NLAYER; ++l) {
        const float* wq_l = wq + (size_t)l*DMODEL*DMODEL;
        const float* bq_l = bq + (size_t)l*DMODEL;
        const float* wk_l = wk + (size_t)l*DMODEL*DMODEL;
        const float* bk_l = bk + (size_t)l*DMODEL;
        const float* wv_l = wv + (size_t)l*DMODEL*DMODEL;
        const float* bv_l = bv + (size_t)l*DMODEL;
        const float* wo_l = wo + (size_t)l*DMODEL*DMODEL;
        const float* bo_l = bo + (size_t)l*DMODEL;
        const float* f1w_l = fc1w + (size_t)l*FDIM*DMODEL;
        const float* f1b_l = fc1b + (size_t)l*FDIM;
        const float* f2w_l = fc2w + (size_t)l*DMODEL*FDIM;
        const float* f2b_l = fc2b + (size_t)l*DMODEL;

        // all weight conversions for this layer in one launch
        cvtlayer_k<<<dim3(12294), blk, 0, stream>>>(
            wq_l, wk_l, wv_l, bq_l, bk_l, bv_l, wo_l, f1w_l, f2w_l,
            WcatH, WcatL, bcat, WoH, WoL, W1H, W1L, W2H, W2L);

        // fused QKV (BM=64 -> 768 blocks = 256 CU x 3): q,k f16 planes, v fp32
        mgemm_k<64,0,0,2><<<dim3(12, 64), blk, 0, stream>>>(
            hH, hL, WcatH, WcatL, bcat,
            (float*)qbH, (float*)qbL, (float*)kbH, (float*)kbL, vbuf,
            MROWS, 1536, DMODEL);

        attn_k<<<dim3(T_SEQ/64, NB*NHEAD), dim3(512), 0, stream>>>(
            qbH, qbL, kbH, kbL, vbuf, aoH, aoL);

        // o-proj + spike (BM=64 -> 256 blocks)
        mgemm_k<64,0,2,0><<<dim3(4, 64), blk, 0, stream>>>(
            aoH, aoL, WoH, WoL, bo_l, t1, nullptr, nullptr, nullptr, nullptr,
            MROWS, DMODEL, DMODEL);
        ln_k<<<dim3(MROWS), blk, 0, stream>>>(h, t1, ln1g + (size_t)l*DMODEL,
                                              ln1b + (size_t)l*DMODEL, h, hH, hL);

        // FFN: fc1 (BM=128, 512 blocks) spike->f16; fc2 (BM=64, 256 blocks)
        mgemm_k<128,0,3,0><<<dim3(16, 32), blk, 0, stream>>>(
            hH, hL, W1H, W1L, f1b_l, (float*)hid, nullptr, nullptr, nullptr, nullptr,
            MROWS, FDIM, DMODEL);
        mgemm_k<64,1,2,0><<<dim3(4, 64), blk, 0, stream>>>(
            hid, nullptr, W2H, W2L, f2b_l, t1, nullptr, nullptr, nullptr, nullptr,
            MROWS, DMODEL, FDIM);
        ln_k<<<dim3(MROWS), blk, 0, stream>>>(h, t1, ln2g + (size_t)l*DMODEL,
                                              ln2b + (size_t)l*DMODEL, h, hH, hL);
    }

    ln_k<<<dim3(MROWS), blk, 0, stream>>>(h, nullptr, fng, fnb, h, hH, hL);
    pool_k<<<dim3(64), blk, 0, stream>>>(h, part);
    poolsum_k<<<dim3(4), blk, 0, stream>>>(part, pooled);
    cls_k<<<dim3(128), blk, 0, stream>>>(pooled, clsw, clsb, (float*)d_out);
}

// Round 5
// 1151.839 us; speedup vs baseline: 1.0102x; 1.0102x over previous
//
#include <hip/hip_runtime.h>
#include <math.h>
#include <float.h>

#define T_SEQ  2048
#define DMODEL 512
#define NHEAD  8
#define DHEAD  64
#define FDIM   2048
#define NLAYER 4
#define NB     2
#define MROWS  (NB*T_SEQ)   // 4096

typedef _Float16 f16x8 __attribute__((ext_vector_type(8)));
typedef float    f32x4 __attribute__((ext_vector_type(4)));

// async 16B global -> LDS (wave-uniform LDS base, lane x 16B dest)
__device__ __forceinline__ void async16(const _Float16* g, _Float16* l) {
    __builtin_amdgcn_global_load_lds(
        (const __attribute__((address_space(1))) unsigned int*)g,
        (__attribute__((address_space(3))) unsigned int*)l, 16, 0, 0);
}

// ---------------------------------------------------------------------------
// fp32 vector GEMM — embedding only (K=128)
// ---------------------------------------------------------------------------
template<int BN, int EPI>
__global__ __launch_bounds__(256) void gemm_k(
    const float* __restrict__ A, const float* __restrict__ W,
    const float* __restrict__ bias, const float* __restrict__ pos,
    float* __restrict__ C, int M, int N, int K)
{
    constexpr int BM = 128;
    constexpr int BK = 32;
    constexpr int MN = BN / 16;
    __shared__ float As[BK][BM + 4];
    __shared__ float Ws[BK][BN + 4];
    const int tid = threadIdx.x;
    const int n0 = blockIdx.x * BN;
    const int m0 = blockIdx.y * BM;
    const int tx = tid & 15;
    const int ty = tid >> 4;

    float acc[8][MN];
    #pragma unroll
    for (int i = 0; i < 8; ++i)
        #pragma unroll
        for (int j = 0; j < MN; ++j) acc[i][j] = 0.f;

    for (int k0 = 0; k0 < K; k0 += BK) {
        #pragma unroll
        for (int it = 0; it < 4; ++it) {
            int qq = tid + 256 * it;
            int m = qq >> 3, kq = qq & 7;
            float4 v4 = *(const float4*)(A + (size_t)(m0 + m) * K + k0 + kq * 4);
            As[kq*4+0][m] = v4.x; As[kq*4+1][m] = v4.y;
            As[kq*4+2][m] = v4.z; As[kq*4+3][m] = v4.w;
        }
        #pragma unroll
        for (int it = 0; it < BN/32; ++it) {
            int qq = tid + 256 * it;
            int n = qq >> 3, kq = qq & 7;
            float4 v4 = *(const float4*)(W + (size_t)(n0 + n) * K + k0 + kq * 4);
            Ws[kq*4+0][n] = v4.x; Ws[kq*4+1][n] = v4.y;
            Ws[kq*4+2][n] = v4.z; Ws[kq*4+3][n] = v4.w;
        }
        __syncthreads();
        for (int kk = 0; kk < BK; ++kk) {
            float a[8], b[MN];
            float4 a0 = *(const float4*)&As[kk][ty*8];
            float4 a1 = *(const float4*)&As[kk][ty*8+4];
            a[0]=a0.x; a[1]=a0.y; a[2]=a0.z; a[3]=a0.w;
            a[4]=a1.x; a[5]=a1.y; a[6]=a1.z; a[7]=a1.w;
            float4 b0 = *(const float4*)&Ws[kk][tx*4];
            b[0]=b0.x; b[1]=b0.y; b[2]=b0.z; b[3]=b0.w;
            if constexpr (MN == 8) {
                float4 b1 = *(const float4*)&Ws[kk][64 + tx*4];
                b[4]=b1.x; b[5]=b1.y; b[6]=b1.z; b[7]=b1.w;
            }
            #pragma unroll
            for (int i = 0; i < 8; ++i)
                #pragma unroll
                for (int j = 0; j < MN; ++j)
                    acc[i][j] = fmaf(a[i], b[j], acc[i][j]);
        }
        __syncthreads();
    }

    #pragma unroll
    for (int i = 0; i < 8; ++i) {
        int m = m0 + ty*8 + i;
        #pragma unroll
        for (int jb = 0; jb < MN/4; ++jb) {
            int nn = n0 + jb*64 + tx*4;
            float4 r;
            r.x = acc[i][jb*4+0] + bias[nn+0];
            r.y = acc[i][jb*4+1] + bias[nn+1];
            r.z = acc[i][jb*4+2] + bias[nn+2];
            r.w = acc[i][jb*4+3] + bias[nn+3];
            if constexpr (EPI == 1) {
                const float* pp = pos + (size_t)(m & (T_SEQ-1)) * DMODEL + nn;
                r.x += pp[0]; r.y += pp[1]; r.z += pp[2]; r.w += pp[3];
            }
            *(float4*)(C + (size_t)m * N + nn) = r;
        }
    }
}

// ---------------------------------------------------------------------------
// f16-split MFMA GEMM: C = (1/1024)·A'[M,K]·W'[N,K]^T + bias
// (reg-staged LDS: 64B-granule coalesced global loads -> ds_write)
// BM: 128 or 64. BN: 128 or 64.
// BN==64 exists for the N=512 GEMMs (o-proj, fc2): grid (8,64)=512 blocks
// = 2 blocks/CU instead of (4,64)=256 = 1/CU where barrier drains have no
// co-resident block to overlap with. A-traffic doubles (~+5-10us HBM) but
// occupancy doubles.
// ASRC: 0 = dual-plane A; 1 = single-plane A (exact spikes; AsL elided)
// EPI:  0 = fp32; 2 = spike->fp32; 3 = spike->f16 plane (x16)
// LAYOUT: 0 = [M,N]; 2 = fused QKV (q,k f16 planes head layout; v fp32)
// ---------------------------------------------------------------------------
template<int BM, int BN, int ASRC, int EPI, int LAYOUT>
__global__ __launch_bounds__(256, (BM == 64) ? 3 : 2) void mgemm_k(
    const _Float16* __restrict__ AH, const _Float16* __restrict__ AL,
    const _Float16* __restrict__ WH, const _Float16* __restrict__ WL,
    const float* __restrict__ bias,
    float* __restrict__ O0, float* __restrict__ O1, float* __restrict__ O2,
    float* __restrict__ O3, float* __restrict__ O4,
    int M, int N, int K)
{
    constexpr int MI = BM / 32;
    constexpr int NJ = BN / 32;
    __shared__ _Float16 AsH[4][BM][8];
    __shared__ _Float16 AsL[(ASRC == 0) ? 4 : 1][BM][8];
    __shared__ _Float16 WsH[4][BN][8];
    __shared__ _Float16 WsL[4][BN][8];

    const int tid = threadIdx.x;
    const int n0 = blockIdx.x * BN;
    const int m0 = blockIdx.y * BM;
    const int wv = tid >> 6, lane = tid & 63;
    const int mw = (wv >> 1) * (BM/2), nw = (wv & 1) * (BN/2);
    const int fr = lane & 15;
    const int kb = lane >> 4;

    const int wsrow = tid >> 1;
    const int wskb  = (tid & 1) * 2;
    const int wkoff = (tid & 1) * 16;

    f32x4 acc[MI][NJ];
    #pragma unroll
    for (int i = 0; i < MI; ++i)
        #pragma unroll
        for (int j = 0; j < NJ; ++j) acc[i][j] = (f32x4)(0.f);

    for (int k0 = 0; k0 < K; k0 += 32) {
        if constexpr (BM == 128) {
            const _Float16* ap = AH + (size_t)(m0 + wsrow) * K + k0 + wkoff;
            *(f16x8*)&AsH[wskb  ][wsrow][0] = *(const f16x8*)ap;
            *(f16x8*)&AsH[wskb+1][wsrow][0] = *(const f16x8*)(ap + 8);
            if constexpr (ASRC == 0) {
                const _Float16* alp = AL + (size_t)(m0 + wsrow) * K + k0 + wkoff;
                *(f16x8*)&AsL[wskb  ][wsrow][0] = *(const f16x8*)alp;
                *(f16x8*)&AsL[wskb+1][wsrow][0] = *(const f16x8*)(alp + 8);
            }
        } else {
            const int arow = tid >> 2, akb = tid & 3;
            *(f16x8*)&AsH[akb][arow][0] =
                *(const f16x8*)(AH + (size_t)(m0 + arow) * K + k0 + akb*8);
            if constexpr (ASRC == 0)
                *(f16x8*)&AsL[akb][arow][0] =
                    *(const f16x8*)(AL + (size_t)(m0 + arow) * K + k0 + akb*8);
        }
        if constexpr (BN == 128) {
            const _Float16* wp = WH + (size_t)(n0 + wsrow) * K + k0 + wkoff;
            *(f16x8*)&WsH[wskb  ][wsrow][0] = *(const f16x8*)wp;
            *(f16x8*)&WsH[wskb+1][wsrow][0] = *(const f16x8*)(wp + 8);
            const _Float16* wlp = WL + (size_t)(n0 + wsrow) * K + k0 + wkoff;
            *(f16x8*)&WsL[wskb  ][wsrow][0] = *(const f16x8*)wlp;
            *(f16x8*)&WsL[wskb+1][wsrow][0] = *(const f16x8*)(wlp + 8);
        } else {
            const int wrow = tid >> 2, wwkb = tid & 3;
            *(f16x8*)&WsH[wwkb][wrow][0] =
                *(const f16x8*)(WH + (size_t)(n0 + wrow) * K + k0 + wwkb*8);
            *(f16x8*)&WsL[wwkb][wrow][0] =
                *(const f16x8*)(WL + (size_t)(n0 + wrow) * K + k0 + wwkb*8);
        }
        __syncthreads();

        f16x8 aH[MI], aL[MI], bH[NJ], bL[NJ];
        #pragma unroll
        for (int i = 0; i < MI; ++i) {
            aH[i] = *(const f16x8*)&AsH[kb][mw + i*16 + fr][0];
            if constexpr (ASRC == 0) aL[i] = *(const f16x8*)&AsL[kb][mw + i*16 + fr][0];
        }
        #pragma unroll
        for (int j = 0; j < NJ; ++j) {
            bH[j] = *(const f16x8*)&WsH[kb][nw + j*16 + fr][0];
            bL[j] = *(const f16x8*)&WsL[kb][nw + j*16 + fr][0];
        }
        #pragma unroll
        for (int i = 0; i < MI; ++i)
            #pragma unroll
            for (int j = 0; j < NJ; ++j) {
                acc[i][j] = __builtin_amdgcn_mfma_f32_16x16x32_f16(aH[i], bH[j], acc[i][j], 0, 0, 0);
                acc[i][j] = __builtin_amdgcn_mfma_f32_16x16x32_f16(aH[i], bL[j], acc[i][j], 0, 0, 0);
                if constexpr (ASRC == 0)
                    acc[i][j] = __builtin_amdgcn_mfma_f32_16x16x32_f16(aL[i], bH[j], acc[i][j], 0, 0, 0);
            }
        __syncthreads();
    }

    const int qq = lane >> 4;
    #pragma unroll
    for (int j = 0; j < NJ; ++j) {
        int n = n0 + nw + j*16 + fr;
        float bv = bias[n];
        #pragma unroll
        for (int i = 0; i < MI; ++i) {
            #pragma unroll
            for (int r = 0; r < 4; ++r) {
                int m = m0 + mw + i*16 + qq*4 + r;
                float val = acc[i][j][r] * (1.f/1024.f) + bv;
                if constexpr (EPI == 2) val = val > 0.5f ? 1.f : 0.f;
                if constexpr (EPI == 3) {
                    ((_Float16*)O0)[(size_t)m * N + n] = (val > 0.5f) ? (_Float16)16.f : (_Float16)0.f;
                } else if constexpr (LAYOUT == 0) {
                    O0[(size_t)m * N + n] = val;
                } else {
                    int b_ = m >> 11, t_ = m & (T_SEQ-1);
                    if (n < 512) {
                        size_t hl = (((size_t)(b_*NHEAD + (n>>6))*T_SEQ + t_) << 6) + (n & 63);
                        float s16 = 16.f * val;
                        _Float16 hh = (_Float16)s16;
                        ((_Float16*)O0)[hl] = hh;
                        ((_Float16*)O1)[hl] = (_Float16)(s16 - (float)hh);
                    } else if (n < 1024) {
                        int nn = n - 512;
                        size_t hl = (((size_t)(b_*NHEAD + (nn>>6))*T_SEQ + t_) << 6) + (nn & 63);
                        float s16 = 16.f * val;
                        _Float16 hh = (_Float16)s16;
                        ((_Float16*)O2)[hl] = hh;
                        ((_Float16*)O3)[hl] = (_Float16)(s16 - (float)hh);
                    } else {
                        int nn = n - 1024;
                        O4[(((size_t)(b_*NHEAD + (nn>>6))*T_SEQ + t_) << 6) + (nn & 63)] = val;
                    }
                }
            }
        }
    }
}

// ---------------------------------------------------------------------------
// h-split (embedding output -> x16 planes)
// ---------------------------------------------------------------------------
__global__ __launch_bounds__(256) void cvtw_k(
    const float* __restrict__ w, _Float16* __restrict__ H, _Float16* __restrict__ L,
    int n, float scale)
{
    int i = blockIdx.x * 256 + threadIdx.x;
    if (i < n) {
        float s = scale * w[i];
        _Float16 h = (_Float16)s;
        H[i] = h;
        L[i] = (_Float16)(s - (float)h);
    }
}

// all of one layer's weight conversions fused (x64 split), one launch
__global__ __launch_bounds__(256) void cvtlayer_k(
    const float* __restrict__ wq, const float* __restrict__ wk, const float* __restrict__ wv,
    const float* __restrict__ bq, const float* __restrict__ bk, const float* __restrict__ bv,
    const float* __restrict__ wo, const float* __restrict__ f1w, const float* __restrict__ f2w,
    _Float16* __restrict__ WcatH, _Float16* __restrict__ WcatL, float* __restrict__ bcat,
    _Float16* __restrict__ WoH, _Float16* __restrict__ WoL,
    _Float16* __restrict__ W1H, _Float16* __restrict__ W1L,
    _Float16* __restrict__ W2H, _Float16* __restrict__ W2L)
{
    int i = blockIdx.x * 256 + threadIdx.x;
    float w;
    _Float16 *H, *L;
    int off;
    if (i < 786432) {
        int src = i >> 18, o = i & 262143;
        w = (src == 0 ? wq : (src == 1 ? wk : wv))[o];
        H = WcatH; L = WcatL; off = i;
    } else if (i < 1048576) {
        off = i - 786432;  w = wo[off];  H = WoH; L = WoL;
    } else if (i < 2097152) {
        off = i - 1048576; w = f1w[off]; H = W1H; L = W1L;
    } else if (i < 3145728) {
        off = i - 2097152; w = f2w[off]; H = W2H; L = W2L;
    } else if (i < 3145728 + 1536) {
        int j = i - 3145728;
        int src = j >> 9, o = j & 511;
        bcat[j] = (src == 0 ? bq : (src == 1 ? bk : bv))[o];
        return;
    } else return;
    float s = 64.f * w;
    _Float16 h = (_Float16)s;
    H[off] = h;
    L[off] = (_Float16)(s - (float)h);
}

// ---------------------------------------------------------------------------
// Fused sparse attention v9 — v8 + __expf (shorter instruction sequence;
// softmax wave pays full issue cost even with 8/64 lanes active).
// 512 thr / 64 q-rows, 512 blocks = 2/CU exactly; ss[64][132] padded;
// sort-16 CE as explicit min/max; Q in registers; async K staging.
// ---------------------------------------------------------------------------
__global__ __launch_bounds__(512, 4) void attn_k(
    const _Float16* __restrict__ qH, const _Float16* __restrict__ qL,
    const _Float16* __restrict__ kH, const _Float16* __restrict__ kL,
    const float* __restrict__ v,
    _Float16* __restrict__ outH, _Float16* __restrict__ outL)
{
    // ksH [128*64] @0 (16384) | ksL @16384 | ss[64][132] f32 @32768 (33792)
    // -> total 66560; wrow/irow alias ss
    __shared__ unsigned char lds[66560];
    _Float16* ksH = (_Float16*)(lds);
    _Float16* ksL = (_Float16*)(lds + 16384);
    float    (*ss)[132] = (float(*)[132])(lds + 32768);
    float*   wrow       = (float*)(lds + 32768);
    int*     irow       = (int*)(lds + 32768 + 8448);

    const int tid = threadIdx.x;
    const int bh  = blockIdx.y;
    const int t0  = blockIdx.x * 64;
    const _Float16* qHb = qH + ((size_t)bh * T_SEQ + t0) * DHEAD;
    const _Float16* qLb = qL + ((size_t)bh * T_SEQ + t0) * DHEAD;
    const _Float16* kHb = kH + (size_t)bh * T_SEQ * DHEAD;
    const _Float16* kLb = kL + (size_t)bh * T_SEQ * DHEAD;
    const float*    vb  = v  + (size_t)bh * T_SEQ * DHEAD;

    unsigned kreg[32];
    #pragma unroll
    for (int i = 0; i < 32; ++i) kreg[i] = 0u;

    const int wv = tid >> 6, lane = tid & 63;
    const int fr = lane & 15, q4 = lane >> 4;
    const int mh  = (wv >> 2) * 32;      // q-row half owned by this wave
    const int c0w = (wv & 3) * 32;       // col strip owned by this wave
    const int srow = tid >> 3;           // 0..63
    const int ssub = tid & 7;

    // Q fragments in registers: loop-invariant across all K tiles.
    // [ks][mi]: row = mh + mi*16 + fr; doff = ks*32 + q4*8
    f16x8 qaH[2][2], qaL[2][2];
    #pragma unroll
    for (int ks = 0; ks < 2; ++ks) {
        const int doff = ks*32 + q4*8;
        qaH[ks][0] = *(const f16x8*)(qHb + (mh + fr)*DHEAD + doff);
        qaH[ks][1] = *(const f16x8*)(qHb + (mh + 16 + fr)*DHEAD + doff);
        qaL[ks][0] = *(const f16x8*)(qLb + (mh + fr)*DHEAD + doff);
        qaL[ks][1] = *(const f16x8*)(qLb + (mh + 16 + fr)*DHEAD + doff);
    }

    // async stage of one K tile: 8 waves x 16 rows -> 2 instrs/plane/wave
    auto stage = [&](int jt) {
        const int j0 = jt * 128;
        #pragma unroll
        for (int i = 0; i < 2; ++i) {
            const int r0 = wv*16 + i*8;                 // wave-uniform
            const int cc = r0 + (lane >> 3);
            const int ch = (lane & 7) ^ (cc & 7);       // swizzled source chunk
            const size_t goff = (size_t)(j0 + cc) * DHEAD + ch*8;
            async16(kHb + goff, ksH + r0*64);
            async16(kLb + goff, ksL + r0*64);
        }
    };

    stage(0);
    __syncthreads();                     // ks(0) ready (drains vmcnt)

    for (int jt = 0; jt < 16; ++jt) {
        const int j0 = jt * 128;

        // QK^T: 2 m-frags x 2 n-frags x 2 k-steps x 3 split passes
        f32x4 acc[2][2];
        acc[0][0] = (f32x4)(0.f); acc[0][1] = (f32x4)(0.f);
        acc[1][0] = (f32x4)(0.f); acc[1][1] = (f32x4)(0.f);
        #pragma unroll
        for (int ks = 0; ks < 2; ++ks) {
            const int chq  = ks*4 + q4;                 // chunk index of doff
            #pragma unroll
            for (int nj = 0; nj < 2; ++nj) {
                const int cc = c0w + nj*16 + fr;
                const int sl = cc*64 + (chq ^ (cc & 7))*8;
                f16x8 bHf = *(const f16x8*)&ksH[sl];
                f16x8 bLf = *(const f16x8*)&ksL[sl];
                acc[0][nj] = __builtin_amdgcn_mfma_f32_16x16x32_f16(qaH[ks][0], bHf, acc[0][nj], 0, 0, 0);
                acc[0][nj] = __builtin_amdgcn_mfma_f32_16x16x32_f16(qaH[ks][0], bLf, acc[0][nj], 0, 0, 0);
                acc[0][nj] = __builtin_amdgcn_mfma_f32_16x16x32_f16(qaL[ks][0], bHf, acc[0][nj], 0, 0, 0);
                acc[1][nj] = __builtin_amdgcn_mfma_f32_16x16x32_f16(qaH[ks][1], bHf, acc[1][nj], 0, 0, 0);
                acc[1][nj] = __builtin_amdgcn_mfma_f32_16x16x32_f16(qaH[ks][1], bLf, acc[1][nj], 0, 0, 0);
                acc[1][nj] = __builtin_amdgcn_mfma_f32_16x16x32_f16(qaL[ks][1], bHf, acc[1][nj], 0, 0, 0);
            }
        }
        // scores to LDS (row = mh + mi*16 + q4*4 + r, col = c0w + nj*16 + fr)
        #pragma unroll
        for (int mi = 0; mi < 2; ++mi)
            #pragma unroll
            for (int nj = 0; nj < 2; ++nj)
                #pragma unroll
                for (int r = 0; r < 4; ++r)
                    ss[mh + mi*16 + q4*4 + r][c0w + nj*16 + fr] = acc[mi][nj][r] * (1.f/2048.f);
        __syncthreads();                 // C: ss visible; all ks reads done

        if (jt < 15) stage(jt + 1);      // async; hides under select

        // branch-free select: 16 candidates / thread, u32 packed keys
        float4 c4[4];
        {
            const float* ssr = &ss[srow][0] + ssub*4;
            #pragma unroll
            for (int g = 0; g < 4; ++g) c4[g] = *(const float4*)(ssr + g*32);
        }
        unsigned cand[16];
        #pragma unroll
        for (int g = 0; g < 4; ++g) {
            float vg[4] = {c4[g].x, c4[g].y, c4[g].z, c4[g].w};
            #pragma unroll
            for (int r = 0; r < 4; ++r) {
                unsigned u = __float_as_uint(vg[r]);
                u ^= (unsigned)((int)u >> 31) | 0x80000000u;
                int col = ssub*4 + g*32 + r;
                cand[g*4+r] = (u & 0xFFFFF800u) | (unsigned)(2047 - (j0 + col));
            }
        }
        // bitonic sort-16 descending; CE as explicit min/max (v_min/max_u32)
        #pragma unroll
        for (int k2 = 2; k2 <= 16; k2 <<= 1) {
            #pragma unroll
            for (int j2 = k2 >> 1; j2 > 0; j2 >>= 1) {
                #pragma unroll
                for (int i2 = 0; i2 < 16; ++i2) {
                    int l2 = i2 ^ j2;
                    if (l2 > i2) {
                        unsigned a = cand[i2], b = cand[l2];
                        unsigned mn = a < b ? a : b;
                        unsigned mx = a < b ? b : a;
                        if ((i2 & k2) == 0) { cand[i2] = mx; cand[l2] = mn; }
                        else                { cand[i2] = mn; cand[l2] = mx; }
                    }
                }
            }
        }
        #pragma unroll
        for (int j2 = 0; j2 < 16; ++j2) {
            unsigned b = cand[15 - j2];
            if (kreg[16 + j2] < b) kreg[16 + j2] = b;
        }
        #pragma unroll
        for (int st = 16; st >= 1; st >>= 1) {
            #pragma unroll
            for (int i2 = 0; i2 < 32; ++i2) {
                if ((i2 & st) == 0) {
                    unsigned lo = kreg[i2], hi = kreg[i2 | st];
                    kreg[i2]      = lo < hi ? hi : lo;
                    kreg[i2 | st] = lo < hi ? lo : hi;
                }
            }
        }
        __syncthreads();                 // A: ks(t+1) ready; ss reads done
    }

    // merge 8 per-sub lists (lane^1,2,4)
    #pragma unroll
    for (int s = 1; s <= 4; s <<= 1) {
        #pragma unroll
        for (int i = 0; i < 16; ++i) {
            unsigned pa = (unsigned)__shfl_xor((int)kreg[31-i], s, 64);
            unsigned pb = (unsigned)__shfl_xor((int)kreg[i],    s, 64);
            if (pa > kreg[i])    kreg[i]    = pa;
            if (pb > kreg[31-i]) kreg[31-i] = pb;
        }
        #pragma unroll
        for (int st = 16; st >= 1; st >>= 1) {
            #pragma unroll
            for (int i2 = 0; i2 < 32; ++i2) {
                if ((i2 & st) == 0) {
                    unsigned lo = kreg[i2], hi = kreg[i2 | st];
                    kreg[i2]      = lo < hi ? hi : lo;
                    kreg[i2 | st] = lo < hi ? lo : hi;
                }
            }
        }
    }

    // softmax over kept 32
    if (ssub == 0) {
        float w[32];
        #pragma unroll
        for (int i = 0; i < 32; ++i) {
            unsigned um = kreg[i] & 0xFFFFF800u;
            unsigned ub = (um & 0x80000000u) ? (um ^ 0x80000000u) : ~um;
            w[i] = __uint_as_float(ub);
        }
        float m = w[0];
        float s = 0.f;
        #pragma unroll
        for (int i = 0; i < 32; ++i) { w[i] = __expf(w[i] - m); s += w[i]; }
        float inv = 1.f / s;
        #pragma unroll
        for (int i = 0; i < 32; ++i) {
            wrow[srow*33 + i] = w[i] * inv;
            irow[srow*33 + i] = 2047 - (int)(kreg[i] & 0x7FFu);
        }
    }
    __syncthreads();

    // AV: wave per row-group, lane = head dim; 4 partial accumulators
    const int wid = tid >> 6, lane2 = tid & 63;
    const int b = bh >> 3, h = bh & 7;
    for (int rr = wid; rr < 64; rr += 8) {
        float a0 = 0.f, a1 = 0.f, a2 = 0.f, a3 = 0.f;
        #pragma unroll
        for (int i = 0; i < 8; ++i) {
            a0 = fmaf(wrow[rr*33 + i],      vb[(size_t)irow[rr*33 + i]      * DHEAD + lane2], a0);
            a1 = fmaf(wrow[rr*33 + 8 + i],  vb[(size_t)irow[rr*33 + 8 + i]  * DHEAD + lane2], a1);
            a2 = fmaf(wrow[rr*33 + 16 + i], vb[(size_t)irow[rr*33 + 16 + i] * DHEAD + lane2], a2);
            a3 = fmaf(wrow[rr*33 + 24 + i], vb[(size_t)irow[rr*33 + 24 + i] * DHEAD + lane2], a3);
        }
        float accv = (a0 + a1) + (a2 + a3);
        size_t oi = ((size_t)(b * T_SEQ + t0 + rr)) * DMODEL + h * DHEAD + lane2;
        float s16 = 16.f * accv;
        _Float16 hh = (_Float16)s16;
        outH[oi] = hh;
        outL[oi] = (_Float16)(s16 - (float)hh);
    }
}

// ---------------------------------------------------------------------------
// LayerNorm (+residual); also emits x16 f16 hi/lo planes of the output
// ---------------------------------------------------------------------------
__global__ __launch_bounds__(256) void ln_k(
    const float* __restrict__ x, const float* __restrict__ res,
    const float* __restrict__ g, const float* __restrict__ bb,
    float* __restrict__ out, _Float16* __restrict__ oH, _Float16* __restrict__ oL)
{
    __shared__ float red[8];
    const int row = blockIdx.x;
    const int tid = threadIdx.x;
    const float* xr = x + (size_t)row * DMODEL;
    float v0 = xr[tid], v1 = xr[tid + 256];
    if (res) {
        const float* rr = res + (size_t)row * DMODEL;
        v0 += rr[tid]; v1 += rr[tid + 256];
    }
    float s = v0 + v1;
    #pragma unroll
    for (int o = 1; o < 64; o <<= 1) s += __shfl_xor(s, o);
    const int wid = tid >> 6, lane = tid & 63;
    if (lane == 0) red[wid] = s;
    __syncthreads();
    float mean = (red[0] + red[1] + red[2] + red[3]) * (1.f / DMODEL);
    float d0 = v0 - mean, d1 = v1 - mean;
    float qs = d0*d0 + d1*d1;
    #pragma unroll
    for (int o = 1; o < 64; o <<= 1) qs += __shfl_xor(qs, o);
    if (lane == 0) red[4 + wid] = qs;
    __syncthreads();
    float var = (red[4] + red[5] + red[6] + red[7]) * (1.f / DMODEL);
    float rs = rsqrtf(var + 1e-5f);
    float o0 = d0 * rs * g[tid]       + bb[tid];
    float o1 = d1 * rs * g[tid + 256] + bb[tid + 256];
    size_t base = (size_t)row * DMODEL;
    out[base + tid]       = o0;
    out[base + tid + 256] = o1;
    float s0 = 16.f * o0, s1 = 16.f * o1;
    _Float16 h0 = (_Float16)s0, h1 = (_Float16)s1;
    oH[base + tid]       = h0;
    oH[base + tid + 256] = h1;
    oL[base + tid]       = (_Float16)(s0 - (float)h0);
    oL[base + tid + 256] = (_Float16)(s1 - (float)h1);
}

// ---------------------------------------------------------------------------
__global__ __launch_bounds__(256) void pool_k(
    const float* __restrict__ h, float* __restrict__ part)
{
    const int chunk = blockIdx.x & 15;
    const int idx = (blockIdx.x >> 4) * 256 + threadIdx.x;
    const int b = idx >> 9, d = idx & 511;
    const float* p = h + ((size_t)b * T_SEQ + chunk * 128) * DMODEL + d;
    float s = 0.f;
    for (int t = 0; t < 128; ++t) s += p[(size_t)t * DMODEL];
    part[chunk * 1024 + idx] = s;
}

__global__ __launch_bounds__(256) void poolsum_k(
    const float* __restrict__ part, float* __restrict__ pooled)
{
    int idx = blockIdx.x * 256 + threadIdx.x;
    float s = 0.f;
    #pragma unroll
    for (int c = 0; c < 16; ++c) s += part[c * 1024 + idx];
    pooled[idx] = s * (1.f / T_SEQ);
}

__global__ __launch_bounds__(256) void cls_k(
    const float* __restrict__ pooled, const float* __restrict__ w,
    const float* __restrict__ bias, float* __restrict__ out)
{
    const int wid = threadIdx.x >> 6, lane = threadIdx.x & 63;
    const int oi = blockIdx.x * 4 + wid;
    const int b = oi >> 8, o = oi & 255;
    const float* pr = pooled + b * DMODEL;
    const float* wr = w + (size_t)o * DMODEL;
    float s = 0.f;
    for (int d = lane; d < DMODEL; d += 64) s = fmaf(pr[d], wr[d], s);
    #pragma unroll
    for (int off = 1; off < 64; off <<= 1) s += __shfl_xor(s, off);
    if (lane == 0) out[oi] = s + bias[o];
}

// ---------------------------------------------------------------------------
extern "C" void kernel_launch(void* const* d_in, const int* in_sizes, int n_in,
                              void* d_out, int out_size, void* d_ws, size_t ws_size,
                              hipStream_t stream)
{
    const float* x     = (const float*)d_in[0];
    const float* emb_w = (const float*)d_in[1];
    const float* emb_b = (const float*)d_in[2];
    const float* pos   = (const float*)d_in[3];
    const float* wq    = (const float*)d_in[4];
    const float* bq    = (const float*)d_in[5];
    const float* wk    = (const float*)d_in[6];
    const float* bk    = (const float*)d_in[7];
    const float* wv    = (const float*)d_in[8];
    const float* bv    = (const float*)d_in[9];
    const float* wo    = (const float*)d_in[10];
    const float* bo    = (const float*)d_in[11];
    const float* ln1g  = (const float*)d_in[12];
    const float* ln1b  = (const float*)d_in[13];
    const float* fc1w  = (const float*)d_in[14];
    const float* fc1b  = (const float*)d_in[15];
    const float* fc2w  = (const float*)d_in[16];
    const float* fc2b  = (const float*)d_in[17];
    const float* ln2g  = (const float*)d_in[18];
    const float* ln2b  = (const float*)d_in[19];
    const float* fng   = (const float*)d_in[20];
    const float* fnb   = (const float*)d_in[21];
    const float* clsw  = (const float*)d_in[22];
    const float* clsb  = (const float*)d_in[23];

    float* ws = (float*)d_ws;
    const size_t SZ  = (size_t)MROWS * DMODEL;   // 2,097,152 floats
    const size_t HP  = SZ / 2;
    float*     h     = ws;
    float*     t1    = ws + 1*SZ;
    _Float16*  hH    = (_Float16*)(ws + 2*SZ);
    _Float16*  hL    = (_Float16*)(ws + 2*SZ + HP);
    _Float16*  aoH   = (_Float16*)(ws + 3*SZ);
    _Float16*  aoL   = (_Float16*)(ws + 3*SZ + HP);
    _Float16*  qbH   = (_Float16*)(ws + 4*SZ);
    _Float16*  qbL   = (_Float16*)(ws + 4*SZ + HP);
    _Float16*  kbH   = (_Float16*)(ws + 5*SZ);
    _Float16*  kbL   = (_Float16*)(ws + 5*SZ + HP);
    float*     vbuf  = ws + 6*SZ;
    _Float16*  WcatH = (_Float16*)(ws + 7*SZ);
    _Float16*  WcatL = (_Float16*)(ws + 7*SZ + 393216);
    _Float16*  WoH   = (_Float16*)(ws + 7*SZ + 786432);
    _Float16*  WoL   = (_Float16*)(ws + 7*SZ + 917504);
    _Float16*  W1H   = (_Float16*)(ws + 7*SZ + 1048576);
    _Float16*  W1L   = (_Float16*)(ws + 7*SZ + 1572864);
    _Float16*  W2H   = (_Float16*)(ws + 7*SZ + 2097152);
    _Float16*  W2L   = (_Float16*)(ws + 7*SZ + 2621440);
    float*     bcat  = ws + 7*SZ + 3145728;
    float*     pooled= ws + 7*SZ + 3145728 + 1536;
    float*     part  = ws + 7*SZ + 3145728 + 1536 + 1024;
    _Float16*  hid   = (_Float16*)(ws + 4*SZ);   // aliases q/k planes (dead then)
    const size_t needed = (7*SZ + 3145728 + 1536 + 1024 + 16384) * sizeof(float);
    if (ws_size < needed) return;

    dim3 blk(256);

    gemm_k<64,1><<<dim3(DMODEL/64, MROWS/128), blk, 0, stream>>>(
        x, emb_w, emb_b, pos, h, MROWS, DMODEL, 128);
    cvtw_k<<<dim3((int)(SZ/256)), blk, 0, stream>>>(h, hH, hL, (int)SZ, 16.f);

    for (int l = 0; l < NLAYER; ++l) {
        const float* wq_l = wq + (size_t)l*DMODEL*DMODEL;
        const float* bq_l = bq + (size_t)l*DMODEL;
        const float* wk_l = wk + (size_t)l*DMODEL*DMODEL;
        const float* bk_l = bk + (size_t)l*DMODEL;
        const float* wv_l = wv + (size_t)l*DMODEL*DMODEL;
        const float* bv_l = bv + (size_t)l*DMODEL;
        const float* wo_l = wo + (size_t)l*DMODEL*DMODEL;
        const float* bo_l = bo + (size_t)l*DMODEL;
        const float* f1w_l = fc1w + (size_t)l*FDIM*DMODEL;
        const float* f1b_l = fc1b + (size_t)l*FDIM;
        const float* f2w_l = fc2w + (size_t)l*DMODEL*FDIM;
        const float* f2b_l = fc2b + (size_t)l*DMODEL;

        // all weight conversions for this layer in one launch
        cvtlayer_k<<<dim3(12294), blk, 0, stream>>>(
            wq_l, wk_l, wv_l, bq_l, bk_l, bv_l, wo_l, f1w_l, f2w_l,
            WcatH, WcatL, bcat, WoH, WoL, W1H, W1L, W2H, W2L);

        // fused QKV (BM=64,BN=128 -> 768 blocks = 256 CU x 3)
        mgemm_k<64,128,0,0,2><<<dim3(12, 64), blk, 0, stream>>>(
            hH, hL, WcatH, WcatL, bcat,
            (float*)qbH, (float*)qbL, (float*)kbH, (float*)kbL, vbuf,
            MROWS, 1536, DMODEL);

        attn_k<<<dim3(T_SEQ/64, NB*NHEAD), dim3(512), 0, stream>>>(
            qbH, qbL, kbH, kbL, vbuf, aoH, aoL);

        // o-proj + spike (BM=64,BN=64 -> 512 blocks = 2/CU)
        mgemm_k<64,64,0,2,0><<<dim3(8, 64), blk, 0, stream>>>(
            aoH, aoL, WoH, WoL, bo_l, t1, nullptr, nullptr, nullptr, nullptr,
            MROWS, DMODEL, DMODEL);
        ln_k<<<dim3(MROWS), blk, 0, stream>>>(h, t1, ln1g + (size_t)l*DMODEL,
                                              ln1b + (size_t)l*DMODEL, h, hH, hL);

        // FFN: fc1 (BM=128,BN=128, 512 blocks); fc2 (BM=64,BN=64, 512 blocks)
        mgemm_k<128,128,0,3,0><<<dim3(16, 32), blk, 0, stream>>>(
            hH, hL, W1H, W1L, f1b_l, (float*)hid, nullptr, nullptr, nullptr, nullptr,
            MROWS, FDIM, DMODEL);
        mgemm_k<64,64,1,2,0><<<dim3(8, 64), blk, 0, stream>>>(
            hid, nullptr, W2H, W2L, f2b_l, t1, nullptr, nullptr, nullptr, nullptr,
            MROWS, DMODEL, FDIM);
        ln_k<<<dim3(MROWS), blk, 0, stream>>>(h, t1, ln2g + (size_t)l*DMODEL,
                                              ln2b + (size_t)l*DMODEL, h, hH, hL);
    }

    ln_k<<<dim3(MROWS), blk, 0, stream>>>(h, nullptr, fng, fnb, h, hH, hL);
    pool_k<<<dim3(64), blk, 0, stream>>>(h, part);
    poolsum_k<<<dim3(4), blk, 0, stream>>>(part, pooled);
    cls_k<<<dim3(128), blk, 0, stream>>>(pooled, clsw, clsb, (float*)d_out);
}

// Round 6
// 1133.141 us; speedup vs baseline: 1.0269x; 1.0165x over previous
//
#include <hip/hip_runtime.h>
#include <math.h>
#include <float.h>

#define T_SEQ  2048
#define DMODEL 512
#define NHEAD  8
#define DHEAD  64
#define FDIM   2048
#define NLAYER 4
#define NB     2
#define MROWS  (NB*T_SEQ)   // 4096

typedef _Float16 f16x8 __attribute__((ext_vector_type(8)));
typedef float    f32x4 __attribute__((ext_vector_type(4)));

// async 16B global -> LDS (wave-uniform LDS base, lane x 16B dest)
__device__ __forceinline__ void async16(const _Float16* g, _Float16* l) {
    __builtin_amdgcn_global_load_lds(
        (const __attribute__((address_space(1))) unsigned int*)g,
        (__attribute__((address_space(3))) unsigned int*)l, 16, 0, 0);
}

// ---------------------------------------------------------------------------
// fp32 vector GEMM — embedding only (K=128)
// ---------------------------------------------------------------------------
template<int BN, int EPI>
__global__ __launch_bounds__(256) void gemm_k(
    const float* __restrict__ A, const float* __restrict__ W,
    const float* __restrict__ bias, const float* __restrict__ pos,
    float* __restrict__ C, int M, int N, int K)
{
    constexpr int BM = 128;
    constexpr int BK = 32;
    constexpr int MN = BN / 16;
    __shared__ float As[BK][BM + 4];
    __shared__ float Ws[BK][BN + 4];
    const int tid = threadIdx.x;
    const int n0 = blockIdx.x * BN;
    const int m0 = blockIdx.y * BM;
    const int tx = tid & 15;
    const int ty = tid >> 4;

    float acc[8][MN];
    #pragma unroll
    for (int i = 0; i < 8; ++i)
        #pragma unroll
        for (int j = 0; j < MN; ++j) acc[i][j] = 0.f;

    for (int k0 = 0; k0 < K; k0 += BK) {
        #pragma unroll
        for (int it = 0; it < 4; ++it) {
            int qq = tid + 256 * it;
            int m = qq >> 3, kq = qq & 7;
            float4 v4 = *(const float4*)(A + (size_t)(m0 + m) * K + k0 + kq * 4);
            As[kq*4+0][m] = v4.x; As[kq*4+1][m] = v4.y;
            As[kq*4+2][m] = v4.z; As[kq*4+3][m] = v4.w;
        }
        #pragma unroll
        for (int it = 0; it < BN/32; ++it) {
            int qq = tid + 256 * it;
            int n = qq >> 3, kq = qq & 7;
            float4 v4 = *(const float4*)(W + (size_t)(n0 + n) * K + k0 + kq * 4);
            Ws[kq*4+0][n] = v4.x; Ws[kq*4+1][n] = v4.y;
            Ws[kq*4+2][n] = v4.z; Ws[kq*4+3][n] = v4.w;
        }
        __syncthreads();
        for (int kk = 0; kk < BK; ++kk) {
            float a[8], b[MN];
            float4 a0 = *(const float4*)&As[kk][ty*8];
            float4 a1 = *(const float4*)&As[kk][ty*8+4];
            a[0]=a0.x; a[1]=a0.y; a[2]=a0.z; a[3]=a0.w;
            a[4]=a1.x; a[5]=a1.y; a[6]=a1.z; a[7]=a1.w;
            float4 b0 = *(const float4*)&Ws[kk][tx*4];
            b[0]=b0.x; b[1]=b0.y; b[2]=b0.z; b[3]=b0.w;
            if constexpr (MN == 8) {
                float4 b1 = *(const float4*)&Ws[kk][64 + tx*4];
                b[4]=b1.x; b[5]=b1.y; b[6]=b1.z; b[7]=b1.w;
            }
            #pragma unroll
            for (int i = 0; i < 8; ++i)
                #pragma unroll
                for (int j = 0; j < MN; ++j)
                    acc[i][j] = fmaf(a[i], b[j], acc[i][j]);
        }
        __syncthreads();
    }

    #pragma unroll
    for (int i = 0; i < 8; ++i) {
        int m = m0 + ty*8 + i;
        #pragma unroll
        for (int jb = 0; jb < MN/4; ++jb) {
            int nn = n0 + jb*64 + tx*4;
            float4 r;
            r.x = acc[i][jb*4+0] + bias[nn+0];
            r.y = acc[i][jb*4+1] + bias[nn+1];
            r.z = acc[i][jb*4+2] + bias[nn+2];
            r.w = acc[i][jb*4+3] + bias[nn+3];
            if constexpr (EPI == 1) {
                const float* pp = pos + (size_t)(m & (T_SEQ-1)) * DMODEL + nn;
                r.x += pp[0]; r.y += pp[1]; r.z += pp[2]; r.w += pp[3];
            }
            *(float4*)(C + (size_t)m * N + nn) = r;
        }
    }
}

// ---------------------------------------------------------------------------
// f16-split MFMA GEMM: C = (1/1024)·A'[M,K]·W'[N,K]^T + bias
// v2: LDS double-buffer, ONE barrier per K-step, register prefetch.
// Old loop was {gload->reg, ds_write, barrier, ds_read, MFMA, barrier}:
// ~300-500cy global latency fully exposed between barriers (~400 TF eff).
// New loop: issue gload(t+1) -> ds_read buf[cur] -> MFMA -> ds_write regs
// -> buf[cur^1] -> barrier. Latency hides under ds_read+MFMA; barriers halve.
// LDS doubles but occupancy unchanged at all instantiations:
//  QKV 48KBx3=144, fc1 64KBx2=128, o-proj 32KBx3=96, fc2 24KBx3=72 (<=160).
// ASRC: 0 = dual-plane A; 1 = single-plane A (exact spikes; AsL elided)
// EPI:  0 = fp32; 2 = spike->fp32; 3 = spike->f16 plane (x16)
// LAYOUT: 0 = [M,N]; 2 = fused QKV (q,k f16 planes head layout; v fp32)
// ---------------------------------------------------------------------------
template<int BM, int BN, int ASRC, int EPI, int LAYOUT>
__global__ __launch_bounds__(256, (BM == 64) ? 3 : 2) void mgemm_k(
    const _Float16* __restrict__ AH, const _Float16* __restrict__ AL,
    const _Float16* __restrict__ WH, const _Float16* __restrict__ WL,
    const float* __restrict__ bias,
    float* __restrict__ O0, float* __restrict__ O1, float* __restrict__ O2,
    float* __restrict__ O3, float* __restrict__ O4,
    int M, int N, int K)
{
    constexpr int MI = BM / 32;
    constexpr int NJ = BN / 32;
    __shared__ _Float16 AsH[2][4][BM][8];
    __shared__ _Float16 AsL[(ASRC == 0) ? 2 : 1][(ASRC == 0) ? 4 : 1][(ASRC == 0) ? BM : 1][8];
    __shared__ _Float16 WsH[2][4][BN][8];
    __shared__ _Float16 WsL[2][4][BN][8];

    const int tid = threadIdx.x;
    const int n0 = blockIdx.x * BN;
    const int m0 = blockIdx.y * BM;
    const int wv = tid >> 6, lane = tid & 63;
    const int mw = (wv >> 1) * (BM/2), nw = (wv & 1) * (BN/2);
    const int fr = lane & 15;
    const int kb = lane >> 4;

    const int wsrow = tid >> 1;          // BM/BN==128 staging row
    const int wskb  = (tid & 1) * 2;
    const int wkoff = (tid & 1) * 16;
    const int arow  = tid >> 2, akb = tid & 3;   // 64-row staging

    // register prefetch holders
    f16x8 pa0, pa1, pal0, pal1, pw0, pw1, pwl0, pwl1;

    auto gload = [&](int k0) {
        if constexpr (BM == 128) {
            const _Float16* ap = AH + (size_t)(m0 + wsrow) * K + k0 + wkoff;
            pa0 = *(const f16x8*)ap;
            pa1 = *(const f16x8*)(ap + 8);
            if constexpr (ASRC == 0) {
                const _Float16* alp = AL + (size_t)(m0 + wsrow) * K + k0 + wkoff;
                pal0 = *(const f16x8*)alp;
                pal1 = *(const f16x8*)(alp + 8);
            }
        } else {
            pa0 = *(const f16x8*)(AH + (size_t)(m0 + arow) * K + k0 + akb*8);
            if constexpr (ASRC == 0)
                pal0 = *(const f16x8*)(AL + (size_t)(m0 + arow) * K + k0 + akb*8);
        }
        if constexpr (BN == 128) {
            const _Float16* wp = WH + (size_t)(n0 + wsrow) * K + k0 + wkoff;
            pw0 = *(const f16x8*)wp;
            pw1 = *(const f16x8*)(wp + 8);
            const _Float16* wlp = WL + (size_t)(n0 + wsrow) * K + k0 + wkoff;
            pwl0 = *(const f16x8*)wlp;
            pwl1 = *(const f16x8*)(wlp + 8);
        } else {
            pw0  = *(const f16x8*)(WH + (size_t)(n0 + arow) * K + k0 + akb*8);
            pwl0 = *(const f16x8*)(WL + (size_t)(n0 + arow) * K + k0 + akb*8);
        }
    };
    auto swrite = [&](int buf) {
        if constexpr (BM == 128) {
            *(f16x8*)&AsH[buf][wskb  ][wsrow][0] = pa0;
            *(f16x8*)&AsH[buf][wskb+1][wsrow][0] = pa1;
            if constexpr (ASRC == 0) {
                *(f16x8*)&AsL[buf][wskb  ][wsrow][0] = pal0;
                *(f16x8*)&AsL[buf][wskb+1][wsrow][0] = pal1;
            }
        } else {
            *(f16x8*)&AsH[buf][akb][arow][0] = pa0;
            if constexpr (ASRC == 0)
                *(f16x8*)&AsL[buf][akb][arow][0] = pal0;
        }
        if constexpr (BN == 128) {
            *(f16x8*)&WsH[buf][wskb  ][wsrow][0] = pw0;
            *(f16x8*)&WsH[buf][wskb+1][wsrow][0] = pw1;
            *(f16x8*)&WsL[buf][wskb  ][wsrow][0] = pwl0;
            *(f16x8*)&WsL[buf][wskb+1][wsrow][0] = pwl1;
        } else {
            *(f16x8*)&WsH[buf][akb][arow][0] = pw0;
            *(f16x8*)&WsL[buf][akb][arow][0] = pwl0;
        }
    };

    f32x4 acc[MI][NJ];
    #pragma unroll
    for (int i = 0; i < MI; ++i)
        #pragma unroll
        for (int j = 0; j < NJ; ++j) acc[i][j] = (f32x4)(0.f);

    const int NT = K >> 5;
    int cur = 0;
    gload(0);
    swrite(0);
    __syncthreads();

    for (int t = 0; t < NT; ++t) {
        const bool more = (t + 1 < NT);
        if (more) gload((t + 1) << 5);   // issue next tile early (latency hides)

        f16x8 aH[MI], aL[MI], bH[NJ], bL[NJ];
        #pragma unroll
        for (int i = 0; i < MI; ++i) {
            aH[i] = *(const f16x8*)&AsH[cur][kb][mw + i*16 + fr][0];
            if constexpr (ASRC == 0) aL[i] = *(const f16x8*)&AsL[cur][kb][mw + i*16 + fr][0];
        }
        #pragma unroll
        for (int j = 0; j < NJ; ++j) {
            bH[j] = *(const f16x8*)&WsH[cur][kb][nw + j*16 + fr][0];
            bL[j] = *(const f16x8*)&WsL[cur][kb][nw + j*16 + fr][0];
        }
        #pragma unroll
        for (int i = 0; i < MI; ++i)
            #pragma unroll
            for (int j = 0; j < NJ; ++j) {
                acc[i][j] = __builtin_amdgcn_mfma_f32_16x16x32_f16(aH[i], bH[j], acc[i][j], 0, 0, 0);
                acc[i][j] = __builtin_amdgcn_mfma_f32_16x16x32_f16(aH[i], bL[j], acc[i][j], 0, 0, 0);
                if constexpr (ASRC == 0)
                    acc[i][j] = __builtin_amdgcn_mfma_f32_16x16x32_f16(aL[i], bH[j], acc[i][j], 0, 0, 0);
            }
        if (more) {
            swrite(cur ^ 1);             // write-late: after reads of buf[cur]
            __syncthreads();             // ONE barrier per K-step
            cur ^= 1;
        }
    }

    const int qq = lane >> 4;
    #pragma unroll
    for (int j = 0; j < NJ; ++j) {
        int n = n0 + nw + j*16 + fr;
        float bv = bias[n];
        #pragma unroll
        for (int i = 0; i < MI; ++i) {
            #pragma unroll
            for (int r = 0; r < 4; ++r) {
                int m = m0 + mw + i*16 + qq*4 + r;
                float val = acc[i][j][r] * (1.f/1024.f) + bv;
                if constexpr (EPI == 2) val = val > 0.5f ? 1.f : 0.f;
                if constexpr (EPI == 3) {
                    ((_Float16*)O0)[(size_t)m * N + n] = (val > 0.5f) ? (_Float16)16.f : (_Float16)0.f;
                } else if constexpr (LAYOUT == 0) {
                    O0[(size_t)m * N + n] = val;
                } else {
                    int b_ = m >> 11, t_ = m & (T_SEQ-1);
                    if (n < 512) {
                        size_t hl = (((size_t)(b_*NHEAD + (n>>6))*T_SEQ + t_) << 6) + (n & 63);
                        float s16 = 16.f * val;
                        _Float16 hh = (_Float16)s16;
                        ((_Float16*)O0)[hl] = hh;
                        ((_Float16*)O1)[hl] = (_Float16)(s16 - (float)hh);
                    } else if (n < 1024) {
                        int nn = n - 512;
                        size_t hl = (((size_t)(b_*NHEAD + (nn>>6))*T_SEQ + t_) << 6) + (nn & 63);
                        float s16 = 16.f * val;
                        _Float16 hh = (_Float16)s16;
                        ((_Float16*)O2)[hl] = hh;
                        ((_Float16*)O3)[hl] = (_Float16)(s16 - (float)hh);
                    } else {
                        int nn = n - 1024;
                        O4[(((size_t)(b_*NHEAD + (nn>>6))*T_SEQ + t_) << 6) + (nn & 63)] = val;
                    }
                }
            }
        }
    }
}

// ---------------------------------------------------------------------------
// h-split (embedding output -> x16 planes)
// ---------------------------------------------------------------------------
__global__ __launch_bounds__(256) void cvtw_k(
    const float* __restrict__ w, _Float16* __restrict__ H, _Float16* __restrict__ L,
    int n, float scale)
{
    int i = blockIdx.x * 256 + threadIdx.x;
    if (i < n) {
        float s = scale * w[i];
        _Float16 h = (_Float16)s;
        H[i] = h;
        L[i] = (_Float16)(s - (float)h);
    }
}

// all of one layer's weight conversions fused (x64 split), one launch
__global__ __launch_bounds__(256) void cvtlayer_k(
    const float* __restrict__ wq, const float* __restrict__ wk, const float* __restrict__ wv,
    const float* __restrict__ bq, const float* __restrict__ bk, const float* __restrict__ bv,
    const float* __restrict__ wo, const float* __restrict__ f1w, const float* __restrict__ f2w,
    _Float16* __restrict__ WcatH, _Float16* __restrict__ WcatL, float* __restrict__ bcat,
    _Float16* __restrict__ WoH, _Float16* __restrict__ WoL,
    _Float16* __restrict__ W1H, _Float16* __restrict__ W1L,
    _Float16* __restrict__ W2H, _Float16* __restrict__ W2L)
{
    int i = blockIdx.x * 256 + threadIdx.x;
    float w;
    _Float16 *H, *L;
    int off;
    if (i < 786432) {
        int src = i >> 18, o = i & 262143;
        w = (src == 0 ? wq : (src == 1 ? wk : wv))[o];
        H = WcatH; L = WcatL; off = i;
    } else if (i < 1048576) {
        off = i - 786432;  w = wo[off];  H = WoH; L = WoL;
    } else if (i < 2097152) {
        off = i - 1048576; w = f1w[off]; H = W1H; L = W1L;
    } else if (i < 3145728) {
        off = i - 2097152; w = f2w[off]; H = W2H; L = W2L;
    } else if (i < 3145728 + 1536) {
        int j = i - 3145728;
        int src = j >> 9, o = j & 511;
        bcat[j] = (src == 0 ? bq : (src == 1 ? bk : bv))[o];
        return;
    } else return;
    float s = 64.f * w;
    _Float16 h = (_Float16)s;
    H[off] = h;
    L[off] = (_Float16)(s - (float)h);
}

// ---------------------------------------------------------------------------
// Fused sparse attention v9 — 512 thr / 64 q-rows, 512 blocks = 2/CU exactly;
// ss[64][132] padded; sort-16 CE as explicit min/max; Q in registers;
// async K staging; __expf softmax.
// ---------------------------------------------------------------------------
__global__ __launch_bounds__(512, 4) void attn_k(
    const _Float16* __restrict__ qH, const _Float16* __restrict__ qL,
    const _Float16* __restrict__ kH, const _Float16* __restrict__ kL,
    const float* __restrict__ v,
    _Float16* __restrict__ outH, _Float16* __restrict__ outL)
{
    // ksH [128*64] @0 (16384) | ksL @16384 | ss[64][132] f32 @32768 (33792)
    // -> total 66560; wrow/irow alias ss
    __shared__ unsigned char lds[66560];
    _Float16* ksH = (_Float16*)(lds);
    _Float16* ksL = (_Float16*)(lds + 16384);
    float    (*ss)[132] = (float(*)[132])(lds + 32768);
    float*   wrow       = (float*)(lds + 32768);
    int*     irow       = (int*)(lds + 32768 + 8448);

    const int tid = threadIdx.x;
    const int bh  = blockIdx.y;
    const int t0  = blockIdx.x * 64;
    const _Float16* qHb = qH + ((size_t)bh * T_SEQ + t0) * DHEAD;
    const _Float16* qLb = qL + ((size_t)bh * T_SEQ + t0) * DHEAD;
    const _Float16* kHb = kH + (size_t)bh * T_SEQ * DHEAD;
    const _Float16* kLb = kL + (size_t)bh * T_SEQ * DHEAD;
    const float*    vb  = v  + (size_t)bh * T_SEQ * DHEAD;

    unsigned kreg[32];
    #pragma unroll
    for (int i = 0; i < 32; ++i) kreg[i] = 0u;

    const int wv = tid >> 6, lane = tid & 63;
    const int fr = lane & 15, q4 = lane >> 4;
    const int mh  = (wv >> 2) * 32;      // q-row half owned by this wave
    const int c0w = (wv & 3) * 32;       // col strip owned by this wave
    const int srow = tid >> 3;           // 0..63
    const int ssub = tid & 7;

    // Q fragments in registers: loop-invariant across all K tiles.
    // [ks][mi]: row = mh + mi*16 + fr; doff = ks*32 + q4*8
    f16x8 qaH[2][2], qaL[2][2];
    #pragma unroll
    for (int ks = 0; ks < 2; ++ks) {
        const int doff = ks*32 + q4*8;
        qaH[ks][0] = *(const f16x8*)(qHb + (mh + fr)*DHEAD + doff);
        qaH[ks][1] = *(const f16x8*)(qHb + (mh + 16 + fr)*DHEAD + doff);
        qaL[ks][0] = *(const f16x8*)(qLb + (mh + fr)*DHEAD + doff);
        qaL[ks][1] = *(const f16x8*)(qLb + (mh + 16 + fr)*DHEAD + doff);
    }

    // async stage of one K tile: 8 waves x 16 rows -> 2 instrs/plane/wave
    auto stage = [&](int jt) {
        const int j0 = jt * 128;
        #pragma unroll
        for (int i = 0; i < 2; ++i) {
            const int r0 = wv*16 + i*8;                 // wave-uniform
            const int cc = r0 + (lane >> 3);
            const int ch = (lane & 7) ^ (cc & 7);       // swizzled source chunk
            const size_t goff = (size_t)(j0 + cc) * DHEAD + ch*8;
            async16(kHb + goff, ksH + r0*64);
            async16(kLb + goff, ksL + r0*64);
        }
    };

    stage(0);
    __syncthreads();                     // ks(0) ready (drains vmcnt)

    for (int jt = 0; jt < 16; ++jt) {
        const int j0 = jt * 128;

        // QK^T: 2 m-frags x 2 n-frags x 2 k-steps x 3 split passes
        f32x4 acc[2][2];
        acc[0][0] = (f32x4)(0.f); acc[0][1] = (f32x4)(0.f);
        acc[1][0] = (f32x4)(0.f); acc[1][1] = (f32x4)(0.f);
        #pragma unroll
        for (int ks = 0; ks < 2; ++ks) {
            const int chq  = ks*4 + q4;                 // chunk index of doff
            #pragma unroll
            for (int nj = 0; nj < 2; ++nj) {
                const int cc = c0w + nj*16 + fr;
                const int sl = cc*64 + (chq ^ (cc & 7))*8;
                f16x8 bHf = *(const f16x8*)&ksH[sl];
                f16x8 bLf = *(const f16x8*)&ksL[sl];
                acc[0][nj] = __builtin_amdgcn_mfma_f32_16x16x32_f16(qaH[ks][0], bHf, acc[0][nj], 0, 0, 0);
                acc[0][nj] = __builtin_amdgcn_mfma_f32_16x16x32_f16(qaH[ks][0], bLf, acc[0][nj], 0, 0, 0);
                acc[0][nj] = __builtin_amdgcn_mfma_f32_16x16x32_f16(qaL[ks][0], bHf, acc[0][nj], 0, 0, 0);
                acc[1][nj] = __builtin_amdgcn_mfma_f32_16x16x32_f16(qaH[ks][1], bHf, acc[1][nj], 0, 0, 0);
                acc[1][nj] = __builtin_amdgcn_mfma_f32_16x16x32_f16(qaH[ks][1], bLf, acc[1][nj], 0, 0, 0);
                acc[1][nj] = __builtin_amdgcn_mfma_f32_16x16x32_f16(qaL[ks][1], bHf, acc[1][nj], 0, 0, 0);
            }
        }
        // scores to LDS (row = mh + mi*16 + q4*4 + r, col = c0w + nj*16 + fr)
        #pragma unroll
        for (int mi = 0; mi < 2; ++mi)
            #pragma unroll
            for (int nj = 0; nj < 2; ++nj)
                #pragma unroll
                for (int r = 0; r < 4; ++r)
                    ss[mh + mi*16 + q4*4 + r][c0w + nj*16 + fr] = acc[mi][nj][r] * (1.f/2048.f);
        __syncthreads();                 // C: ss visible; all ks reads done

        if (jt < 15) stage(jt + 1);      // async; hides under select

        // branch-free select: 16 candidates / thread, u32 packed keys
        float4 c4[4];
        {
            const float* ssr = &ss[srow][0] + ssub*4;
            #pragma unroll
            for (int g = 0; g < 4; ++g) c4[g] = *(const float4*)(ssr + g*32);
        }
        unsigned cand[16];
        #pragma unroll
        for (int g = 0; g < 4; ++g) {
            float vg[4] = {c4[g].x, c4[g].y, c4[g].z, c4[g].w};
            #pragma unroll
            for (int r = 0; r < 4; ++r) {
                unsigned u = __float_as_uint(vg[r]);
                u ^= (unsigned)((int)u >> 31) | 0x80000000u;
                int col = ssub*4 + g*32 + r;
                cand[g*4+r] = (u & 0xFFFFF800u) | (unsigned)(2047 - (j0 + col));
            }
        }
        // bitonic sort-16 descending; CE as explicit min/max (v_min/max_u32)
        #pragma unroll
        for (int k2 = 2; k2 <= 16; k2 <<= 1) {
            #pragma unroll
            for (int j2 = k2 >> 1; j2 > 0; j2 >>= 1) {
                #pragma unroll
                for (int i2 = 0; i2 < 16; ++i2) {
                    int l2 = i2 ^ j2;
                    if (l2 > i2) {
                        unsigned a = cand[i2], b = cand[l2];
                        unsigned mn = a < b ? a : b;
                        unsigned mx = a < b ? b : a;
                        if ((i2 & k2) == 0) { cand[i2] = mx; cand[l2] = mn; }
                        else                { cand[i2] = mn; cand[l2] = mx; }
                    }
                }
            }
        }
        #pragma unroll
        for (int j2 = 0; j2 < 16; ++j2) {
            unsigned b = cand[15 - j2];
            if (kreg[16 + j2] < b) kreg[16 + j2] = b;
        }
        #pragma unroll
        for (int st = 16; st >= 1; st >>= 1) {
            #pragma unroll
            for (int i2 = 0; i2 < 32; ++i2) {
                if ((i2 & st) == 0) {
                    unsigned lo = kreg[i2], hi = kreg[i2 | st];
                    kreg[i2]      = lo < hi ? hi : lo;
                    kreg[i2 | st] = lo < hi ? lo : hi;
                }
            }
        }
        __syncthreads();                 // A: ks(t+1) ready; ss reads done
    }

    // merge 8 per-sub lists (lane^1,2,4)
    #pragma unroll
    for (int s = 1; s <= 4; s <<= 1) {
        #pragma unroll
        for (int i = 0; i < 16; ++i) {
            unsigned pa = (unsigned)__shfl_xor((int)kreg[31-i], s, 64);
            unsigned pb = (unsigned)__shfl_xor((int)kreg[i],    s, 64);
            if (pa > kreg[i])    kreg[i]    = pa;
            if (pb > kreg[31-i]) kreg[31-i] = pb;
        }
        #pragma unroll
        for (int st = 16; st >= 1; st >>= 1) {
            #pragma unroll
            for (int i2 = 0; i2 < 32; ++i2) {
                if ((i2 & st) == 0) {
                    unsigned lo = kreg[i2], hi = kreg[i2 | st];
                    kreg[i2]      = lo < hi ? hi : lo;
                    kreg[i2 | st] = lo < hi ? lo : hi;
                }
            }
        }
    }

    // softmax over kept 32
    if (ssub == 0) {
        float w[32];
        #pragma unroll
        for (int i = 0; i < 32; ++i) {
            unsigned um = kreg[i] & 0xFFFFF800u;
            unsigned ub = (um & 0x80000000u) ? (um ^ 0x80000000u) : ~um;
            w[i] = __uint_as_float(ub);
        }
        float m = w[0];
        float s = 0.f;
        #pragma unroll
        for (int i = 0; i < 32; ++i) { w[i] = __expf(w[i] - m); s += w[i]; }
        float inv = 1.f / s;
        #pragma unroll
        for (int i = 0; i < 32; ++i) {
            wrow[srow*33 + i] = w[i] * inv;
            irow[srow*33 + i] = 2047 - (int)(kreg[i] & 0x7FFu);
        }
    }
    __syncthreads();

    // AV: wave per row-group, lane = head dim; 4 partial accumulators
    const int wid = tid >> 6, lane2 = tid & 63;
    const int b = bh >> 3, h = bh & 7;
    for (int rr = wid; rr < 64; rr += 8) {
        float a0 = 0.f, a1 = 0.f, a2 = 0.f, a3 = 0.f;
        #pragma unroll
        for (int i = 0; i < 8; ++i) {
            a0 = fmaf(wrow[rr*33 + i],      vb[(size_t)irow[rr*33 + i]      * DHEAD + lane2], a0);
            a1 = fmaf(wrow[rr*33 + 8 + i],  vb[(size_t)irow[rr*33 + 8 + i]  * DHEAD + lane2], a1);
            a2 = fmaf(wrow[rr*33 + 16 + i], vb[(size_t)irow[rr*33 + 16 + i] * DHEAD + lane2], a2);
            a3 = fmaf(wrow[rr*33 + 24 + i], vb[(size_t)irow[rr*33 + 24 + i] * DHEAD + lane2], a3);
        }
        float accv = (a0 + a1) + (a2 + a3);
        size_t oi = ((size_t)(b * T_SEQ + t0 + rr)) * DMODEL + h * DHEAD + lane2;
        float s16 = 16.f * accv;
        _Float16 hh = (_Float16)s16;
        outH[oi] = hh;
        outL[oi] = (_Float16)(s16 - (float)hh);
    }
}

// ---------------------------------------------------------------------------
// LayerNorm (+residual); also emits x16 f16 hi/lo planes of the output
// ---------------------------------------------------------------------------
__global__ __launch_bounds__(256) void ln_k(
    const float* __restrict__ x, const float* __restrict__ res,
    const float* __restrict__ g, const float* __restrict__ bb,
    float* __restrict__ out, _Float16* __restrict__ oH, _Float16* __restrict__ oL)
{
    __shared__ float red[8];
    const int row = blockIdx.x;
    const int tid = threadIdx.x;
    const float* xr = x + (size_t)row * DMODEL;
    float v0 = xr[tid], v1 = xr[tid + 256];
    if (res) {
        const float* rr = res + (size_t)row * DMODEL;
        v0 += rr[tid]; v1 += rr[tid + 256];
    }
    float s = v0 + v1;
    #pragma unroll
    for (int o = 1; o < 64; o <<= 1) s += __shfl_xor(s, o);
    const int wid = tid >> 6, lane = tid & 63;
    if (lane == 0) red[wid] = s;
    __syncthreads();
    float mean = (red[0] + red[1] + red[2] + red[3]) * (1.f / DMODEL);
    float d0 = v0 - mean, d1 = v1 - mean;
    float qs = d0*d0 + d1*d1;
    #pragma unroll
    for (int o = 1; o < 64; o <<= 1) qs += __shfl_xor(qs, o);
    if (lane == 0) red[4 + wid] = qs;
    __syncthreads();
    float var = (red[4] + red[5] + red[6] + red[7]) * (1.f / DMODEL);
    float rs = rsqrtf(var + 1e-5f);
    float o0 = d0 * rs * g[tid]       + bb[tid];
    float o1 = d1 * rs * g[tid + 256] + bb[tid + 256];
    size_t base = (size_t)row * DMODEL;
    out[base + tid]       = o0;
    out[base + tid + 256] = o1;
    float s0 = 16.f * o0, s1 = 16.f * o1;
    _Float16 h0 = (_Float16)s0, h1 = (_Float16)s1;
    oH[base + tid]       = h0;
    oH[base + tid + 256] = h1;
    oL[base + tid]       = (_Float16)(s0 - (float)h0);
    oL[base + tid + 256] = (_Float16)(s1 - (float)h1);
}

// ---------------------------------------------------------------------------
__global__ __launch_bounds__(256) void pool_k(
    const float* __restrict__ h, float* __restrict__ part)
{
    const int chunk = blockIdx.x & 15;
    const int idx = (blockIdx.x >> 4) * 256 + threadIdx.x;
    const int b = idx >> 9, d = idx & 511;
    const float* p = h + ((size_t)b * T_SEQ + chunk * 128) * DMODEL + d;
    float s = 0.f;
    for (int t = 0; t < 128; ++t) s += p[(size_t)t * DMODEL];
    part[chunk * 1024 + idx] = s;
}

__global__ __launch_bounds__(256) void poolsum_k(
    const float* __restrict__ part, float* __restrict__ pooled)
{
    int idx = blockIdx.x * 256 + threadIdx.x;
    float s = 0.f;
    #pragma unroll
    for (int c = 0; c < 16; ++c) s += part[c * 1024 + idx];
    pooled[idx] = s * (1.f / T_SEQ);
}

__global__ __launch_bounds__(256) void cls_k(
    const float* __restrict__ pooled, const float* __restrict__ w,
    const float* __restrict__ bias, float* __restrict__ out)
{
    const int wid = threadIdx.x >> 6, lane = threadIdx.x & 63;
    const int oi = blockIdx.x * 4 + wid;
    const int b = oi >> 8, o = oi & 255;
    const float* pr = pooled + b * DMODEL;
    const float* wr = w + (size_t)o * DMODEL;
    float s = 0.f;
    for (int d = lane; d < DMODEL; d += 64) s = fmaf(pr[d], wr[d], s);
    #pragma unroll
    for (int off = 1; off < 64; off <<= 1) s += __shfl_xor(s, off);
    if (lane == 0) out[oi] = s + bias[o];
}

// ---------------------------------------------------------------------------
extern "C" void kernel_launch(void* const* d_in, const int* in_sizes, int n_in,
                              void* d_out, int out_size, void* d_ws, size_t ws_size,
                              hipStream_t stream)
{
    const float* x     = (const float*)d_in[0];
    const float* emb_w = (const float*)d_in[1];
    const float* emb_b = (const float*)d_in[2];
    const float* pos   = (const float*)d_in[3];
    const float* wq    = (const float*)d_in[4];
    const float* bq    = (const float*)d_in[5];
    const float* wk    = (const float*)d_in[6];
    const float* bk    = (const float*)d_in[7];
    const float* wv    = (const float*)d_in[8];
    const float* bv    = (const float*)d_in[9];
    const float* wo    = (const float*)d_in[10];
    const float* bo    = (const float*)d_in[11];
    const float* ln1g  = (const float*)d_in[12];
    const float* ln1b  = (const float*)d_in[13];
    const float* fc1w  = (const float*)d_in[14];
    const float* fc1b  = (const float*)d_in[15];
    const float* fc2w  = (const float*)d_in[16];
    const float* fc2b  = (const float*)d_in[17];
    const float* ln2g  = (const float*)d_in[18];
    const float* ln2b  = (const float*)d_in[19];
    const float* fng   = (const float*)d_in[20];
    const float* fnb   = (const float*)d_in[21];
    const float* clsw  = (const float*)d_in[22];
    const float* clsb  = (const float*)d_in[23];

    float* ws = (float*)d_ws;
    const size_t SZ  = (size_t)MROWS * DMODEL;   // 2,097,152 floats
    const size_t HP  = SZ / 2;
    float*     h     = ws;
    float*     t1    = ws + 1*SZ;
    _Float16*  hH    = (_Float16*)(ws + 2*SZ);
    _Float16*  hL    = (_Float16*)(ws + 2*SZ + HP);
    _Float16*  aoH   = (_Float16*)(ws + 3*SZ);
    _Float16*  aoL   = (_Float16*)(ws + 3*SZ + HP);
    _Float16*  qbH   = (_Float16*)(ws + 4*SZ);
    _Float16*  qbL   = (_Float16*)(ws + 4*SZ + HP);
    _Float16*  kbH   = (_Float16*)(ws + 5*SZ);
    _Float16*  kbL   = (_Float16*)(ws + 5*SZ + HP);
    float*     vbuf  = ws + 6*SZ;
    _Float16*  WcatH = (_Float16*)(ws + 7*SZ);
    _Float16*  WcatL = (_Float16*)(ws + 7*SZ + 393216);
    _Float16*  WoH   = (_Float16*)(ws + 7*SZ + 786432);
    _Float16*  WoL   = (_Float16*)(ws + 7*SZ + 917504);
    _Float16*  W1H   = (_Float16*)(ws + 7*SZ + 1048576);
    _Float16*  W1L   = (_Float16*)(ws + 7*SZ + 1572864);
    _Float16*  W2H   = (_Float16*)(ws + 7*SZ + 2097152);
    _Float16*  W2L   = (_Float16*)(ws + 7*SZ + 2621440);
    float*     bcat  = ws + 7*SZ + 3145728;
    float*     pooled= ws + 7*SZ + 3145728 + 1536;
    float*     part  = ws + 7*SZ + 3145728 + 1536 + 1024;
    _Float16*  hid   = (_Float16*)(ws + 4*SZ);   // aliases q/k planes (dead then)
    const size_t needed = (7*SZ + 3145728 + 1536 + 1024 + 16384) * sizeof(float);
    if (ws_size < needed) return;

    dim3 blk(256);

    gemm_k<64,1><<<dim3(DMODEL/64, MROWS/128), blk, 0, stream>>>(
        x, emb_w, emb_b, pos, h, MROWS, DMODEL, 128);
    cvtw_k<<<dim3((int)(SZ/256)), blk, 0, stream>>>(h, hH, hL, (int)SZ, 16.f);

    for (int l = 0; l < NLAYER; ++l) {
        const float* wq_l = wq + (size_t)l*DMODEL*DMODEL;
        const float* bq_l = bq + (size_t)l*DMODEL;
        const float* wk_l = wk + (size_t)l*DMODEL*DMODEL;
        const float* bk_l = bk + (size_t)l*DMODEL;
        const float* wv_l = wv + (size_t)l*DMODEL*DMODEL;
        const float* bv_l = bv + (size_t)l*DMODEL;
        const float* wo_l = wo + (size_t)l*DMODEL*DMODEL;
        const float* bo_l = bo + (size_t)l*DMODEL;
        const float* f1w_l = fc1w + (size_t)l*FDIM*DMODEL;
        const float* f1b_l = fc1b + (size_t)l*FDIM;
        const float* f2w_l = fc2w + (size_t)l*DMODEL*FDIM;
        const float* f2b_l = fc2b + (size_t)l*DMODEL;

        // all weight conversions for this layer in one launch
        cvtlayer_k<<<dim3(12294), blk, 0, stream>>>(
            wq_l, wk_l, wv_l, bq_l, bk_l, bv_l, wo_l, f1w_l, f2w_l,
            WcatH, WcatL, bcat, WoH, WoL, W1H, W1L, W2H, W2L);

        // fused QKV (BM=64,BN=128 -> 768 blocks = 256 CU x 3)
        mgemm_k<64,128,0,0,2><<<dim3(12, 64), blk, 0, stream>>>(
            hH, hL, WcatH, WcatL, bcat,
            (float*)qbH, (float*)qbL, (float*)kbH, (float*)kbL, vbuf,
            MROWS, 1536, DMODEL);

        attn_k<<<dim3(T_SEQ/64, NB*NHEAD), dim3(512), 0, stream>>>(
            qbH, qbL, kbH, kbL, vbuf, aoH, aoL);

        // o-proj + spike (BM=64,BN=64 -> 512 blocks = 2/CU)
        mgemm_k<64,64,0,2,0><<<dim3(8, 64), blk, 0, stream>>>(
            aoH, aoL, WoH, WoL, bo_l, t1, nullptr, nullptr, nullptr, nullptr,
            MROWS, DMODEL, DMODEL);
        ln_k<<<dim3(MROWS), blk, 0, stream>>>(h, t1, ln1g + (size_t)l*DMODEL,
                                              ln1b + (size_t)l*DMODEL, h, hH, hL);

        // FFN: fc1 (BM=128,BN=128, 512 blocks); fc2 (BM=64,BN=64, 512 blocks)
        mgemm_k<128,128,0,3,0><<<dim3(16, 32), blk, 0, stream>>>(
            hH, hL, W1H, W1L, f1b_l, (float*)hid, nullptr, nullptr, nullptr, nullptr,
            MROWS, FDIM, DMODEL);
        mgemm_k<64,64,1,2,0><<<dim3(8, 64), blk, 0, stream>>>(
            hid, nullptr, W2H, W2L, f2b_l, t1, nullptr, nullptr, nullptr, nullptr,
            MROWS, DMODEL, FDIM);
        ln_k<<<dim3(MROWS), blk, 0, stream>>>(h, t1, ln2g + (size_t)l*DMODEL,
                                              ln2b + (size_t)l*DMODEL, h, hH, hL);
    }

    ln_k<<<dim3(MROWS), blk, 0, stream>>>(h, nullptr, fng, fnb, h, hH, hL);
    pool_k<<<dim3(64), blk, 0, stream>>>(h, part);
    poolsum_k<<<dim3(4), blk, 0, stream>>>(part, pooled);
    cls_k<<<dim3(128), blk, 0, stream>>>(pooled, clsw, clsb, (float*)d_out);
}

// Round 7
// 1117.514 us; speedup vs baseline: 1.0412x; 1.0140x over previous
//
#include <hip/hip_runtime.h>
#include <math.h>
#include <float.h>

#define T_SEQ  2048
#define DMODEL 512
#define NHEAD  8
#define DHEAD  64
#define FDIM   2048
#define NLAYER 4
#define NB     2
#define MROWS  (NB*T_SEQ)   // 4096

typedef _Float16 f16x8 __attribute__((ext_vector_type(8)));
typedef float    f32x4 __attribute__((ext_vector_type(4)));

// async 16B global -> LDS (wave-uniform LDS base, lane x 16B dest)
__device__ __forceinline__ void async16(const _Float16* g, _Float16* l) {
    __builtin_amdgcn_global_load_lds(
        (const __attribute__((address_space(1))) unsigned int*)g,
        (__attribute__((address_space(3))) unsigned int*)l, 16, 0, 0);
}

// ---------------------------------------------------------------------------
// fp32 vector GEMM — embedding only (K=128)
// ---------------------------------------------------------------------------
template<int BN, int EPI>
__global__ __launch_bounds__(256) void gemm_k(
    const float* __restrict__ A, const float* __restrict__ W,
    const float* __restrict__ bias, const float* __restrict__ pos,
    float* __restrict__ C, int M, int N, int K)
{
    constexpr int BM = 128;
    constexpr int BK = 32;
    constexpr int MN = BN / 16;
    __shared__ float As[BK][BM + 4];
    __shared__ float Ws[BK][BN + 4];
    const int tid = threadIdx.x;
    const int n0 = blockIdx.x * BN;
    const int m0 = blockIdx.y * BM;
    const int tx = tid & 15;
    const int ty = tid >> 4;

    float acc[8][MN];
    #pragma unroll
    for (int i = 0; i < 8; ++i)
        #pragma unroll
        for (int j = 0; j < MN; ++j) acc[i][j] = 0.f;

    for (int k0 = 0; k0 < K; k0 += BK) {
        #pragma unroll
        for (int it = 0; it < 4; ++it) {
            int qq = tid + 256 * it;
            int m = qq >> 3, kq = qq & 7;
            float4 v4 = *(const float4*)(A + (size_t)(m0 + m) * K + k0 + kq * 4);
            As[kq*4+0][m] = v4.x; As[kq*4+1][m] = v4.y;
            As[kq*4+2][m] = v4.z; As[kq*4+3][m] = v4.w;
        }
        #pragma unroll
        for (int it = 0; it < BN/32; ++it) {
            int qq = tid + 256 * it;
            int n = qq >> 3, kq = qq & 7;
            float4 v4 = *(const float4*)(W + (size_t)(n0 + n) * K + k0 + kq * 4);
            Ws[kq*4+0][n] = v4.x; Ws[kq*4+1][n] = v4.y;
            Ws[kq*4+2][n] = v4.z; Ws[kq*4+3][n] = v4.w;
        }
        __syncthreads();
        for (int kk = 0; kk < BK; ++kk) {
            float a[8], b[MN];
            float4 a0 = *(const float4*)&As[kk][ty*8];
            float4 a1 = *(const float4*)&As[kk][ty*8+4];
            a[0]=a0.x; a[1]=a0.y; a[2]=a0.z; a[3]=a0.w;
            a[4]=a1.x; a[5]=a1.y; a[6]=a1.z; a[7]=a1.w;
            float4 b0 = *(const float4*)&Ws[kk][tx*4];
            b[0]=b0.x; b[1]=b0.y; b[2]=b0.z; b[3]=b0.w;
            if constexpr (MN == 8) {
                float4 b1 = *(const float4*)&Ws[kk][64 + tx*4];
                b[4]=b1.x; b[5]=b1.y; b[6]=b1.z; b[7]=b1.w;
            }
            #pragma unroll
            for (int i = 0; i < 8; ++i)
                #pragma unroll
                for (int j = 0; j < MN; ++j)
                    acc[i][j] = fmaf(a[i], b[j], acc[i][j]);
        }
        __syncthreads();
    }

    #pragma unroll
    for (int i = 0; i < 8; ++i) {
        int m = m0 + ty*8 + i;
        #pragma unroll
        for (int jb = 0; jb < MN/4; ++jb) {
            int nn = n0 + jb*64 + tx*4;
            float4 r;
            r.x = acc[i][jb*4+0] + bias[nn+0];
            r.y = acc[i][jb*4+1] + bias[nn+1];
            r.z = acc[i][jb*4+2] + bias[nn+2];
            r.w = acc[i][jb*4+3] + bias[nn+3];
            if constexpr (EPI == 1) {
                const float* pp = pos + (size_t)(m & (T_SEQ-1)) * DMODEL + nn;
                r.x += pp[0]; r.y += pp[1]; r.z += pp[2]; r.w += pp[3];
            }
            *(float4*)(C + (size_t)m * N + nn) = r;
        }
    }
}

// ---------------------------------------------------------------------------
// f16-split MFMA GEMM: C = (1/1024)·A'[M,K]·W'[N,K]^T + bias
// v3: 1D grid, n-panel-fastest block order for XCD L2 panel pinning.
// Consecutive blockIdx round-robin across 8 XCDs [m09]; with
// n_idx = bid % npan and npan % 8 == 0 (o-proj 8, fc1 16, fc2 8), each
// XCD owns its n-panel(s), so the W panel (<=1MB) stays L2-resident across
// all m-blocks that reuse it. W re-read traffic (up to 268MB/dispatch)
// collapses to one L3 read per panel. QKV (npan=12): whole W = 3.1MB fits
// per-XCD L2 anyway. Dbuf + single barrier per K-step retained (R6).
// ASRC: 0 = dual-plane A; 1 = single-plane A (exact spikes; AsL elided)
// EPI:  0 = fp32; 2 = spike->fp32; 3 = spike->f16 plane (x16)
// LAYOUT: 0 = [M,N]; 2 = fused QKV (q,k f16 planes head layout; v fp32)
// ---------------------------------------------------------------------------
template<int BM, int BN, int ASRC, int EPI, int LAYOUT>
__global__ __launch_bounds__(256, (BM == 64) ? 3 : 2) void mgemm_k(
    const _Float16* __restrict__ AH, const _Float16* __restrict__ AL,
    const _Float16* __restrict__ WH, const _Float16* __restrict__ WL,
    const float* __restrict__ bias,
    float* __restrict__ O0, float* __restrict__ O1, float* __restrict__ O2,
    float* __restrict__ O3, float* __restrict__ O4,
    int M, int N, int K)
{
    constexpr int MI = BM / 32;
    constexpr int NJ = BN / 32;
    __shared__ _Float16 AsH[2][4][BM][8];
    __shared__ _Float16 AsL[(ASRC == 0) ? 2 : 1][(ASRC == 0) ? 4 : 1][(ASRC == 0) ? BM : 1][8];
    __shared__ _Float16 WsH[2][4][BN][8];
    __shared__ _Float16 WsL[2][4][BN][8];

    const int tid = threadIdx.x;
    // n-panel-fastest decomposition: bid%npan -> XCD-pinned W panel
    const int npan = N / BN;
    const int bid  = blockIdx.x;
    const int n0 = (bid % npan) * BN;
    const int m0 = (bid / npan) * BM;
    const int wv = tid >> 6, lane = tid & 63;
    const int mw = (wv >> 1) * (BM/2), nw = (wv & 1) * (BN/2);
    const int fr = lane & 15;
    const int kb = lane >> 4;

    const int wsrow = tid >> 1;          // BM/BN==128 staging row
    const int wskb  = (tid & 1) * 2;
    const int wkoff = (tid & 1) * 16;
    const int arow  = tid >> 2, akb = tid & 3;   // 64-row staging

    // register prefetch holders
    f16x8 pa0, pa1, pal0, pal1, pw0, pw1, pwl0, pwl1;

    auto gload = [&](int k0) {
        if constexpr (BM == 128) {
            const _Float16* ap = AH + (size_t)(m0 + wsrow) * K + k0 + wkoff;
            pa0 = *(const f16x8*)ap;
            pa1 = *(const f16x8*)(ap + 8);
            if constexpr (ASRC == 0) {
                const _Float16* alp = AL + (size_t)(m0 + wsrow) * K + k0 + wkoff;
                pal0 = *(const f16x8*)alp;
                pal1 = *(const f16x8*)(alp + 8);
            }
        } else {
            pa0 = *(const f16x8*)(AH + (size_t)(m0 + arow) * K + k0 + akb*8);
            if constexpr (ASRC == 0)
                pal0 = *(const f16x8*)(AL + (size_t)(m0 + arow) * K + k0 + akb*8);
        }
        if constexpr (BN == 128) {
            const _Float16* wp = WH + (size_t)(n0 + wsrow) * K + k0 + wkoff;
            pw0 = *(const f16x8*)wp;
            pw1 = *(const f16x8*)(wp + 8);
            const _Float16* wlp = WL + (size_t)(n0 + wsrow) * K + k0 + wkoff;
            pwl0 = *(const f16x8*)wlp;
            pwl1 = *(const f16x8*)(wlp + 8);
        } else {
            pw0  = *(const f16x8*)(WH + (size_t)(n0 + arow) * K + k0 + akb*8);
            pwl0 = *(const f16x8*)(WL + (size_t)(n0 + arow) * K + k0 + akb*8);
        }
    };
    auto swrite = [&](int buf) {
        if constexpr (BM == 128) {
            *(f16x8*)&AsH[buf][wskb  ][wsrow][0] = pa0;
            *(f16x8*)&AsH[buf][wskb+1][wsrow][0] = pa1;
            if constexpr (ASRC == 0) {
                *(f16x8*)&AsL[buf][wskb  ][wsrow][0] = pal0;
                *(f16x8*)&AsL[buf][wskb+1][wsrow][0] = pal1;
            }
        } else {
            *(f16x8*)&AsH[buf][akb][arow][0] = pa0;
            if constexpr (ASRC == 0)
                *(f16x8*)&AsL[buf][akb][arow][0] = pal0;
        }
        if constexpr (BN == 128) {
            *(f16x8*)&WsH[buf][wskb  ][wsrow][0] = pw0;
            *(f16x8*)&WsH[buf][wskb+1][wsrow][0] = pw1;
            *(f16x8*)&WsL[buf][wskb  ][wsrow][0] = pwl0;
            *(f16x8*)&WsL[buf][wskb+1][wsrow][0] = pwl1;
        } else {
            *(f16x8*)&WsH[buf][akb][arow][0] = pw0;
            *(f16x8*)&WsL[buf][akb][arow][0] = pwl0;
        }
    };

    f32x4 acc[MI][NJ];
    #pragma unroll
    for (int i = 0; i < MI; ++i)
        #pragma unroll
        for (int j = 0; j < NJ; ++j) acc[i][j] = (f32x4)(0.f);

    const int NT = K >> 5;
    int cur = 0;
    gload(0);
    swrite(0);
    __syncthreads();

    for (int t = 0; t < NT; ++t) {
        const bool more = (t + 1 < NT);
        if (more) gload((t + 1) << 5);   // issue next tile early (latency hides)

        f16x8 aH[MI], aL[MI], bH[NJ], bL[NJ];
        #pragma unroll
        for (int i = 0; i < MI; ++i) {
            aH[i] = *(const f16x8*)&AsH[cur][kb][mw + i*16 + fr][0];
            if constexpr (ASRC == 0) aL[i] = *(const f16x8*)&AsL[cur][kb][mw + i*16 + fr][0];
        }
        #pragma unroll
        for (int j = 0; j < NJ; ++j) {
            bH[j] = *(const f16x8*)&WsH[cur][kb][nw + j*16 + fr][0];
            bL[j] = *(const f16x8*)&WsL[cur][kb][nw + j*16 + fr][0];
        }
        #pragma unroll
        for (int i = 0; i < MI; ++i)
            #pragma unroll
            for (int j = 0; j < NJ; ++j) {
                acc[i][j] = __builtin_amdgcn_mfma_f32_16x16x32_f16(aH[i], bH[j], acc[i][j], 0, 0, 0);
                acc[i][j] = __builtin_amdgcn_mfma_f32_16x16x32_f16(aH[i], bL[j], acc[i][j], 0, 0, 0);
                if constexpr (ASRC == 0)
                    acc[i][j] = __builtin_amdgcn_mfma_f32_16x16x32_f16(aL[i], bH[j], acc[i][j], 0, 0, 0);
            }
        if (more) {
            swrite(cur ^ 1);             // write-late: after reads of buf[cur]
            __syncthreads();             // ONE barrier per K-step
            cur ^= 1;
        }
    }

    const int qq = lane >> 4;
    #pragma unroll
    for (int j = 0; j < NJ; ++j) {
        int n = n0 + nw + j*16 + fr;
        float bv = bias[n];
        #pragma unroll
        for (int i = 0; i < MI; ++i) {
            #pragma unroll
            for (int r = 0; r < 4; ++r) {
                int m = m0 + mw + i*16 + qq*4 + r;
                float val = acc[i][j][r] * (1.f/1024.f) + bv;
                if constexpr (EPI == 2) val = val > 0.5f ? 1.f : 0.f;
                if constexpr (EPI == 3) {
                    ((_Float16*)O0)[(size_t)m * N + n] = (val > 0.5f) ? (_Float16)16.f : (_Float16)0.f;
                } else if constexpr (LAYOUT == 0) {
                    O0[(size_t)m * N + n] = val;
                } else {
                    int b_ = m >> 11, t_ = m & (T_SEQ-1);
                    if (n < 512) {
                        size_t hl = (((size_t)(b_*NHEAD + (n>>6))*T_SEQ + t_) << 6) + (n & 63);
                        float s16 = 16.f * val;
                        _Float16 hh = (_Float16)s16;
                        ((_Float16*)O0)[hl] = hh;
                        ((_Float16*)O1)[hl] = (_Float16)(s16 - (float)hh);
                    } else if (n < 1024) {
                        int nn = n - 512;
                        size_t hl = (((size_t)(b_*NHEAD + (nn>>6))*T_SEQ + t_) << 6) + (nn & 63);
                        float s16 = 16.f * val;
                        _Float16 hh = (_Float16)s16;
                        ((_Float16*)O2)[hl] = hh;
                        ((_Float16*)O3)[hl] = (_Float16)(s16 - (float)hh);
                    } else {
                        int nn = n - 1024;
                        O4[(((size_t)(b_*NHEAD + (nn>>6))*T_SEQ + t_) << 6) + (nn & 63)] = val;
                    }
                }
            }
        }
    }
}

// ---------------------------------------------------------------------------
// h-split (embedding output -> x16 planes)
// ---------------------------------------------------------------------------
__global__ __launch_bounds__(256) void cvtw_k(
    const float* __restrict__ w, _Float16* __restrict__ H, _Float16* __restrict__ L,
    int n, float scale)
{
    int i = blockIdx.x * 256 + threadIdx.x;
    if (i < n) {
        float s = scale * w[i];
        _Float16 h = (_Float16)s;
        H[i] = h;
        L[i] = (_Float16)(s - (float)h);
    }
}

// all of one layer's weight conversions fused (x64 split), one launch
__global__ __launch_bounds__(256) void cvtlayer_k(
    const float* __restrict__ wq, const float* __restrict__ wk, const float* __restrict__ wv,
    const float* __restrict__ bq, const float* __restrict__ bk, const float* __restrict__ bv,
    const float* __restrict__ wo, const float* __restrict__ f1w, const float* __restrict__ f2w,
    _Float16* __restrict__ WcatH, _Float16* __restrict__ WcatL, float* __restrict__ bcat,
    _Float16* __restrict__ WoH, _Float16* __restrict__ WoL,
    _Float16* __restrict__ W1H, _Float16* __restrict__ W1L,
    _Float16* __restrict__ W2H, _Float16* __restrict__ W2L)
{
    int i = blockIdx.x * 256 + threadIdx.x;
    float w;
    _Float16 *H, *L;
    int off;
    if (i < 786432) {
        int src = i >> 18, o = i & 262143;
        w = (src == 0 ? wq : (src == 1 ? wk : wv))[o];
        H = WcatH; L = WcatL; off = i;
    } else if (i < 1048576) {
        off = i - 786432;  w = wo[off];  H = WoH; L = WoL;
    } else if (i < 2097152) {
        off = i - 1048576; w = f1w[off]; H = W1H; L = W1L;
    } else if (i < 3145728) {
        off = i - 2097152; w = f2w[off]; H = W2H; L = W2L;
    } else if (i < 3145728 + 1536) {
        int j = i - 3145728;
        int src = j >> 9, o = j & 511;
        bcat[j] = (src == 0 ? bq : (src == 1 ? bk : bv))[o];
        return;
    } else return;
    float s = 64.f * w;
    _Float16 h = (_Float16)s;
    H[off] = h;
    L[off] = (_Float16)(s - (float)h);
}

// ---------------------------------------------------------------------------
// Fused sparse attention v9 — 512 thr / 64 q-rows, 512 blocks = 2/CU exactly;
// ss[64][132] padded; sort-16 CE as explicit min/max; Q in registers;
// async K staging; __expf softmax.
// ---------------------------------------------------------------------------
__global__ __launch_bounds__(512, 4) void attn_k(
    const _Float16* __restrict__ qH, const _Float16* __restrict__ qL,
    const _Float16* __restrict__ kH, const _Float16* __restrict__ kL,
    const float* __restrict__ v,
    _Float16* __restrict__ outH, _Float16* __restrict__ outL)
{
    // ksH [128*64] @0 (16384) | ksL @16384 | ss[64][132] f32 @32768 (33792)
    // -> total 66560; wrow/irow alias ss
    __shared__ unsigned char lds[66560];
    _Float16* ksH = (_Float16*)(lds);
    _Float16* ksL = (_Float16*)(lds + 16384);
    float    (*ss)[132] = (float(*)[132])(lds + 32768);
    float*   wrow       = (float*)(lds + 32768);
    int*     irow       = (int*)(lds + 32768 + 8448);

    const int tid = threadIdx.x;
    const int bh  = blockIdx.y;
    const int t0  = blockIdx.x * 64;
    const _Float16* qHb = qH + ((size_t)bh * T_SEQ + t0) * DHEAD;
    const _Float16* qLb = qL + ((size_t)bh * T_SEQ + t0) * DHEAD;
    const _Float16* kHb = kH + (size_t)bh * T_SEQ * DHEAD;
    const _Float16* kLb = kL + (size_t)bh * T_SEQ * DHEAD;
    const float*    vb  = v  + (size_t)bh * T_SEQ * DHEAD;

    unsigned kreg[32];
    #pragma unroll
    for (int i = 0; i < 32; ++i) kreg[i] = 0u;

    const int wv = tid >> 6, lane = tid & 63;
    const int fr = lane & 15, q4 = lane >> 4;
    const int mh  = (wv >> 2) * 32;      // q-row half owned by this wave
    const int c0w = (wv & 3) * 32;       // col strip owned by this wave
    const int srow = tid >> 3;           // 0..63
    const int ssub = tid & 7;

    // Q fragments in registers: loop-invariant across all K tiles.
    // [ks][mi]: row = mh + mi*16 + fr; doff = ks*32 + q4*8
    f16x8 qaH[2][2], qaL[2][2];
    #pragma unroll
    for (int ks = 0; ks < 2; ++ks) {
        const int doff = ks*32 + q4*8;
        qaH[ks][0] = *(const f16x8*)(qHb + (mh + fr)*DHEAD + doff);
        qaH[ks][1] = *(const f16x8*)(qHb + (mh + 16 + fr)*DHEAD + doff);
        qaL[ks][0] = *(const f16x8*)(qLb + (mh + fr)*DHEAD + doff);
        qaL[ks][1] = *(const f16x8*)(qLb + (mh + 16 + fr)*DHEAD + doff);
    }

    // async stage of one K tile: 8 waves x 16 rows -> 2 instrs/plane/wave
    auto stage = [&](int jt) {
        const int j0 = jt * 128;
        #pragma unroll
        for (int i = 0; i < 2; ++i) {
            const int r0 = wv*16 + i*8;                 // wave-uniform
            const int cc = r0 + (lane >> 3);
            const int ch = (lane & 7) ^ (cc & 7);       // swizzled source chunk
            const size_t goff = (size_t)(j0 + cc) * DHEAD + ch*8;
            async16(kHb + goff, ksH + r0*64);
            async16(kLb + goff, ksL + r0*64);
        }
    };

    stage(0);
    __syncthreads();                     // ks(0) ready (drains vmcnt)

    for (int jt = 0; jt < 16; ++jt) {
        const int j0 = jt * 128;

        // QK^T: 2 m-frags x 2 n-frags x 2 k-steps x 3 split passes
        f32x4 acc[2][2];
        acc[0][0] = (f32x4)(0.f); acc[0][1] = (f32x4)(0.f);
        acc[1][0] = (f32x4)(0.f); acc[1][1] = (f32x4)(0.f);
        #pragma unroll
        for (int ks = 0; ks < 2; ++ks) {
            const int chq  = ks*4 + q4;                 // chunk index of doff
            #pragma unroll
            for (int nj = 0; nj < 2; ++nj) {
                const int cc = c0w + nj*16 + fr;
                const int sl = cc*64 + (chq ^ (cc & 7))*8;
                f16x8 bHf = *(const f16x8*)&ksH[sl];
                f16x8 bLf = *(const f16x8*)&ksL[sl];
                acc[0][nj] = __builtin_amdgcn_mfma_f32_16x16x32_f16(qaH[ks][0], bHf, acc[0][nj], 0, 0, 0);
                acc[0][nj] = __builtin_amdgcn_mfma_f32_16x16x32_f16(qaH[ks][0], bLf, acc[0][nj], 0, 0, 0);
                acc[0][nj] = __builtin_amdgcn_mfma_f32_16x16x32_f16(qaL[ks][0], bHf, acc[0][nj], 0, 0, 0);
                acc[1][nj] = __builtin_amdgcn_mfma_f32_16x16x32_f16(qaH[ks][1], bHf, acc[1][nj], 0, 0, 0);
                acc[1][nj] = __builtin_amdgcn_mfma_f32_16x16x32_f16(qaH[ks][1], bLf, acc[1][nj], 0, 0, 0);
                acc[1][nj] = __builtin_amdgcn_mfma_f32_16x16x32_f16(qaL[ks][1], bHf, acc[1][nj], 0, 0, 0);
            }
        }
        // scores to LDS (row = mh + mi*16 + q4*4 + r, col = c0w + nj*16 + fr)
        #pragma unroll
        for (int mi = 0; mi < 2; ++mi)
            #pragma unroll
            for (int nj = 0; nj < 2; ++nj)
                #pragma unroll
                for (int r = 0; r < 4; ++r)
                    ss[mh + mi*16 + q4*4 + r][c0w + nj*16 + fr] = acc[mi][nj][r] * (1.f/2048.f);
        __syncthreads();                 // C: ss visible; all ks reads done

        if (jt < 15) stage(jt + 1);      // async; hides under select

        // branch-free select: 16 candidates / thread, u32 packed keys
        float4 c4[4];
        {
            const float* ssr = &ss[srow][0] + ssub*4;
            #pragma unroll
            for (int g = 0; g < 4; ++g) c4[g] = *(const float4*)(ssr + g*32);
        }
        unsigned cand[16];
        #pragma unroll
        for (int g = 0; g < 4; ++g) {
            float vg[4] = {c4[g].x, c4[g].y, c4[g].z, c4[g].w};
            #pragma unroll
            for (int r = 0; r < 4; ++r) {
                unsigned u = __float_as_uint(vg[r]);
                u ^= (unsigned)((int)u >> 31) | 0x80000000u;
                int col = ssub*4 + g*32 + r;
                cand[g*4+r] = (u & 0xFFFFF800u) | (unsigned)(2047 - (j0 + col));
            }
        }
        // bitonic sort-16 descending; CE as explicit min/max (v_min/max_u32)
        #pragma unroll
        for (int k2 = 2; k2 <= 16; k2 <<= 1) {
            #pragma unroll
            for (int j2 = k2 >> 1; j2 > 0; j2 >>= 1) {
                #pragma unroll
                for (int i2 = 0; i2 < 16; ++i2) {
                    int l2 = i2 ^ j2;
                    if (l2 > i2) {
                        unsigned a = cand[i2], b = cand[l2];
                        unsigned mn = a < b ? a : b;
                        unsigned mx = a < b ? b : a;
                        if ((i2 & k2) == 0) { cand[i2] = mx; cand[l2] = mn; }
                        else                { cand[i2] = mn; cand[l2] = mx; }
                    }
                }
            }
        }
        #pragma unroll
        for (int j2 = 0; j2 < 16; ++j2) {
            unsigned b = cand[15 - j2];
            if (kreg[16 + j2] < b) kreg[16 + j2] = b;
        }
        #pragma unroll
        for (int st = 16; st >= 1; st >>= 1) {
            #pragma unroll
            for (int i2 = 0; i2 < 32; ++i2) {
                if ((i2 & st) == 0) {
                    unsigned lo = kreg[i2], hi = kreg[i2 | st];
                    kreg[i2]      = lo < hi ? hi : lo;
                    kreg[i2 | st] = lo < hi ? lo : hi;
                }
            }
        }
        __syncthreads();                 // A: ks(t+1) ready; ss reads done
    }

    // merge 8 per-sub lists (lane^1,2,4)
    #pragma unroll
    for (int s = 1; s <= 4; s <<= 1) {
        #pragma unroll
        for (int i = 0; i < 16; ++i) {
            unsigned pa = (unsigned)__shfl_xor((int)kreg[31-i], s, 64);
            unsigned pb = (unsigned)__shfl_xor((int)kreg[i],    s, 64);
            if (pa > kreg[i])    kreg[i]    = pa;
            if (pb > kreg[31-i]) kreg[31-i] = pb;
        }
        #pragma unroll
        for (int st = 16; st >= 1; st >>= 1) {
            #pragma unroll
            for (int i2 = 0; i2 < 32; ++i2) {
                if ((i2 & st) == 0) {
                    unsigned lo = kreg[i2], hi = kreg[i2 | st];
                    kreg[i2]      = lo < hi ? hi : lo;
                    kreg[i2 | st] = lo < hi ? lo : hi;
                }
            }
        }
    }

    // softmax over kept 32
    if (ssub == 0) {
        float w[32];
        #pragma unroll
        for (int i = 0; i < 32; ++i) {
            unsigned um = kreg[i] & 0xFFFFF800u;
            unsigned ub = (um & 0x80000000u) ? (um ^ 0x80000000u) : ~um;
            w[i] = __uint_as_float(ub);
        }
        float m = w[0];
        float s = 0.f;
        #pragma unroll
        for (int i = 0; i < 32; ++i) { w[i] = __expf(w[i] - m); s += w[i]; }
        float inv = 1.f / s;
        #pragma unroll
        for (int i = 0; i < 32; ++i) {
            wrow[srow*33 + i] = w[i] * inv;
            irow[srow*33 + i] = 2047 - (int)(kreg[i] & 0x7FFu);
        }
    }
    __syncthreads();

    // AV: wave per row-group, lane = head dim; 4 partial accumulators
    const int wid = tid >> 6, lane2 = tid & 63;
    const int b = bh >> 3, h = bh & 7;
    for (int rr = wid; rr < 64; rr += 8) {
        float a0 = 0.f, a1 = 0.f, a2 = 0.f, a3 = 0.f;
        #pragma unroll
        for (int i = 0; i < 8; ++i) {
            a0 = fmaf(wrow[rr*33 + i],      vb[(size_t)irow[rr*33 + i]      * DHEAD + lane2], a0);
            a1 = fmaf(wrow[rr*33 + 8 + i],  vb[(size_t)irow[rr*33 + 8 + i]  * DHEAD + lane2], a1);
            a2 = fmaf(wrow[rr*33 + 16 + i], vb[(size_t)irow[rr*33 + 16 + i] * DHEAD + lane2], a2);
            a3 = fmaf(wrow[rr*33 + 24 + i], vb[(size_t)irow[rr*33 + 24 + i] * DHEAD + lane2], a3);
        }
        float accv = (a0 + a1) + (a2 + a3);
        size_t oi = ((size_t)(b * T_SEQ + t0 + rr)) * DMODEL + h * DHEAD + lane2;
        float s16 = 16.f * accv;
        _Float16 hh = (_Float16)s16;
        outH[oi] = hh;
        outL[oi] = (_Float16)(s16 - (float)hh);
    }
}

// ---------------------------------------------------------------------------
// LayerNorm (+residual); also emits x16 f16 hi/lo planes of the output
// ---------------------------------------------------------------------------
__global__ __launch_bounds__(256) void ln_k(
    const float* __restrict__ x, const float* __restrict__ res,
    const float* __restrict__ g, const float* __restrict__ bb,
    float* __restrict__ out, _Float16* __restrict__ oH, _Float16* __restrict__ oL)
{
    __shared__ float red[8];
    const int row = blockIdx.x;
    const int tid = threadIdx.x;
    const float* xr = x + (size_t)row * DMODEL;
    float v0 = xr[tid], v1 = xr[tid + 256];
    if (res) {
        const float* rr = res + (size_t)row * DMODEL;
        v0 += rr[tid]; v1 += rr[tid + 256];
    }
    float s = v0 + v1;
    #pragma unroll
    for (int o = 1; o < 64; o <<= 1) s += __shfl_xor(s, o);
    const int wid = tid >> 6, lane = tid & 63;
    if (lane == 0) red[wid] = s;
    __syncthreads();
    float mean = (red[0] + red[1] + red[2] + red[3]) * (1.f / DMODEL);
    float d0 = v0 - mean, d1 = v1 - mean;
    float qs = d0*d0 + d1*d1;
    #pragma unroll
    for (int o = 1; o < 64; o <<= 1) qs += __shfl_xor(qs, o);
    if (lane == 0) red[4 + wid] = qs;
    __syncthreads();
    float var = (red[4] + red[5] + red[6] + red[7]) * (1.f / DMODEL);
    float rs = rsqrtf(var + 1e-5f);
    float o0 = d0 * rs * g[tid]       + bb[tid];
    float o1 = d1 * rs * g[tid + 256] + bb[tid + 256];
    size_t base = (size_t)row * DMODEL;
    out[base + tid]       = o0;
    out[base + tid + 256] = o1;
    float s0 = 16.f * o0, s1 = 16.f * o1;
    _Float16 h0 = (_Float16)s0, h1 = (_Float16)s1;
    oH[base + tid]       = h0;
    oH[base + tid + 256] = h1;
    oL[base + tid]       = (_Float16)(s0 - (float)h0);
    oL[base + tid + 256] = (_Float16)(s1 - (float)h1);
}

// ---------------------------------------------------------------------------
__global__ __launch_bounds__(256) void pool_k(
    const float* __restrict__ h, float* __restrict__ part)
{
    const int chunk = blockIdx.x & 15;
    const int idx = (blockIdx.x >> 4) * 256 + threadIdx.x;
    const int b = idx >> 9, d = idx & 511;
    const float* p = h + ((size_t)b * T_SEQ + chunk * 128) * DMODEL + d;
    float s = 0.f;
    for (int t = 0; t < 128; ++t) s += p[(size_t)t * DMODEL];
    part[chunk * 1024 + idx] = s;
}

__global__ __launch_bounds__(256) void poolsum_k(
    const float* __restrict__ part, float* __restrict__ pooled)
{
    int idx = blockIdx.x * 256 + threadIdx.x;
    float s = 0.f;
    #pragma unroll
    for (int c = 0; c < 16; ++c) s += part[c * 1024 + idx];
    pooled[idx] = s * (1.f / T_SEQ);
}

__global__ __launch_bounds__(256) void cls_k(
    const float* __restrict__ pooled, const float* __restrict__ w,
    const float* __restrict__ bias, float* __restrict__ out)
{
    const int wid = threadIdx.x >> 6, lane = threadIdx.x & 63;
    const int oi = blockIdx.x * 4 + wid;
    const int b = oi >> 8, o = oi & 255;
    const float* pr = pooled + b * DMODEL;
    const float* wr = w + (size_t)o * DMODEL;
    float s = 0.f;
    for (int d = lane; d < DMODEL; d += 64) s = fmaf(pr[d], wr[d], s);
    #pragma unroll
    for (int off = 1; off < 64; off <<= 1) s += __shfl_xor(s, off);
    if (lane == 0) out[oi] = s + bias[o];
}

// ---------------------------------------------------------------------------
extern "C" void kernel_launch(void* const* d_in, const int* in_sizes, int n_in,
                              void* d_out, int out_size, void* d_ws, size_t ws_size,
                              hipStream_t stream)
{
    const float* x     = (const float*)d_in[0];
    const float* emb_w = (const float*)d_in[1];
    const float* emb_b = (const float*)d_in[2];
    const float* pos   = (const float*)d_in[3];
    const float* wq    = (const float*)d_in[4];
    const float* bq    = (const float*)d_in[5];
    const float* wk    = (const float*)d_in[6];
    const float* bk    = (const float*)d_in[7];
    const float* wv    = (const float*)d_in[8];
    const float* bv    = (const float*)d_in[9];
    const float* wo    = (const float*)d_in[10];
    const float* bo    = (const float*)d_in[11];
    const float* ln1g  = (const float*)d_in[12];
    const float* ln1b  = (const float*)d_in[13];
    const float* fc1w  = (const float*)d_in[14];
    const float* fc1b  = (const float*)d_in[15];
    const float* fc2w  = (const float*)d_in[16];
    const float* fc2b  = (const float*)d_in[17];
    const float* ln2g  = (const float*)d_in[18];
    const float* ln2b  = (const float*)d_in[19];
    const float* fng   = (const float*)d_in[20];
    const float* fnb   = (const float*)d_in[21];
    const float* clsw  = (const float*)d_in[22];
    const float* clsb  = (const float*)d_in[23];

    float* ws = (float*)d_ws;
    const size_t SZ  = (size_t)MROWS * DMODEL;   // 2,097,152 floats
    const size_t HP  = SZ / 2;
    float*     h     = ws;
    float*     t1    = ws + 1*SZ;
    _Float16*  hH    = (_Float16*)(ws + 2*SZ);
    _Float16*  hL    = (_Float16*)(ws + 2*SZ + HP);
    _Float16*  aoH   = (_Float16*)(ws + 3*SZ);
    _Float16*  aoL   = (_Float16*)(ws + 3*SZ + HP);
    _Float16*  qbH   = (_Float16*)(ws + 4*SZ);
    _Float16*  qbL   = (_Float16*)(ws + 4*SZ + HP);
    _Float16*  kbH   = (_Float16*)(ws + 5*SZ);
    _Float16*  kbL   = (_Float16*)(ws + 5*SZ + HP);
    float*     vbuf  = ws + 6*SZ;
    _Float16*  WcatH = (_Float16*)(ws + 7*SZ);
    _Float16*  WcatL = (_Float16*)(ws + 7*SZ + 393216);
    _Float16*  WoH   = (_Float16*)(ws + 7*SZ + 786432);
    _Float16*  WoL   = (_Float16*)(ws + 7*SZ + 917504);
    _Float16*  W1H   = (_Float16*)(ws + 7*SZ + 1048576);
    _Float16*  W1L   = (_Float16*)(ws + 7*SZ + 1572864);
    _Float16*  W2H   = (_Float16*)(ws + 7*SZ + 2097152);
    _Float16*  W2L   = (_Float16*)(ws + 7*SZ + 2621440);
    float*     bcat  = ws + 7*SZ + 3145728;
    float*     pooled= ws + 7*SZ + 3145728 + 1536;
    float*     part  = ws + 7*SZ + 3145728 + 1536 + 1024;
    _Float16*  hid   = (_Float16*)(ws + 4*SZ);   // aliases q/k planes (dead then)
    const size_t needed = (7*SZ + 3145728 + 1536 + 1024 + 16384) * sizeof(float);
    if (ws_size < needed) return;

    dim3 blk(256);

    gemm_k<64,1><<<dim3(DMODEL/64, MROWS/128), blk, 0, stream>>>(
        x, emb_w, emb_b, pos, h, MROWS, DMODEL, 128);
    cvtw_k<<<dim3((int)(SZ/256)), blk, 0, stream>>>(h, hH, hL, (int)SZ, 16.f);

    for (int l = 0; l < NLAYER; ++l) {
        const float* wq_l = wq + (size_t)l*DMODEL*DMODEL;
        const float* bq_l = bq + (size_t)l*DMODEL;
        const float* wk_l = wk + (size_t)l*DMODEL*DMODEL;
        const float* bk_l = bk + (size_t)l*DMODEL;
        const float* wv_l = wv + (size_t)l*DMODEL*DMODEL;
        const float* bv_l = bv + (size_t)l*DMODEL;
        const float* wo_l = wo + (size_t)l*DMODEL*DMODEL;
        const float* bo_l = bo + (size_t)l*DMODEL;
        const float* f1w_l = fc1w + (size_t)l*FDIM*DMODEL;
        const float* f1b_l = fc1b + (size_t)l*FDIM;
        const float* f2w_l = fc2w + (size_t)l*DMODEL*FDIM;
        const float* f2b_l = fc2b + (size_t)l*DMODEL;

        // all weight conversions for this layer in one launch
        cvtlayer_k<<<dim3(12294), blk, 0, stream>>>(
            wq_l, wk_l, wv_l, bq_l, bk_l, bv_l, wo_l, f1w_l, f2w_l,
            WcatH, WcatL, bcat, WoH, WoL, W1H, W1L, W2H, W2L);

        // fused QKV: 1D grid 768 = 12 n-panels x 64 m-blocks (n fastest)
        mgemm_k<64,128,0,0,2><<<dim3(768), blk, 0, stream>>>(
            hH, hL, WcatH, WcatL, bcat,
            (float*)qbH, (float*)qbL, (float*)kbH, (float*)kbL, vbuf,
            MROWS, 1536, DMODEL);

        attn_k<<<dim3(T_SEQ/64, NB*NHEAD), dim3(512), 0, stream>>>(
            qbH, qbL, kbH, kbL, vbuf, aoH, aoL);

        // o-proj + spike: 512 = 8 n-panels x 64 m-blocks; panel k -> XCD k
        mgemm_k<64,64,0,2,0><<<dim3(512), blk, 0, stream>>>(
            aoH, aoL, WoH, WoL, bo_l, t1, nullptr, nullptr, nullptr, nullptr,
            MROWS, DMODEL, DMODEL);
        ln_k<<<dim3(MROWS), blk, 0, stream>>>(h, t1, ln1g + (size_t)l*DMODEL,
                                              ln1b + (size_t)l*DMODEL, h, hH, hL);

        // fc1: 512 = 16 n-panels x 32 m-blocks (2 panels/XCD);
        // fc2: 512 = 8 n-panels x 64 m-blocks (1 panel/XCD)
        mgemm_k<128,128,0,3,0><<<dim3(512), blk, 0, stream>>>(
            hH, hL, W1H, W1L, f1b_l, (float*)hid, nullptr, nullptr, nullptr, nullptr,
            MROWS, FDIM, DMODEL);
        mgemm_k<64,64,1,2,0><<<dim3(512), blk, 0, stream>>>(
            hid, nullptr, W2H, W2L, f2b_l, t1, nullptr, nullptr, nullptr, nullptr,
            MROWS, DMODEL, FDIM);
        ln_k<<<dim3(MROWS), blk, 0, stream>>>(h, t1, ln2g + (size_t)l*DMODEL,
                                              ln2b + (size_t)l*DMODEL, h, hH, hL);
    }

    ln_k<<<dim3(MROWS), blk, 0, stream>>>(h, nullptr, fng, fnb, h, hH, hL);
    pool_k<<<dim3(64), blk, 0, stream>>>(h, part);
    poolsum_k<<<dim3(4), blk, 0, stream>>>(part, pooled);
    cls_k<<<dim3(128), blk, 0, stream>>>(pooled, clsw, clsb, (float*)d_out);
}

// Round 8
// 1093.911 us; speedup vs baseline: 1.0637x; 1.0216x over previous
//
#include <hip/hip_runtime.h>
#include <math.h>
#include <float.h>

#define T_SEQ  2048
#define DMODEL 512
#define NHEAD  8
#define DHEAD  64
#define FDIM   2048
#define NLAYER 4
#define NB     2
#define MROWS  (NB*T_SEQ)   // 4096

typedef _Float16 f16x8 __attribute__((ext_vector_type(8)));
typedef float    f32x4 __attribute__((ext_vector_type(4)));

// async 16B global -> LDS (wave-uniform LDS base, lane x 16B dest)
__device__ __forceinline__ void async16(const _Float16* g, _Float16* l) {
    __builtin_amdgcn_global_load_lds(
        (const __attribute__((address_space(1))) unsigned int*)g,
        (__attribute__((address_space(3))) unsigned int*)l, 16, 0, 0);
}

// ---------------------------------------------------------------------------
// fp32 vector GEMM — embedding only (K=128)
// ---------------------------------------------------------------------------
template<int BN, int EPI>
__global__ __launch_bounds__(256) void gemm_k(
    const float* __restrict__ A, const float* __restrict__ W,
    const float* __restrict__ bias, const float* __restrict__ pos,
    float* __restrict__ C, int M, int N, int K)
{
    constexpr int BM = 128;
    constexpr int BK = 32;
    constexpr int MN = BN / 16;
    __shared__ float As[BK][BM + 4];
    __shared__ float Ws[BK][BN + 4];
    const int tid = threadIdx.x;
    const int n0 = blockIdx.x * BN;
    const int m0 = blockIdx.y * BM;
    const int tx = tid & 15;
    const int ty = tid >> 4;

    float acc[8][MN];
    #pragma unroll
    for (int i = 0; i < 8; ++i)
        #pragma unroll
        for (int j = 0; j < MN; ++j) acc[i][j] = 0.f;

    for (int k0 = 0; k0 < K; k0 += BK) {
        #pragma unroll
        for (int it = 0; it < 4; ++it) {
            int qq = tid + 256 * it;
            int m = qq >> 3, kq = qq & 7;
            float4 v4 = *(const float4*)(A + (size_t)(m0 + m) * K + k0 + kq * 4);
            As[kq*4+0][m] = v4.x; As[kq*4+1][m] = v4.y;
            As[kq*4+2][m] = v4.z; As[kq*4+3][m] = v4.w;
        }
        #pragma unroll
        for (int it = 0; it < BN/32; ++it) {
            int qq = tid + 256 * it;
            int n = qq >> 3, kq = qq & 7;
            float4 v4 = *(const float4*)(W + (size_t)(n0 + n) * K + k0 + kq * 4);
            Ws[kq*4+0][n] = v4.x; Ws[kq*4+1][n] = v4.y;
            Ws[kq*4+2][n] = v4.z; Ws[kq*4+3][n] = v4.w;
        }
        __syncthreads();
        for (int kk = 0; kk < BK; ++kk) {
            float a[8], b[MN];
            float4 a0 = *(const float4*)&As[kk][ty*8];
            float4 a1 = *(const float4*)&As[kk][ty*8+4];
            a[0]=a0.x; a[1]=a0.y; a[2]=a0.z; a[3]=a0.w;
            a[4]=a1.x; a[5]=a1.y; a[6]=a1.z; a[7]=a1.w;
            float4 b0 = *(const float4*)&Ws[kk][tx*4];
            b[0]=b0.x; b[1]=b0.y; b[2]=b0.z; b[3]=b0.w;
            if constexpr (MN == 8) {
                float4 b1 = *(const float4*)&Ws[kk][64 + tx*4];
                b[4]=b1.x; b[5]=b1.y; b[6]=b1.z; b[7]=b1.w;
            }
            #pragma unroll
            for (int i = 0; i < 8; ++i)
                #pragma unroll
                for (int j = 0; j < MN; ++j)
                    acc[i][j] = fmaf(a[i], b[j], acc[i][j]);
        }
        __syncthreads();
    }

    #pragma unroll
    for (int i = 0; i < 8; ++i) {
        int m = m0 + ty*8 + i;
        #pragma unroll
        for (int jb = 0; jb < MN/4; ++jb) {
            int nn = n0 + jb*64 + tx*4;
            float4 r;
            r.x = acc[i][jb*4+0] + bias[nn+0];
            r.y = acc[i][jb*4+1] + bias[nn+1];
            r.z = acc[i][jb*4+2] + bias[nn+2];
            r.w = acc[i][jb*4+3] + bias[nn+3];
            if constexpr (EPI == 1) {
                const float* pp = pos + (size_t)(m & (T_SEQ-1)) * DMODEL + nn;
                r.x += pp[0]; r.y += pp[1]; r.z += pp[2]; r.w += pp[3];
            }
            *(float4*)(C + (size_t)m * N + nn) = r;
        }
    }
}

// ---------------------------------------------------------------------------
// f16-split MFMA GEMM: C = (1/1024)·A'[M,K]·W'[N,K]^T + bias
// v4: W planes stored k-block-major WT[(k>>3)*N + n][8] (byte-identical to
// the LDS tile layout Ws[kb][row][8]) so W staging is pure async
// global_load_lds with CONTIGUOUS per-lane sources (m151: +35% for exactly
// this staging delta; R1's attempt failed because row-major W forced
// K-strided lane sources). No W VGPR round-trip, no W ds_writes (~half the
// staging LDS traffic). A stays reg-staged (activations remain row-major).
// Retained: dbuf + one barrier/K-step (R6), n-panel-fastest XCD pinning (R7).
// ASRC: 0 = dual-plane A; 1 = single-plane A (exact spikes; AsL elided)
// EPI:  0 = fp32; 2 = spike->fp32; 3 = spike->f16 plane (x16)
// LAYOUT: 0 = [M,N]; 2 = fused QKV (q,k f16 planes head layout; v fp32)
// ---------------------------------------------------------------------------
template<int BM, int BN, int ASRC, int EPI, int LAYOUT>
__global__ __launch_bounds__(256, (BM == 64) ? 3 : 2) void mgemm_k(
    const _Float16* __restrict__ AH, const _Float16* __restrict__ AL,
    const _Float16* __restrict__ WH, const _Float16* __restrict__ WL,
    const float* __restrict__ bias,
    float* __restrict__ O0, float* __restrict__ O1, float* __restrict__ O2,
    float* __restrict__ O3, float* __restrict__ O4,
    int M, int N, int K)
{
    constexpr int MI = BM / 32;
    constexpr int NJ = BN / 32;
    __shared__ _Float16 AsH[2][4][BM][8];
    __shared__ _Float16 AsL[(ASRC == 0) ? 2 : 1][(ASRC == 0) ? 4 : 1][(ASRC == 0) ? BM : 1][8];
    __shared__ _Float16 WsH[2][4][BN][8];
    __shared__ _Float16 WsL[2][4][BN][8];

    const int tid = threadIdx.x;
    // n-panel-fastest decomposition: bid%npan -> XCD-pinned W panel
    const int npan = N / BN;
    const int bid  = blockIdx.x;
    const int n0 = (bid % npan) * BN;
    const int m0 = (bid / npan) * BM;
    const int wv = tid >> 6, lane = tid & 63;
    const int mw = (wv >> 1) * (BM/2), nw = (wv & 1) * (BN/2);
    const int fr = lane & 15;
    const int kb = lane >> 4;

    const int wsrow = tid >> 1;          // BM==128 A staging row
    const int wskb  = (tid & 1) * 2;
    const int wkoff = (tid & 1) * 16;
    const int arow  = tid >> 2, akb = tid & 3;   // BM==64 A staging

    // A register prefetch holders
    f16x8 pa0, pa1, pal0, pal1;

    // W: wave wv stages kb-plane wv via async16, contiguous per-lane source
    auto stageW = [&](int k0, int buf) {
        const size_t base = ((size_t)((k0 >> 3) + wv) * N + n0) * 8;
        const _Float16* sH = WH + base + (size_t)lane * 8;
        const _Float16* sL = WL + base + (size_t)lane * 8;
        async16(sH, &WsH[buf][wv][0][0]);
        async16(sL, &WsL[buf][wv][0][0]);
        if constexpr (BN == 128) {
            async16(sH + 512, &WsH[buf][wv][64][0]);
            async16(sL + 512, &WsL[buf][wv][64][0]);
        }
    };
    auto gloadA = [&](int k0) {
        if constexpr (BM == 128) {
            const _Float16* ap = AH + (size_t)(m0 + wsrow) * K + k0 + wkoff;
            pa0 = *(const f16x8*)ap;
            pa1 = *(const f16x8*)(ap + 8);
            if constexpr (ASRC == 0) {
                const _Float16* alp = AL + (size_t)(m0 + wsrow) * K + k0 + wkoff;
                pal0 = *(const f16x8*)alp;
                pal1 = *(const f16x8*)(alp + 8);
            }
        } else {
            pa0 = *(const f16x8*)(AH + (size_t)(m0 + arow) * K + k0 + akb*8);
            if constexpr (ASRC == 0)
                pal0 = *(const f16x8*)(AL + (size_t)(m0 + arow) * K + k0 + akb*8);
        }
    };
    auto swriteA = [&](int buf) {
        if constexpr (BM == 128) {
            *(f16x8*)&AsH[buf][wskb  ][wsrow][0] = pa0;
            *(f16x8*)&AsH[buf][wskb+1][wsrow][0] = pa1;
            if constexpr (ASRC == 0) {
                *(f16x8*)&AsL[buf][wskb  ][wsrow][0] = pal0;
                *(f16x8*)&AsL[buf][wskb+1][wsrow][0] = pal1;
            }
        } else {
            *(f16x8*)&AsH[buf][akb][arow][0] = pa0;
            if constexpr (ASRC == 0)
                *(f16x8*)&AsL[buf][akb][arow][0] = pal0;
        }
    };

    f32x4 acc[MI][NJ];
    #pragma unroll
    for (int i = 0; i < MI; ++i)
        #pragma unroll
        for (int j = 0; j < NJ; ++j) acc[i][j] = (f32x4)(0.f);

    const int NT = K >> 5;
    int cur = 0;
    stageW(0, 0);
    gloadA(0);
    swriteA(0);
    __syncthreads();                     // drains vmcnt (W async) + lgkm (A)

    for (int t = 0; t < NT; ++t) {
        const bool more = (t + 1 < NT);
        if (more) {                      // issue next tile early; cur^1 was
            stageW((t + 1) << 5, cur ^ 1);   // fully consumed last iter
            gloadA((t + 1) << 5);
        }

        f16x8 aH[MI], aL[MI], bH[NJ], bL[NJ];
        #pragma unroll
        for (int i = 0; i < MI; ++i) {
            aH[i] = *(const f16x8*)&AsH[cur][kb][mw + i*16 + fr][0];
            if constexpr (ASRC == 0) aL[i] = *(const f16x8*)&AsL[cur][kb][mw + i*16 + fr][0];
        }
        #pragma unroll
        for (int j = 0; j < NJ; ++j) {
            bH[j] = *(const f16x8*)&WsH[cur][kb][nw + j*16 + fr][0];
            bL[j] = *(const f16x8*)&WsL[cur][kb][nw + j*16 + fr][0];
        }
        #pragma unroll
        for (int i = 0; i < MI; ++i)
            #pragma unroll
            for (int j = 0; j < NJ; ++j) {
                acc[i][j] = __builtin_amdgcn_mfma_f32_16x16x32_f16(aH[i], bH[j], acc[i][j], 0, 0, 0);
                acc[i][j] = __builtin_amdgcn_mfma_f32_16x16x32_f16(aH[i], bL[j], acc[i][j], 0, 0, 0);
                if constexpr (ASRC == 0)
                    acc[i][j] = __builtin_amdgcn_mfma_f32_16x16x32_f16(aL[i], bH[j], acc[i][j], 0, 0, 0);
            }
        if (more) {
            swriteA(cur ^ 1);            // write-late: after reads of buf[cur]
            __syncthreads();             // ONE barrier: drains async W + A
            cur ^= 1;
        }
    }

    const int qq = lane >> 4;
    #pragma unroll
    for (int j = 0; j < NJ; ++j) {
        int n = n0 + nw + j*16 + fr;
        float bv = bias[n];
        #pragma unroll
        for (int i = 0; i < MI; ++i) {
            #pragma unroll
            for (int r = 0; r < 4; ++r) {
                int m = m0 + mw + i*16 + qq*4 + r;
                float val = acc[i][j][r] * (1.f/1024.f) + bv;
                if constexpr (EPI == 2) val = val > 0.5f ? 1.f : 0.f;
                if constexpr (EPI == 3) {
                    ((_Float16*)O0)[(size_t)m * N + n] = (val > 0.5f) ? (_Float16)16.f : (_Float16)0.f;
                } else if constexpr (LAYOUT == 0) {
                    O0[(size_t)m * N + n] = val;
                } else {
                    int b_ = m >> 11, t_ = m & (T_SEQ-1);
                    if (n < 512) {
                        size_t hl = (((size_t)(b_*NHEAD + (n>>6))*T_SEQ + t_) << 6) + (n & 63);
                        float s16 = 16.f * val;
                        _Float16 hh = (_Float16)s16;
                        ((_Float16*)O0)[hl] = hh;
                        ((_Float16*)O1)[hl] = (_Float16)(s16 - (float)hh);
                    } else if (n < 1024) {
                        int nn = n - 512;
                        size_t hl = (((size_t)(b_*NHEAD + (nn>>6))*T_SEQ + t_) << 6) + (nn & 63);
                        float s16 = 16.f * val;
                        _Float16 hh = (_Float16)s16;
                        ((_Float16*)O2)[hl] = hh;
                        ((_Float16*)O3)[hl] = (_Float16)(s16 - (float)hh);
                    } else {
                        int nn = n - 1024;
                        O4[(((size_t)(b_*NHEAD + (nn>>6))*T_SEQ + t_) << 6) + (nn & 63)] = val;
                    }
                }
            }
        }
    }
}

// ---------------------------------------------------------------------------
// h-split (embedding output -> x16 planes)
// ---------------------------------------------------------------------------
__global__ __launch_bounds__(256) void cvtw_k(
    const float* __restrict__ w, _Float16* __restrict__ H, _Float16* __restrict__ L,
    int n, float scale)
{
    int i = blockIdx.x * 256 + threadIdx.x;
    if (i < n) {
        float s = scale * w[i];
        _Float16 h = (_Float16)s;
        H[i] = h;
        L[i] = (_Float16)(s - (float)h);
    }
}

// all of one layer's weight conversions fused (x64 split), one launch.
// v2: writes k-block-major planes WT[(k>>3)*N + n][8] so mgemm W staging
// can async global_load_lds with contiguous per-lane sources.
// Thread i = DEST linear index j within its region; source = row-major.
__global__ __launch_bounds__(256) void cvtlayer_k(
    const float* __restrict__ wq, const float* __restrict__ wk, const float* __restrict__ wv,
    const float* __restrict__ bq, const float* __restrict__ bk, const float* __restrict__ bv,
    const float* __restrict__ wo, const float* __restrict__ f1w, const float* __restrict__ f2w,
    _Float16* __restrict__ WcatH, _Float16* __restrict__ WcatL, float* __restrict__ bcat,
    _Float16* __restrict__ WoH, _Float16* __restrict__ WoL,
    _Float16* __restrict__ W1H, _Float16* __restrict__ W1L,
    _Float16* __restrict__ W2H, _Float16* __restrict__ W2L)
{
    int i = blockIdx.x * 256 + threadIdx.x;
    float w;
    _Float16 *H, *L;
    int off;
    if (i < 786432) {
        // Wcat: N=1536 (q|k|v rows), K=512
        int j = i;
        int kbq = j / 12288;             // N*8 = 12288
        int rem = j - kbq * 12288;
        int n = rem >> 3;
        int k = kbq * 8 + (j & 7);
        int sm = n >> 9, nn = n & 511;
        w = (sm == 0 ? wq : (sm == 1 ? wk : wv))[nn * 512 + k];
        H = WcatH; L = WcatL; off = j;
    } else if (i < 1048576) {
        // Wo: N=512, K=512 (N*8 = 4096)
        int j = i - 786432;
        int kbq = j >> 12;
        int n = (j >> 3) & 511;
        int k = (kbq << 3) | (j & 7);
        w = wo[n * 512 + k];
        H = WoH; L = WoL; off = j;
    } else if (i < 2097152) {
        // W1: N=2048, K=512 (N*8 = 16384)
        int j = i - 1048576;
        int kbq = j >> 14;
        int n = (j >> 3) & 2047;
        int k = (kbq << 3) | (j & 7);
        w = f1w[n * 512 + k];
        H = W1H; L = W1L; off = j;
    } else if (i < 3145728) {
        // W2: N=512, K=2048 (N*8 = 4096)
        int j = i - 2097152;
        int kbq = j >> 12;
        int n = (j >> 3) & 511;
        int k = (kbq << 3) | (j & 7);
        w = f2w[n * 2048 + k];
        H = W2H; L = W2L; off = j;
    } else if (i < 3145728 + 1536) {
        int j = i - 3145728;
        int src = j >> 9, o = j & 511;
        bcat[j] = (src == 0 ? bq : (src == 1 ? bk : bv))[o];
        return;
    } else return;
    float s = 64.f * w;
    _Float16 h = (_Float16)s;
    H[off] = h;
    L[off] = (_Float16)(s - (float)h);
}

// ---------------------------------------------------------------------------
// Fused sparse attention v9 — 512 thr / 64 q-rows, 512 blocks = 2/CU exactly;
// ss[64][132] padded; sort-16 CE as explicit min/max; Q in registers;
// async K staging; __expf softmax.
// ---------------------------------------------------------------------------
__global__ __launch_bounds__(512, 4) void attn_k(
    const _Float16* __restrict__ qH, const _Float16* __restrict__ qL,
    const _Float16* __restrict__ kH, const _Float16* __restrict__ kL,
    const float* __restrict__ v,
    _Float16* __restrict__ outH, _Float16* __restrict__ outL)
{
    // ksH [128*64] @0 (16384) | ksL @16384 | ss[64][132] f32 @32768 (33792)
    // -> total 66560; wrow/irow alias ss
    __shared__ unsigned char lds[66560];
    _Float16* ksH = (_Float16*)(lds);
    _Float16* ksL = (_Float16*)(lds + 16384);
    float    (*ss)[132] = (float(*)[132])(lds + 32768);
    float*   wrow       = (float*)(lds + 32768);
    int*     irow       = (int*)(lds + 32768 + 8448);

    const int tid = threadIdx.x;
    const int bh  = blockIdx.y;
    const int t0  = blockIdx.x * 64;
    const _Float16* qHb = qH + ((size_t)bh * T_SEQ + t0) * DHEAD;
    const _Float16* qLb = qL + ((size_t)bh * T_SEQ + t0) * DHEAD;
    const _Float16* kHb = kH + (size_t)bh * T_SEQ * DHEAD;
    const _Float16* kLb = kL + (size_t)bh * T_SEQ * DHEAD;
    const float*    vb  = v  + (size_t)bh * T_SEQ * DHEAD;

    unsigned kreg[32];
    #pragma unroll
    for (int i = 0; i < 32; ++i) kreg[i] = 0u;

    const int wv = tid >> 6, lane = tid & 63;
    const int fr = lane & 15, q4 = lane >> 4;
    const int mh  = (wv >> 2) * 32;      // q-row half owned by this wave
    const int c0w = (wv & 3) * 32;       // col strip owned by this wave
    const int srow = tid >> 3;           // 0..63
    const int ssub = tid & 7;

    // Q fragments in registers: loop-invariant across all K tiles.
    // [ks][mi]: row = mh + mi*16 + fr; doff = ks*32 + q4*8
    f16x8 qaH[2][2], qaL[2][2];
    #pragma unroll
    for (int ks = 0; ks < 2; ++ks) {
        const int doff = ks*32 + q4*8;
        qaH[ks][0] = *(const f16x8*)(qHb + (mh + fr)*DHEAD + doff);
        qaH[ks][1] = *(const f16x8*)(qHb + (mh + 16 + fr)*DHEAD + doff);
        qaL[ks][0] = *(const f16x8*)(qLb + (mh + fr)*DHEAD + doff);
        qaL[ks][1] = *(const f16x8*)(qLb + (mh + 16 + fr)*DHEAD + doff);
    }

    // async stage of one K tile: 8 waves x 16 rows -> 2 instrs/plane/wave
    auto stage = [&](int jt) {
        const int j0 = jt * 128;
        #pragma unroll
        for (int i = 0; i < 2; ++i) {
            const int r0 = wv*16 + i*8;                 // wave-uniform
            const int cc = r0 + (lane >> 3);
            const int ch = (lane & 7) ^ (cc & 7);       // swizzled source chunk
            const size_t goff = (size_t)(j0 + cc) * DHEAD + ch*8;
            async16(kHb + goff, ksH + r0*64);
            async16(kLb + goff, ksL + r0*64);
        }
    };

    stage(0);
    __syncthreads();                     // ks(0) ready (drains vmcnt)

    for (int jt = 0; jt < 16; ++jt) {
        const int j0 = jt * 128;

        // QK^T: 2 m-frags x 2 n-frags x 2 k-steps x 3 split passes
        f32x4 acc[2][2];
        acc[0][0] = (f32x4)(0.f); acc[0][1] = (f32x4)(0.f);
        acc[1][0] = (f32x4)(0.f); acc[1][1] = (f32x4)(0.f);
        #pragma unroll
        for (int ks = 0; ks < 2; ++ks) {
            const int chq  = ks*4 + q4;                 // chunk index of doff
            #pragma unroll
            for (int nj = 0; nj < 2; ++nj) {
                const int cc = c0w + nj*16 + fr;
                const int sl = cc*64 + (chq ^ (cc & 7))*8;
                f16x8 bHf = *(const f16x8*)&ksH[sl];
                f16x8 bLf = *(const f16x8*)&ksL[sl];
                acc[0][nj] = __builtin_amdgcn_mfma_f32_16x16x32_f16(qaH[ks][0], bHf, acc[0][nj], 0, 0, 0);
                acc[0][nj] = __builtin_amdgcn_mfma_f32_16x16x32_f16(qaH[ks][0], bLf, acc[0][nj], 0, 0, 0);
                acc[0][nj] = __builtin_amdgcn_mfma_f32_16x16x32_f16(qaL[ks][0], bHf, acc[0][nj], 0, 0, 0);
                acc[1][nj] = __builtin_amdgcn_mfma_f32_16x16x32_f16(qaH[ks][1], bHf, acc[1][nj], 0, 0, 0);
                acc[1][nj] = __builtin_amdgcn_mfma_f32_16x16x32_f16(qaH[ks][1], bLf, acc[1][nj], 0, 0, 0);
                acc[1][nj] = __builtin_amdgcn_mfma_f32_16x16x32_f16(qaL[ks][1], bHf, acc[1][nj], 0, 0, 0);
            }
        }
        // scores to LDS (row = mh + mi*16 + q4*4 + r, col = c0w + nj*16 + fr)
        #pragma unroll
        for (int mi = 0; mi < 2; ++mi)
            #pragma unroll
            for (int nj = 0; nj < 2; ++nj)
                #pragma unroll
                for (int r = 0; r < 4; ++r)
                    ss[mh + mi*16 + q4*4 + r][c0w + nj*16 + fr] = acc[mi][nj][r] * (1.f/2048.f);
        __syncthreads();                 // C: ss visible; all ks reads done

        if (jt < 15) stage(jt + 1);      // async; hides under select

        // branch-free select: 16 candidates / thread, u32 packed keys
        float4 c4[4];
        {
            const float* ssr = &ss[srow][0] + ssub*4;
            #pragma unroll
            for (int g = 0; g < 4; ++g) c4[g] = *(const float4*)(ssr + g*32);
        }
        unsigned cand[16];
        #pragma unroll
        for (int g = 0; g < 4; ++g) {
            float vg[4] = {c4[g].x, c4[g].y, c4[g].z, c4[g].w};
            #pragma unroll
            for (int r = 0; r < 4; ++r) {
                unsigned u = __float_as_uint(vg[r]);
                u ^= (unsigned)((int)u >> 31) | 0x80000000u;
                int col = ssub*4 + g*32 + r;
                cand[g*4+r] = (u & 0xFFFFF800u) | (unsigned)(2047 - (j0 + col));
            }
        }
        // bitonic sort-16 descending; CE as explicit min/max (v_min/max_u32)
        #pragma unroll
        for (int k2 = 2; k2 <= 16; k2 <<= 1) {
            #pragma unroll
            for (int j2 = k2 >> 1; j2 > 0; j2 >>= 1) {
                #pragma unroll
                for (int i2 = 0; i2 < 16; ++i2) {
                    int l2 = i2 ^ j2;
                    if (l2 > i2) {
                        unsigned a = cand[i2], b = cand[l2];
                        unsigned mn = a < b ? a : b;
                        unsigned mx = a < b ? b : a;
                        if ((i2 & k2) == 0) { cand[i2] = mx; cand[l2] = mn; }
                        else                { cand[i2] = mn; cand[l2] = mx; }
                    }
                }
            }
        }
        #pragma unroll
        for (int j2 = 0; j2 < 16; ++j2) {
            unsigned b = cand[15 - j2];
            if (kreg[16 + j2] < b) kreg[16 + j2] = b;
        }
        #pragma unroll
        for (int st = 16; st >= 1; st >>= 1) {
            #pragma unroll
            for (int i2 = 0; i2 < 32; ++i2) {
                if ((i2 & st) == 0) {
                    unsigned lo = kreg[i2], hi = kreg[i2 | st];
                    kreg[i2]      = lo < hi ? hi : lo;
                    kreg[i2 | st] = lo < hi ? lo : hi;
                }
            }
        }
        __syncthreads();                 // A: ks(t+1) ready; ss reads done
    }

    // merge 8 per-sub lists (lane^1,2,4)
    #pragma unroll
    for (int s = 1; s <= 4; s <<= 1) {
        #pragma unroll
        for (int i = 0; i < 16; ++i) {
            unsigned pa = (unsigned)__shfl_xor((int)kreg[31-i], s, 64);
            unsigned pb = (unsigned)__shfl_xor((int)kreg[i],    s, 64);
            if (pa > kreg[i])    kreg[i]    = pa;
            if (pb > kreg[31-i]) kreg[31-i] = pb;
        }
        #pragma unroll
        for (int st = 16; st >= 1; st >>= 1) {
            #pragma unroll
            for (int i2 = 0; i2 < 32; ++i2) {
                if ((i2 & st) == 0) {
                    unsigned lo = kreg[i2], hi = kreg[i2 | st];
                    kreg[i2]      = lo < hi ? hi : lo;
                    kreg[i2 | st] = lo < hi ? lo : hi;
                }
            }
        }
    }

    // softmax over kept 32
    if (ssub == 0) {
        float w[32];
        #pragma unroll
        for (int i = 0; i < 32; ++i) {
            unsigned um = kreg[i] & 0xFFFFF800u;
            unsigned ub = (um & 0x80000000u) ? (um ^ 0x80000000u) : ~um;
            w[i] = __uint_as_float(ub);
        }
        float m = w[0];
        float s = 0.f;
        #pragma unroll
        for (int i = 0; i < 32; ++i) { w[i] = __expf(w[i] - m); s += w[i]; }
        float inv = 1.f / s;
        #pragma unroll
        for (int i = 0; i < 32; ++i) {
            wrow[srow*33 + i] = w[i] * inv;
            irow[srow*33 + i] = 2047 - (int)(kreg[i] & 0x7FFu);
        }
    }
    __syncthreads();

    // AV: wave per row-group, lane = head dim; 4 partial accumulators
    const int wid = tid >> 6, lane2 = tid & 63;
    const int b = bh >> 3, h = bh & 7;
    for (int rr = wid; rr < 64; rr += 8) {
        float a0 = 0.f, a1 = 0.f, a2 = 0.f, a3 = 0.f;
        #pragma unroll
        for (int i = 0; i < 8; ++i) {
            a0 = fmaf(wrow[rr*33 + i],      vb[(size_t)irow[rr*33 + i]      * DHEAD + lane2], a0);
            a1 = fmaf(wrow[rr*33 + 8 + i],  vb[(size_t)irow[rr*33 + 8 + i]  * DHEAD + lane2], a1);
            a2 = fmaf(wrow[rr*33 + 16 + i], vb[(size_t)irow[rr*33 + 16 + i] * DHEAD + lane2], a2);
            a3 = fmaf(wrow[rr*33 + 24 + i], vb[(size_t)irow[rr*33 + 24 + i] * DHEAD + lane2], a3);
        }
        float accv = (a0 + a1) + (a2 + a3);
        size_t oi = ((size_t)(b * T_SEQ + t0 + rr)) * DMODEL + h * DHEAD + lane2;
        float s16 = 16.f * accv;
        _Float16 hh = (_Float16)s16;
        outH[oi] = hh;
        outL[oi] = (_Float16)(s16 - (float)hh);
    }
}

// ---------------------------------------------------------------------------
// LayerNorm (+residual); also emits x16 f16 hi/lo planes of the output
// ---------------------------------------------------------------------------
__global__ __launch_bounds__(256) void ln_k(
    const float* __restrict__ x, const float* __restrict__ res,
    const float* __restrict__ g, const float* __restrict__ bb,
    float* __restrict__ out, _Float16* __restrict__ oH, _Float16* __restrict__ oL)
{
    __shared__ float red[8];
    const int row = blockIdx.x;
    const int tid = threadIdx.x;
    const float* xr = x + (size_t)row * DMODEL;
    float v0 = xr[tid], v1 = xr[tid + 256];
    if (res) {
        const float* rr = res + (size_t)row * DMODEL;
        v0 += rr[tid]; v1 += rr[tid + 256];
    }
    float s = v0 + v1;
    #pragma unroll
    for (int o = 1; o < 64; o <<= 1) s += __shfl_xor(s, o);
    const int wid = tid >> 6, lane = tid & 63;
    if (lane == 0) red[wid] = s;
    __syncthreads();
    float mean = (red[0] + red[1] + red[2] + red[3]) * (1.f / DMODEL);
    float d0 = v0 - mean, d1 = v1 - mean;
    float qs = d0*d0 + d1*d1;
    #pragma unroll
    for (int o = 1; o < 64; o <<= 1) qs += __shfl_xor(qs, o);
    if (lane == 0) red[4 + wid] = qs;
    __syncthreads();
    float var = (red[4] + red[5] + red[6] + red[7]) * (1.f / DMODEL);
    float rs = rsqrtf(var + 1e-5f);
    float o0 = d0 * rs * g[tid]       + bb[tid];
    float o1 = d1 * rs * g[tid + 256] + bb[tid + 256];
    size_t base = (size_t)row * DMODEL;
    out[base + tid]       = o0;
    out[base + tid + 256] = o1;
    float s0 = 16.f * o0, s1 = 16.f * o1;
    _Float16 h0 = (_Float16)s0, h1 = (_Float16)s1;
    oH[base + tid]       = h0;
    oH[base + tid + 256] = h1;
    oL[base + tid]       = (_Float16)(s0 - (float)h0);
    oL[base + tid + 256] = (_Float16)(s1 - (float)h1);
}

// ---------------------------------------------------------------------------
__global__ __launch_bounds__(256) void pool_k(
    const float* __restrict__ h, float* __restrict__ part)
{
    const int chunk = blockIdx.x & 15;
    const int idx = (blockIdx.x >> 4) * 256 + threadIdx.x;
    const int b = idx >> 9, d = idx & 511;
    const float* p = h + ((size_t)b * T_SEQ + chunk * 128) * DMODEL + d;
    float s = 0.f;
    for (int t = 0; t < 128; ++t) s += p[(size_t)t * DMODEL];
    part[chunk * 1024 + idx] = s;
}

__global__ __launch_bounds__(256) void poolsum_k(
    const float* __restrict__ part, float* __restrict__ pooled)
{
    int idx = blockIdx.x * 256 + threadIdx.x;
    float s = 0.f;
    #pragma unroll
    for (int c = 0; c < 16; ++c) s += part[c * 1024 + idx];
    pooled[idx] = s * (1.f / T_SEQ);
}

__global__ __launch_bounds__(256) void cls_k(
    const float* __restrict__ pooled, const float* __restrict__ w,
    const float* __restrict__ bias, float* __restrict__ out)
{
    const int wid = threadIdx.x >> 6, lane = threadIdx.x & 63;
    const int oi = blockIdx.x * 4 + wid;
    const int b = oi >> 8, o = oi & 255;
    const float* pr = pooled + b * DMODEL;
    const float* wr = w + (size_t)o * DMODEL;
    float s = 0.f;
    for (int d = lane; d < DMODEL; d += 64) s = fmaf(pr[d], wr[d], s);
    #pragma unroll
    for (int off = 1; off < 64; off <<= 1) s += __shfl_xor(s, off);
    if (lane == 0) out[oi] = s + bias[o];
}

// ---------------------------------------------------------------------------
extern "C" void kernel_launch(void* const* d_in, const int* in_sizes, int n_in,
                              void* d_out, int out_size, void* d_ws, size_t ws_size,
                              hipStream_t stream)
{
    const float* x     = (const float*)d_in[0];
    const float* emb_w = (const float*)d_in[1];
    const float* emb_b = (const float*)d_in[2];
    const float* pos   = (const float*)d_in[3];
    const float* wq    = (const float*)d_in[4];
    const float* bq    = (const float*)d_in[5];
    const float* wk    = (const float*)d_in[6];
    const float* bk    = (const float*)d_in[7];
    const float* wv    = (const float*)d_in[8];
    const float* bv    = (const float*)d_in[9];
    const float* wo    = (const float*)d_in[10];
    const float* bo    = (const float*)d_in[11];
    const float* ln1g  = (const float*)d_in[12];
    const float* ln1b  = (const float*)d_in[13];
    const float* fc1w  = (const float*)d_in[14];
    const float* fc1b  = (const float*)d_in[15];
    const float* fc2w  = (const float*)d_in[16];
    const float* fc2b  = (const float*)d_in[17];
    const float* ln2g  = (const float*)d_in[18];
    const float* ln2b  = (const float*)d_in[19];
    const float* fng   = (const float*)d_in[20];
    const float* fnb   = (const float*)d_in[21];
    const float* clsw  = (const float*)d_in[22];
    const float* clsb  = (const float*)d_in[23];

    float* ws = (float*)d_ws;
    const size_t SZ  = (size_t)MROWS * DMODEL;   // 2,097,152 floats
    const size_t HP  = SZ / 2;
    float*     h     = ws;
    float*     t1    = ws + 1*SZ;
    _Float16*  hH    = (_Float16*)(ws + 2*SZ);
    _Float16*  hL    = (_Float16*)(ws + 2*SZ + HP);
    _Float16*  aoH   = (_Float16*)(ws + 3*SZ);
    _Float16*  aoL   = (_Float16*)(ws + 3*SZ + HP);
    _Float16*  qbH   = (_Float16*)(ws + 4*SZ);
    _Float16*  qbL   = (_Float16*)(ws + 4*SZ + HP);
    _Float16*  kbH   = (_Float16*)(ws + 5*SZ);
    _Float16*  kbL   = (_Float16*)(ws + 5*SZ + HP);
    float*     vbuf  = ws + 6*SZ;
    _Float16*  WcatH = (_Float16*)(ws + 7*SZ);
    _Float16*  WcatL = (_Float16*)(ws + 7*SZ + 393216);
    _Float16*  WoH   = (_Float16*)(ws + 7*SZ + 786432);
    _Float16*  WoL   = (_Float16*)(ws + 7*SZ + 917504);
    _Float16*  W1H   = (_Float16*)(ws + 7*SZ + 1048576);
    _Float16*  W1L   = (_Float16*)(ws + 7*SZ + 1572864);
    _Float16*  W2H   = (_Float16*)(ws + 7*SZ + 2097152);
    _Float16*  W2L   = (_Float16*)(ws + 7*SZ + 2621440);
    float*     bcat  = ws + 7*SZ + 3145728;
    float*     pooled= ws + 7*SZ + 3145728 + 1536;
    float*     part  = ws + 7*SZ + 3145728 + 1536 + 1024;
    _Float16*  hid   = (_Float16*)(ws + 4*SZ);   // aliases q/k planes (dead then)
    const size_t needed = (7*SZ + 3145728 + 1536 + 1024 + 16384) * sizeof(float);
    if (ws_size < needed) return;

    dim3 blk(256);

    gemm_k<64,1><<<dim3(DMODEL/64, MROWS/128), blk, 0, stream>>>(
        x, emb_w, emb_b, pos, h, MROWS, DMODEL, 128);
    cvtw_k<<<dim3((int)(SZ/256)), blk, 0, stream>>>(h, hH, hL, (int)SZ, 16.f);

    for (int l = 0; l < NLAYER; ++l) {
        const float* wq_l = wq + (size_t)l*DMODEL*DMODEL;
        const float* bq_l = bq + (size_t)l*DMODEL;
        const float* wk_l = wk + (size_t)l*DMODEL*DMODEL;
        const float* bk_l = bk + (size_t)l*DMODEL;
        const float* wv_l = wv + (size_t)l*DMODEL*DMODEL;
        const float* bv_l = bv + (size_t)l*DMODEL;
        const float* wo_l = wo + (size_t)l*DMODEL*DMODEL;
        const float* bo_l = bo + (size_t)l*DMODEL;
        const float* f1w_l = fc1w + (size_t)l*FDIM*DMODEL;
        const float* f1b_l = fc1b + (size_t)l*FDIM;
        const float* f2w_l = fc2w + (size_t)l*DMODEL*FDIM;
        const float* f2b_l = fc2b + (size_t)l*DMODEL;

        // all weight conversions for this layer in one launch (k-block-major)
        cvtlayer_k<<<dim3(12294), blk, 0, stream>>>(
            wq_l, wk_l, wv_l, bq_l, bk_l, bv_l, wo_l, f1w_l, f2w_l,
            WcatH, WcatL, bcat, WoH, WoL, W1H, W1L, W2H, W2L);

        // fused QKV: 1D grid 768 = 12 n-panels x 64 m-blocks (n fastest)
        mgemm_k<64,128,0,0,2><<<dim3(768), blk, 0, stream>>>(
            hH, hL, WcatH, WcatL, bcat,
            (float*)qbH, (float*)qbL, (float*)kbH, (float*)kbL, vbuf,
            MROWS, 1536, DMODEL);

        attn_k<<<dim3(T_SEQ/64, NB*NHEAD), dim3(512), 0, stream>>>(
            qbH, qbL, kbH, kbL, vbuf, aoH, aoL);

        // o-proj + spike: 512 = 8 n-panels x 64 m-blocks; panel k -> XCD k
        mgemm_k<64,64,0,2,0><<<dim3(512), blk, 0, stream>>>(
            aoH, aoL, WoH, WoL, bo_l, t1, nullptr, nullptr, nullptr, nullptr,
            MROWS, DMODEL, DMODEL);
        ln_k<<<dim3(MROWS), blk, 0, stream>>>(h, t1, ln1g + (size_t)l*DMODEL,
                                              ln1b + (size_t)l*DMODEL, h, hH, hL);

        // fc1: 512 = 16 n-panels x 32 m-blocks; fc2: 512 = 8 n-panels x 64
        mgemm_k<128,128,0,3,0><<<dim3(512), blk, 0, stream>>>(
            hH, hL, W1H, W1L, f1b_l, (float*)hid, nullptr, nullptr, nullptr, nullptr,
            MROWS, FDIM, DMODEL);
        mgemm_k<64,64,1,2,0><<<dim3(512), blk, 0, stream>>>(
            hid, nullptr, W2H, W2L, f2b_l, t1, nullptr, nullptr, nullptr, nullptr,
            MROWS, DMODEL, FDIM);
        ln_k<<<dim3(MROWS), blk, 0, stream>>>(h, t1, ln2g + (size_t)l*DMODEL,
                                              ln2b + (size_t)l*DMODEL, h, hH, hL);
    }

    ln_k<<<dim3(MROWS), blk, 0, stream>>>(h, nullptr, fng, fnb, h, hH, hL);
    pool_k<<<dim3(64), blk, 0, stream>>>(h, part);
    poolsum_k<<<dim3(4), blk, 0, stream>>>(part, pooled);
    cls_k<<<dim3(128), blk, 0, stream>>>(pooled, clsw, clsb, (float*)d_out);
}

// Round 9
// 1061.839 us; speedup vs baseline: 1.0958x; 1.0302x over previous
//
#include <hip/hip_runtime.h>
#include <math.h>
#include <float.h>

#define T_SEQ  2048
#define DMODEL 512
#define NHEAD  8
#define DHEAD  64
#define FDIM   2048
#define NLAYER 4
#define NB     2
#define MROWS  (NB*T_SEQ)   // 4096

typedef _Float16 f16x8 __attribute__((ext_vector_type(8)));
typedef float    f32x4 __attribute__((ext_vector_type(4)));

// async 16B global -> LDS (wave-uniform LDS base, lane x 16B dest)
__device__ __forceinline__ void async16(const _Float16* g, _Float16* l) {
    __builtin_amdgcn_global_load_lds(
        (const __attribute__((address_space(1))) unsigned int*)g,
        (__attribute__((address_space(3))) unsigned int*)l, 16, 0, 0);
}

// ---------------------------------------------------------------------------
// fp32 vector GEMM — embedding only (K=128)
// ---------------------------------------------------------------------------
template<int BN, int EPI>
__global__ __launch_bounds__(256) void gemm_k(
    const float* __restrict__ A, const float* __restrict__ W,
    const float* __restrict__ bias, const float* __restrict__ pos,
    float* __restrict__ C, int M, int N, int K)
{
    constexpr int BM = 128;
    constexpr int BK = 32;
    constexpr int MN = BN / 16;
    __shared__ float As[BK][BM + 4];
    __shared__ float Ws[BK][BN + 4];
    const int tid = threadIdx.x;
    const int n0 = blockIdx.x * BN;
    const int m0 = blockIdx.y * BM;
    const int tx = tid & 15;
    const int ty = tid >> 4;

    float acc[8][MN];
    #pragma unroll
    for (int i = 0; i < 8; ++i)
        #pragma unroll
        for (int j = 0; j < MN; ++j) acc[i][j] = 0.f;

    for (int k0 = 0; k0 < K; k0 += BK) {
        #pragma unroll
        for (int it = 0; it < 4; ++it) {
            int qq = tid + 256 * it;
            int m = qq >> 3, kq = qq & 7;
            float4 v4 = *(const float4*)(A + (size_t)(m0 + m) * K + k0 + kq * 4);
            As[kq*4+0][m] = v4.x; As[kq*4+1][m] = v4.y;
            As[kq*4+2][m] = v4.z; As[kq*4+3][m] = v4.w;
        }
        #pragma unroll
        for (int it = 0; it < BN/32; ++it) {
            int qq = tid + 256 * it;
            int n = qq >> 3, kq = qq & 7;
            float4 v4 = *(const float4*)(W + (size_t)(n0 + n) * K + k0 + kq * 4);
            Ws[kq*4+0][n] = v4.x; Ws[kq*4+1][n] = v4.y;
            Ws[kq*4+2][n] = v4.z; Ws[kq*4+3][n] = v4.w;
        }
        __syncthreads();
        for (int kk = 0; kk < BK; ++kk) {
            float a[8], b[MN];
            float4 a0 = *(const float4*)&As[kk][ty*8];
            float4 a1 = *(const float4*)&As[kk][ty*8+4];
            a[0]=a0.x; a[1]=a0.y; a[2]=a0.z; a[3]=a0.w;
            a[4]=a1.x; a[5]=a1.y; a[6]=a1.z; a[7]=a1.w;
            float4 b0 = *(const float4*)&Ws[kk][tx*4];
            b[0]=b0.x; b[1]=b0.y; b[2]=b0.z; b[3]=b0.w;
            if constexpr (MN == 8) {
                float4 b1 = *(const float4*)&Ws[kk][64 + tx*4];
                b[4]=b1.x; b[5]=b1.y; b[6]=b1.z; b[7]=b1.w;
            }
            #pragma unroll
            for (int i = 0; i < 8; ++i)
                #pragma unroll
                for (int j = 0; j < MN; ++j)
                    acc[i][j] = fmaf(a[i], b[j], acc[i][j]);
        }
        __syncthreads();
    }

    #pragma unroll
    for (int i = 0; i < 8; ++i) {
        int m = m0 + ty*8 + i;
        #pragma unroll
        for (int jb = 0; jb < MN/4; ++jb) {
            int nn = n0 + jb*64 + tx*4;
            float4 r;
            r.x = acc[i][jb*4+0] + bias[nn+0];
            r.y = acc[i][jb*4+1] + bias[nn+1];
            r.z = acc[i][jb*4+2] + bias[nn+2];
            r.w = acc[i][jb*4+3] + bias[nn+3];
            if constexpr (EPI == 1) {
                const float* pp = pos + (size_t)(m & (T_SEQ-1)) * DMODEL + nn;
                r.x += pp[0]; r.y += pp[1]; r.z += pp[2]; r.w += pp[3];
            }
            *(float4*)(C + (size_t)m * N + nn) = r;
        }
    }
}

// ---------------------------------------------------------------------------
// f16-split MFMA GEMM: C = (1/1024)·A'[M,K]·W'[N,K]^T + bias
// v5: 512-thread blocks (8 waves) on the SAME tile sizes -> grid unchanged,
// resident waves/CU double (QKV 12->24, fc1/o-proj/fc2 8->16). Every prior
// grid was quantization-locked at 2-3 blocks/CU x 4 waves = 8-12 waves/CU
// (2-3/SIMD) - too little TLP for the 3-pass staging structure.
// Wave sub-tiles: 128x128 -> 32x64 (MI2,NJ4); 64x128 -> 32x32 (MI2,NJ2);
// 64x64 -> 16x32 (MI1,NJ2). W staging: wave wv owns plane (wv>=4 ? L : H),
// k-block wv&3, via async16 (contiguous lane sources, k-block-major WT).
// A: one f16x8 per thread reg-staged. Retained: dbuf + 1 barrier/K-step,
// n-panel-fastest XCD pinning, k-block-major W (R6-R8).
// ASRC: 0 = dual-plane A; 1 = single-plane A (exact spikes; AsL elided)
// EPI:  0 = fp32; 2 = spike->fp32; 3 = spike->f16 plane (x16)
// LAYOUT: 0 = [M,N]; 2 = fused QKV (q,k f16 planes head layout; v fp32)
// MW: min waves/EU for launch_bounds (QKV: 6 -> 3 blocks/CU; others 4)
// ---------------------------------------------------------------------------
template<int BM, int BN, int ASRC, int EPI, int LAYOUT, int MW>
__global__ __launch_bounds__(512, MW) void mgemm_k(
    const _Float16* __restrict__ AH, const _Float16* __restrict__ AL,
    const _Float16* __restrict__ WH, const _Float16* __restrict__ WL,
    const float* __restrict__ bias,
    float* __restrict__ O0, float* __restrict__ O1, float* __restrict__ O2,
    float* __restrict__ O3, float* __restrict__ O4,
    int M, int N, int K)
{
    constexpr int WMv = (BM == 128) ? 4 : ((BN == 128) ? 2 : 4);
    constexpr int WNv = 8 / WMv;
    constexpr int MI  = BM / WMv / 16;
    constexpr int NJ  = BN / WNv / 16;
    __shared__ _Float16 AsH[2][4][BM][8];
    __shared__ _Float16 AsL[(ASRC == 0) ? 2 : 1][(ASRC == 0) ? 4 : 1][(ASRC == 0) ? BM : 1][8];
    __shared__ _Float16 WsH[2][4][BN][8];
    __shared__ _Float16 WsL[2][4][BN][8];

    const int tid = threadIdx.x;
    // n-panel-fastest decomposition: bid%npan -> XCD-pinned W panel
    const int npan = N / BN;
    const int bid  = blockIdx.x;
    const int n0 = (bid % npan) * BN;
    const int m0 = (bid / npan) * BM;
    const int wv = tid >> 6, lane = tid & 63;
    const int mw = (wv / WNv) * (BM / WMv);
    const int nw = (wv % WNv) * (BN / WNv);
    const int fr = lane & 15;
    const int kb = lane >> 4;

    // A register prefetch holders (one f16x8 slot per thread per plane)
    f16x8 pa0, pal0;

    // W: wave wv stages plane (wv>=4 ? L : H), k-block wv&3, via async16
    auto stageW = [&](int k0, int buf) {
        const int kb_ = wv & 3;
        const _Float16* WP = (wv >= 4) ? WL : WH;
        _Float16* db = (wv >= 4) ? &WsL[buf][kb_][0][0] : &WsH[buf][kb_][0][0];
        const size_t sb = ((size_t)((k0 >> 3) + kb_) * N + n0);
        async16(WP + (sb + lane) * 8, db);
        if constexpr (BN == 128)
            async16(WP + (sb + 64 + lane) * 8, db + 64 * 8);
    };
    auto gloadA = [&](int k0) {
        if constexpr (BM == 128) {
            const int r_ = tid >> 2, kb_ = tid & 3;
            pa0 = *(const f16x8*)(AH + (size_t)(m0 + r_) * K + k0 + kb_*8);
            if constexpr (ASRC == 0)
                pal0 = *(const f16x8*)(AL + (size_t)(m0 + r_) * K + k0 + kb_*8);
        } else {
            const int slot = tid & 255, r_ = slot >> 2, kb_ = slot & 3;
            if constexpr (ASRC == 0) {
                const _Float16* src = (tid < 256) ? AH : AL;
                pa0 = *(const f16x8*)(src + (size_t)(m0 + r_) * K + k0 + kb_*8);
            } else {
                if (tid < 256)
                    pa0 = *(const f16x8*)(AH + (size_t)(m0 + r_) * K + k0 + kb_*8);
            }
        }
    };
    auto swriteA = [&](int buf) {
        if constexpr (BM == 128) {
            *(f16x8*)&AsH[buf][tid & 3][tid >> 2][0] = pa0;
            if constexpr (ASRC == 0)
                *(f16x8*)&AsL[buf][tid & 3][tid >> 2][0] = pal0;
        } else {
            const int slot = tid & 255, r_ = slot >> 2, kb_ = slot & 3;
            if constexpr (ASRC == 0) {
                _Float16* d = (tid < 256) ? &AsH[buf][kb_][r_][0] : &AsL[buf][kb_][r_][0];
                *(f16x8*)d = pa0;
            } else {
                if (tid < 256) *(f16x8*)&AsH[buf][kb_][r_][0] = pa0;
            }
        }
    };

    f32x4 acc[MI][NJ];
    #pragma unroll
    for (int i = 0; i < MI; ++i)
        #pragma unroll
        for (int j = 0; j < NJ; ++j) acc[i][j] = (f32x4)(0.f);

    const int NT = K >> 5;
    int cur = 0;
    stageW(0, 0);
    gloadA(0);
    swriteA(0);
    __syncthreads();                     // drains vmcnt (W async) + lgkm (A)

    for (int t = 0; t < NT; ++t) {
        const bool more = (t + 1 < NT);
        if (more) {                      // issue next tile early; cur^1 was
            stageW((t + 1) << 5, cur ^ 1);   // fully consumed last iter
            gloadA((t + 1) << 5);
        }

        f16x8 aH[MI], aL[MI], bH[NJ], bL[NJ];
        #pragma unroll
        for (int i = 0; i < MI; ++i) {
            aH[i] = *(const f16x8*)&AsH[cur][kb][mw + i*16 + fr][0];
            if constexpr (ASRC == 0) aL[i] = *(const f16x8*)&AsL[cur][kb][mw + i*16 + fr][0];
        }
        #pragma unroll
        for (int j = 0; j < NJ; ++j) {
            bH[j] = *(const f16x8*)&WsH[cur][kb][nw + j*16 + fr][0];
            bL[j] = *(const f16x8*)&WsL[cur][kb][nw + j*16 + fr][0];
        }
        #pragma unroll
        for (int i = 0; i < MI; ++i)
            #pragma unroll
            for (int j = 0; j < NJ; ++j) {
                acc[i][j] = __builtin_amdgcn_mfma_f32_16x16x32_f16(aH[i], bH[j], acc[i][j], 0, 0, 0);
                acc[i][j] = __builtin_amdgcn_mfma_f32_16x16x32_f16(aH[i], bL[j], acc[i][j], 0, 0, 0);
                if constexpr (ASRC == 0)
                    acc[i][j] = __builtin_amdgcn_mfma_f32_16x16x32_f16(aL[i], bH[j], acc[i][j], 0, 0, 0);
            }
        if (more) {
            swriteA(cur ^ 1);            // write-late: after reads of buf[cur]
            __syncthreads();             // ONE barrier: drains async W + A
            cur ^= 1;
        }
    }

    const int qq = lane >> 4;
    #pragma unroll
    for (int j = 0; j < NJ; ++j) {
        int n = n0 + nw + j*16 + fr;
        float bv = bias[n];
        #pragma unroll
        for (int i = 0; i < MI; ++i) {
            #pragma unroll
            for (int r = 0; r < 4; ++r) {
                int m = m0 + mw + i*16 + qq*4 + r;
                float val = acc[i][j][r] * (1.f/1024.f) + bv;
                if constexpr (EPI == 2) val = val > 0.5f ? 1.f : 0.f;
                if constexpr (EPI == 3) {
                    ((_Float16*)O0)[(size_t)m * N + n] = (val > 0.5f) ? (_Float16)16.f : (_Float16)0.f;
                } else if constexpr (LAYOUT == 0) {
                    O0[(size_t)m * N + n] = val;
                } else {
                    int b_ = m >> 11, t_ = m & (T_SEQ-1);
                    if (n < 512) {
                        size_t hl = (((size_t)(b_*NHEAD + (n>>6))*T_SEQ + t_) << 6) + (n & 63);
                        float s16 = 16.f * val;
                        _Float16 hh = (_Float16)s16;
                        ((_Float16*)O0)[hl] = hh;
                        ((_Float16*)O1)[hl] = (_Float16)(s16 - (float)hh);
                    } else if (n < 1024) {
                        int nn = n - 512;
                        size_t hl = (((size_t)(b_*NHEAD + (nn>>6))*T_SEQ + t_) << 6) + (nn & 63);
                        float s16 = 16.f * val;
                        _Float16 hh = (_Float16)s16;
                        ((_Float16*)O2)[hl] = hh;
                        ((_Float16*)O3)[hl] = (_Float16)(s16 - (float)hh);
                    } else {
                        int nn = n - 1024;
                        O4[(((size_t)(b_*NHEAD + (nn>>6))*T_SEQ + t_) << 6) + (nn & 63)] = val;
                    }
                }
            }
        }
    }
}

// ---------------------------------------------------------------------------
// h-split (embedding output -> x16 planes)
// ---------------------------------------------------------------------------
__global__ __launch_bounds__(256) void cvtw_k(
    const float* __restrict__ w, _Float16* __restrict__ H, _Float16* __restrict__ L,
    int n, float scale)
{
    int i = blockIdx.x * 256 + threadIdx.x;
    if (i < n) {
        float s = scale * w[i];
        _Float16 h = (_Float16)s;
        H[i] = h;
        L[i] = (_Float16)(s - (float)h);
    }
}

// all of one layer's weight conversions fused (x64 split), one launch.
// v2: writes k-block-major planes WT[(k>>3)*N + n][8] so mgemm W staging
// can async global_load_lds with contiguous per-lane sources.
// Thread i = DEST linear index j within its region; source = row-major.
__global__ __launch_bounds__(256) void cvtlayer_k(
    const float* __restrict__ wq, const float* __restrict__ wk, const float* __restrict__ wv,
    const float* __restrict__ bq, const float* __restrict__ bk, const float* __restrict__ bv,
    const float* __restrict__ wo, const float* __restrict__ f1w, const float* __restrict__ f2w,
    _Float16* __restrict__ WcatH, _Float16* __restrict__ WcatL, float* __restrict__ bcat,
    _Float16* __restrict__ WoH, _Float16* __restrict__ WoL,
    _Float16* __restrict__ W1H, _Float16* __restrict__ W1L,
    _Float16* __restrict__ W2H, _Float16* __restrict__ W2L)
{
    int i = blockIdx.x * 256 + threadIdx.x;
    float w;
    _Float16 *H, *L;
    int off;
    if (i < 786432) {
        // Wcat: N=1536 (q|k|v rows), K=512
        int j = i;
        int kbq = j / 12288;             // N*8 = 12288
        int rem = j - kbq * 12288;
        int n = rem >> 3;
        int k = kbq * 8 + (j & 7);
        int sm = n >> 9, nn = n & 511;
        w = (sm == 0 ? wq : (sm == 1 ? wk : wv))[nn * 512 + k];
        H = WcatH; L = WcatL; off = j;
    } else if (i < 1048576) {
        // Wo: N=512, K=512 (N*8 = 4096)
        int j = i - 786432;
        int kbq = j >> 12;
        int n = (j >> 3) & 511;
        int k = (kbq << 3) | (j & 7);
        w = wo[n * 512 + k];
        H = WoH; L = WoL; off = j;
    } else if (i < 2097152) {
        // W1: N=2048, K=512 (N*8 = 16384)
        int j = i - 1048576;
        int kbq = j >> 14;
        int n = (j >> 3) & 2047;
        int k = (kbq << 3) | (j & 7);
        w = f1w[n * 512 + k];
        H = W1H; L = W1L; off = j;
    } else if (i < 3145728) {
        // W2: N=512, K=2048 (N*8 = 4096)
        int j = i - 2097152;
        int kbq = j >> 12;
        int n = (j >> 3) & 511;
        int k = (kbq << 3) | (j & 7);
        w = f2w[n * 2048 + k];
        H = W2H; L = W2L; off = j;
    } else if (i < 3145728 + 1536) {
        int j = i - 3145728;
        int src = j >> 9, o = j & 511;
        bcat[j] = (src == 0 ? bq : (src == 1 ? bk : bv))[o];
        return;
    } else return;
    float s = 64.f * w;
    _Float16 h = (_Float16)s;
    H[off] = h;
    L[off] = (_Float16)(s - (float)h);
}

// ---------------------------------------------------------------------------
// Fused sparse attention v9 — 512 thr / 64 q-rows, 512 blocks = 2/CU exactly;
// ss[64][132] padded; sort-16 CE as explicit min/max; Q in registers;
// async K staging; __expf softmax.
// ---------------------------------------------------------------------------
__global__ __launch_bounds__(512, 4) void attn_k(
    const _Float16* __restrict__ qH, const _Float16* __restrict__ qL,
    const _Float16* __restrict__ kH, const _Float16* __restrict__ kL,
    const float* __restrict__ v,
    _Float16* __restrict__ outH, _Float16* __restrict__ outL)
{
    // ksH [128*64] @0 (16384) | ksL @16384 | ss[64][132] f32 @32768 (33792)
    // -> total 66560; wrow/irow alias ss
    __shared__ unsigned char lds[66560];
    _Float16* ksH = (_Float16*)(lds);
    _Float16* ksL = (_Float16*)(lds + 16384);
    float    (*ss)[132] = (float(*)[132])(lds + 32768);
    float*   wrow       = (float*)(lds + 32768);
    int*     irow       = (int*)(lds + 32768 + 8448);

    const int tid = threadIdx.x;
    const int bh  = blockIdx.y;
    const int t0  = blockIdx.x * 64;
    const _Float16* qHb = qH + ((size_t)bh * T_SEQ + t0) * DHEAD;
    const _Float16* qLb = qL + ((size_t)bh * T_SEQ + t0) * DHEAD;
    const _Float16* kHb = kH + (size_t)bh * T_SEQ * DHEAD;
    const _Float16* kLb = kL + (size_t)bh * T_SEQ * DHEAD;
    const float*    vb  = v  + (size_t)bh * T_SEQ * DHEAD;

    unsigned kreg[32];
    #pragma unroll
    for (int i = 0; i < 32; ++i) kreg[i] = 0u;

    const int wv = tid >> 6, lane = tid & 63;
    const int fr = lane & 15, q4 = lane >> 4;
    const int mh  = (wv >> 2) * 32;      // q-row half owned by this wave
    const int c0w = (wv & 3) * 32;       // col strip owned by this wave
    const int srow = tid >> 3;           // 0..63
    const int ssub = tid & 7;

    // Q fragments in registers: loop-invariant across all K tiles.
    // [ks][mi]: row = mh + mi*16 + fr; doff = ks*32 + q4*8
    f16x8 qaH[2][2], qaL[2][2];
    #pragma unroll
    for (int ks = 0; ks < 2; ++ks) {
        const int doff = ks*32 + q4*8;
        qaH[ks][0] = *(const f16x8*)(qHb + (mh + fr)*DHEAD + doff);
        qaH[ks][1] = *(const f16x8*)(qHb + (mh + 16 + fr)*DHEAD + doff);
        qaL[ks][0] = *(const f16x8*)(qLb + (mh + fr)*DHEAD + doff);
        qaL[ks][1] = *(const f16x8*)(qLb + (mh + 16 + fr)*DHEAD + doff);
    }

    // async stage of one K tile: 8 waves x 16 rows -> 2 instrs/plane/wave
    auto stage = [&](int jt) {
        const int j0 = jt * 128;
        #pragma unroll
        for (int i = 0; i < 2; ++i) {
            const int r0 = wv*16 + i*8;                 // wave-uniform
            const int cc = r0 + (lane >> 3);
            const int ch = (lane & 7) ^ (cc & 7);       // swizzled source chunk
            const size_t goff = (size_t)(j0 + cc) * DHEAD + ch*8;
            async16(kHb + goff, ksH + r0*64);
            async16(kLb + goff, ksL + r0*64);
        }
    };

    stage(0);
    __syncthreads();                     // ks(0) ready (drains vmcnt)

    for (int jt = 0; jt < 16; ++jt) {
        const int j0 = jt * 128;

        // QK^T: 2 m-frags x 2 n-frags x 2 k-steps x 3 split passes
        f32x4 acc[2][2];
        acc[0][0] = (f32x4)(0.f); acc[0][1] = (f32x4)(0.f);
        acc[1][0] = (f32x4)(0.f); acc[1][1] = (f32x4)(0.f);
        #pragma unroll
        for (int ks = 0; ks < 2; ++ks) {
            const int chq  = ks*4 + q4;                 // chunk index of doff
            #pragma unroll
            for (int nj = 0; nj < 2; ++nj) {
                const int cc = c0w + nj*16 + fr;
                const int sl = cc*64 + (chq ^ (cc & 7))*8;
                f16x8 bHf = *(const f16x8*)&ksH[sl];
                f16x8 bLf = *(const f16x8*)&ksL[sl];
                acc[0][nj] = __builtin_amdgcn_mfma_f32_16x16x32_f16(qaH[ks][0], bHf, acc[0][nj], 0, 0, 0);
                acc[0][nj] = __builtin_amdgcn_mfma_f32_16x16x32_f16(qaH[ks][0], bLf, acc[0][nj], 0, 0, 0);
                acc[0][nj] = __builtin_amdgcn_mfma_f32_16x16x32_f16(qaL[ks][0], bHf, acc[0][nj], 0, 0, 0);
                acc[1][nj] = __builtin_amdgcn_mfma_f32_16x16x32_f16(qaH[ks][1], bHf, acc[1][nj], 0, 0, 0);
                acc[1][nj] = __builtin_amdgcn_mfma_f32_16x16x32_f16(qaH[ks][1], bLf, acc[1][nj], 0, 0, 0);
                acc[1][nj] = __builtin_amdgcn_mfma_f32_16x16x32_f16(qaL[ks][1], bHf, acc[1][nj], 0, 0, 0);
            }
        }
        // scores to LDS (row = mh + mi*16 + q4*4 + r, col = c0w + nj*16 + fr)
        #pragma unroll
        for (int mi = 0; mi < 2; ++mi)
            #pragma unroll
            for (int nj = 0; nj < 2; ++nj)
                #pragma unroll
                for (int r = 0; r < 4; ++r)
                    ss[mh + mi*16 + q4*4 + r][c0w + nj*16 + fr] = acc[mi][nj][r] * (1.f/2048.f);
        __syncthreads();                 // C: ss visible; all ks reads done

        if (jt < 15) stage(jt + 1);      // async; hides under select

        // branch-free select: 16 candidates / thread, u32 packed keys
        float4 c4[4];
        {
            const float* ssr = &ss[srow][0] + ssub*4;
            #pragma unroll
            for (int g = 0; g < 4; ++g) c4[g] = *(const float4*)(ssr + g*32);
        }
        unsigned cand[16];
        #pragma unroll
        for (int g = 0; g < 4; ++g) {
            float vg[4] = {c4[g].x, c4[g].y, c4[g].z, c4[g].w};
            #pragma unroll
            for (int r = 0; r < 4; ++r) {
                unsigned u = __float_as_uint(vg[r]);
                u ^= (unsigned)((int)u >> 31) | 0x80000000u;
                int col = ssub*4 + g*32 + r;
                cand[g*4+r] = (u & 0xFFFFF800u) | (unsigned)(2047 - (j0 + col));
            }
        }
        // bitonic sort-16 descending; CE as explicit min/max (v_min/max_u32)
        #pragma unroll
        for (int k2 = 2; k2 <= 16; k2 <<= 1) {
            #pragma unroll
            for (int j2 = k2 >> 1; j2 > 0; j2 >>= 1) {
                #pragma unroll
                for (int i2 = 0; i2 < 16; ++i2) {
                    int l2 = i2 ^ j2;
                    if (l2 > i2) {
                        unsigned a = cand[i2], b = cand[l2];
                        unsigned mn = a < b ? a : b;
                        unsigned mx = a < b ? b : a;
                        if ((i2 & k2) == 0) { cand[i2] = mx; cand[l2] = mn; }
                        else                { cand[i2] = mn; cand[l2] = mx; }
                    }
                }
            }
        }
        #pragma unroll
        for (int j2 = 0; j2 < 16; ++j2) {
            unsigned b = cand[15 - j2];
            if (kreg[16 + j2] < b) kreg[16 + j2] = b;
        }
        #pragma unroll
        for (int st = 16; st >= 1; st >>= 1) {
            #pragma unroll
            for (int i2 = 0; i2 < 32; ++i2) {
                if ((i2 & st) == 0) {
                    unsigned lo = kreg[i2], hi = kreg[i2 | st];
                    kreg[i2]      = lo < hi ? hi : lo;
                    kreg[i2 | st] = lo < hi ? lo : hi;
                }
            }
        }
        __syncthreads();                 // A: ks(t+1) ready; ss reads done
    }

    // merge 8 per-sub lists (lane^1,2,4)
    #pragma unroll
    for (int s = 1; s <= 4; s <<= 1) {
        #pragma unroll
        for (int i = 0; i < 16; ++i) {
            unsigned pa = (unsigned)__shfl_xor((int)kreg[31-i], s, 64);
            unsigned pb = (unsigned)__shfl_xor((int)kreg[i],    s, 64);
            if (pa > kreg[i])    kreg[i]    = pa;
            if (pb > kreg[31-i]) kreg[31-i] = pb;
        }
        #pragma unroll
        for (int st = 16; st >= 1; st >>= 1) {
            #pragma unroll
            for (int i2 = 0; i2 < 32; ++i2) {
                if ((i2 & st) == 0) {
                    unsigned lo = kreg[i2], hi = kreg[i2 | st];
                    kreg[i2]      = lo < hi ? hi : lo;
                    kreg[i2 | st] = lo < hi ? lo : hi;
                }
            }
        }
    }

    // softmax over kept 32
    if (ssub == 0) {
        float w[32];
        #pragma unroll
        for (int i = 0; i < 32; ++i) {
            unsigned um = kreg[i] & 0xFFFFF800u;
            unsigned ub = (um & 0x80000000u) ? (um ^ 0x80000000u) : ~um;
            w[i] = __uint_as_float(ub);
        }
        float m = w[0];
        float s = 0.f;
        #pragma unroll
        for (int i = 0; i < 32; ++i) { w[i] = __expf(w[i] - m); s += w[i]; }
        float inv = 1.f / s;
        #pragma unroll
        for (int i = 0; i < 32; ++i) {
            wrow[srow*33 + i] = w[i] * inv;
            irow[srow*33 + i] = 2047 - (int)(kreg[i] & 0x7FFu);
        }
    }
    __syncthreads();

    // AV: wave per row-group, lane = head dim; 4 partial accumulators
    const int wid = tid >> 6, lane2 = tid & 63;
    const int b = bh >> 3, h = bh & 7;
    for (int rr = wid; rr < 64; rr += 8) {
        float a0 = 0.f, a1 = 0.f, a2 = 0.f, a3 = 0.f;
        #pragma unroll
        for (int i = 0; i < 8; ++i) {
            a0 = fmaf(wrow[rr*33 + i],      vb[(size_t)irow[rr*33 + i]      * DHEAD + lane2], a0);
            a1 = fmaf(wrow[rr*33 + 8 + i],  vb[(size_t)irow[rr*33 + 8 + i]  * DHEAD + lane2], a1);
            a2 = fmaf(wrow[rr*33 + 16 + i], vb[(size_t)irow[rr*33 + 16 + i] * DHEAD + lane2], a2);
            a3 = fmaf(wrow[rr*33 + 24 + i], vb[(size_t)irow[rr*33 + 24 + i] * DHEAD + lane2], a3);
        }
        float accv = (a0 + a1) + (a2 + a3);
        size_t oi = ((size_t)(b * T_SEQ + t0 + rr)) * DMODEL + h * DHEAD + lane2;
        float s16 = 16.f * accv;
        _Float16 hh = (_Float16)s16;
        outH[oi] = hh;
        outL[oi] = (_Float16)(s16 - (float)hh);
    }
}

// ---------------------------------------------------------------------------
// LayerNorm (+residual); also emits x16 f16 hi/lo planes of the output
// ---------------------------------------------------------------------------
__global__ __launch_bounds__(256) void ln_k(
    const float* __restrict__ x, const float* __restrict__ res,
    const float* __restrict__ g, const float* __restrict__ bb,
    float* __restrict__ out, _Float16* __restrict__ oH, _Float16* __restrict__ oL)
{
    __shared__ float red[8];
    const int row = blockIdx.x;
    const int tid = threadIdx.x;
    const float* xr = x + (size_t)row * DMODEL;
    float v0 = xr[tid], v1 = xr[tid + 256];
    if (res) {
        const float* rr = res + (size_t)row * DMODEL;
        v0 += rr[tid]; v1 += rr[tid + 256];
    }
    float s = v0 + v1;
    #pragma unroll
    for (int o = 1; o < 64; o <<= 1) s += __shfl_xor(s, o);
    const int wid = tid >> 6, lane = tid & 63;
    if (lane == 0) red[wid] = s;
    __syncthreads();
    float mean = (red[0] + red[1] + red[2] + red[3]) * (1.f / DMODEL);
    float d0 = v0 - mean, d1 = v1 - mean;
    float qs = d0*d0 + d1*d1;
    #pragma unroll
    for (int o = 1; o < 64; o <<= 1) qs += __shfl_xor(qs, o);
    if (lane == 0) red[4 + wid] = qs;
    __syncthreads();
    float var = (red[4] + red[5] + red[6] + red[7]) * (1.f / DMODEL);
    float rs = rsqrtf(var + 1e-5f);
    float o0 = d0 * rs * g[tid]       + bb[tid];
    float o1 = d1 * rs * g[tid + 256] + bb[tid + 256];
    size_t base = (size_t)row * DMODEL;
    out[base + tid]       = o0;
    out[base + tid + 256] = o1;
    float s0 = 16.f * o0, s1 = 16.f * o1;
    _Float16 h0 = (_Float16)s0, h1 = (_Float16)s1;
    oH[base + tid]       = h0;
    oH[base + tid + 256] = h1;
    oL[base + tid]       = (_Float16)(s0 - (float)h0);
    oL[base + tid + 256] = (_Float16)(s1 - (float)h1);
}

// ---------------------------------------------------------------------------
__global__ __launch_bounds__(256) void pool_k(
    const float* __restrict__ h, float* __restrict__ part)
{
    const int chunk = blockIdx.x & 15;
    const int idx = (blockIdx.x >> 4) * 256 + threadIdx.x;
    const int b = idx >> 9, d = idx & 511;
    const float* p = h + ((size_t)b * T_SEQ + chunk * 128) * DMODEL + d;
    float s = 0.f;
    for (int t = 0; t < 128; ++t) s += p[(size_t)t * DMODEL];
    part[chunk * 1024 + idx] = s;
}

__global__ __launch_bounds__(256) void poolsum_k(
    const float* __restrict__ part, float* __restrict__ pooled)
{
    int idx = blockIdx.x * 256 + threadIdx.x;
    float s = 0.f;
    #pragma unroll
    for (int c = 0; c < 16; ++c) s += part[c * 1024 + idx];
    pooled[idx] = s * (1.f / T_SEQ);
}

__global__ __launch_bounds__(256) void cls_k(
    const float* __restrict__ pooled, const float* __restrict__ w,
    const float* __restrict__ bias, float* __restrict__ out)
{
    const int wid = threadIdx.x >> 6, lane = threadIdx.x & 63;
    const int oi = blockIdx.x * 4 + wid;
    const int b = oi >> 8, o = oi & 255;
    const float* pr = pooled + b * DMODEL;
    const float* wr = w + (size_t)o * DMODEL;
    float s = 0.f;
    for (int d = lane; d < DMODEL; d += 64) s = fmaf(pr[d], wr[d], s);
    #pragma unroll
    for (int off = 1; off < 64; off <<= 1) s += __shfl_xor(s, off);
    if (lane == 0) out[oi] = s + bias[o];
}

// ---------------------------------------------------------------------------
extern "C" void kernel_launch(void* const* d_in, const int* in_sizes, int n_in,
                              void* d_out, int out_size, void* d_ws, size_t ws_size,
                              hipStream_t stream)
{
    const float* x     = (const float*)d_in[0];
    const float* emb_w = (const float*)d_in[1];
    const float* emb_b = (const float*)d_in[2];
    const float* pos   = (const float*)d_in[3];
    const float* wq    = (const float*)d_in[4];
    const float* bq    = (const float*)d_in[5];
    const float* wk    = (const float*)d_in[6];
    const float* bk    = (const float*)d_in[7];
    const float* wv    = (const float*)d_in[8];
    const float* bv    = (const float*)d_in[9];
    const float* wo    = (const float*)d_in[10];
    const float* bo    = (const float*)d_in[11];
    const float* ln1g  = (const float*)d_in[12];
    const float* ln1b  = (const float*)d_in[13];
    const float* fc1w  = (const float*)d_in[14];
    const float* fc1b  = (const float*)d_in[15];
    const float* fc2w  = (const float*)d_in[16];
    const float* fc2b  = (const float*)d_in[17];
    const float* ln2g  = (const float*)d_in[18];
    const float* ln2b  = (const float*)d_in[19];
    const float* fng   = (const float*)d_in[20];
    const float* fnb   = (const float*)d_in[21];
    const float* clsw  = (const float*)d_in[22];
    const float* clsb  = (const float*)d_in[23];

    float* ws = (float*)d_ws;
    const size_t SZ  = (size_t)MROWS * DMODEL;   // 2,097,152 floats
    const size_t HP  = SZ / 2;
    float*     h     = ws;
    float*     t1    = ws + 1*SZ;
    _Float16*  hH    = (_Float16*)(ws + 2*SZ);
    _Float16*  hL    = (_Float16*)(ws + 2*SZ + HP);
    _Float16*  aoH   = (_Float16*)(ws + 3*SZ);
    _Float16*  aoL   = (_Float16*)(ws + 3*SZ + HP);
    _Float16*  qbH   = (_Float16*)(ws + 4*SZ);
    _Float16*  qbL   = (_Float16*)(ws + 4*SZ + HP);
    _Float16*  kbH   = (_Float16*)(ws + 5*SZ);
    _Float16*  kbL   = (_Float16*)(ws + 5*SZ + HP);
    float*     vbuf  = ws + 6*SZ;
    _Float16*  WcatH = (_Float16*)(ws + 7*SZ);
    _Float16*  WcatL = (_Float16*)(ws + 7*SZ + 393216);
    _Float16*  WoH   = (_Float16*)(ws + 7*SZ + 786432);
    _Float16*  WoL   = (_Float16*)(ws + 7*SZ + 917504);
    _Float16*  W1H   = (_Float16*)(ws + 7*SZ + 1048576);
    _Float16*  W1L   = (_Float16*)(ws + 7*SZ + 1572864);
    _Float16*  W2H   = (_Float16*)(ws + 7*SZ + 2097152);
    _Float16*  W2L   = (_Float16*)(ws + 7*SZ + 2621440);
    float*     bcat  = ws + 7*SZ + 3145728;
    float*     pooled= ws + 7*SZ + 3145728 + 1536;
    float*     part  = ws + 7*SZ + 3145728 + 1536 + 1024;
    _Float16*  hid   = (_Float16*)(ws + 4*SZ);   // aliases q/k planes (dead then)
    const size_t needed = (7*SZ + 3145728 + 1536 + 1024 + 16384) * sizeof(float);
    if (ws_size < needed) return;

    dim3 blk(256);

    gemm_k<64,1><<<dim3(DMODEL/64, MROWS/128), blk, 0, stream>>>(
        x, emb_w, emb_b, pos, h, MROWS, DMODEL, 128);
    cvtw_k<<<dim3((int)(SZ/256)), blk, 0, stream>>>(h, hH, hL, (int)SZ, 16.f);

    for (int l = 0; l < NLAYER; ++l) {
        const float* wq_l = wq + (size_t)l*DMODEL*DMODEL;
        const float* bq_l = bq + (size_t)l*DMODEL;
        const float* wk_l = wk + (size_t)l*DMODEL*DMODEL;
        const float* bk_l = bk + (size_t)l*DMODEL;
        const float* wv_l = wv + (size_t)l*DMODEL*DMODEL;
        const float* bv_l = bv + (size_t)l*DMODEL;
        const float* wo_l = wo + (size_t)l*DMODEL*DMODEL;
        const float* bo_l = bo + (size_t)l*DMODEL;
        const float* f1w_l = fc1w + (size_t)l*FDIM*DMODEL;
        const float* f1b_l = fc1b + (size_t)l*FDIM;
        const float* f2w_l = fc2w + (size_t)l*DMODEL*FDIM;
        const float* f2b_l = fc2b + (size_t)l*DMODEL;

        // all weight conversions for this layer in one launch (k-block-major)
        cvtlayer_k<<<dim3(12294), blk, 0, stream>>>(
            wq_l, wk_l, wv_l, bq_l, bk_l, bv_l, wo_l, f1w_l, f2w_l,
            WcatH, WcatL, bcat, WoH, WoL, W1H, W1L, W2H, W2L);

        // fused QKV: 768 blocks x 512 thr = 3 blocks/CU x 8 waves = 24 w/CU
        mgemm_k<64,128,0,0,2,6><<<dim3(768), dim3(512), 0, stream>>>(
            hH, hL, WcatH, WcatL, bcat,
            (float*)qbH, (float*)qbL, (float*)kbH, (float*)kbL, vbuf,
            MROWS, 1536, DMODEL);

        attn_k<<<dim3(T_SEQ/64, NB*NHEAD), dim3(512), 0, stream>>>(
            qbH, qbL, kbH, kbL, vbuf, aoH, aoL);

        // o-proj + spike: 512 blocks x 512 thr = 2/CU x 8 waves = 16 w/CU
        mgemm_k<64,64,0,2,0,4><<<dim3(512), dim3(512), 0, stream>>>(
            aoH, aoL, WoH, WoL, bo_l, t1, nullptr, nullptr, nullptr, nullptr,
            MROWS, DMODEL, DMODEL);
        ln_k<<<dim3(MROWS), blk, 0, stream>>>(h, t1, ln1g + (size_t)l*DMODEL,
                                              ln1b + (size_t)l*DMODEL, h, hH, hL);

        // fc1: 512 blocks x 512 thr (LDS 64KB -> 2/CU = 16 w/CU);
        // fc2: 512 blocks x 512 thr = 16 w/CU
        mgemm_k<128,128,0,3,0,4><<<dim3(512), dim3(512), 0, stream>>>(
            hH, hL, W1H, W1L, f1b_l, (float*)hid, nullptr, nullptr, nullptr, nullptr,
            MROWS, FDIM, DMODEL);
        mgemm_k<64,64,1,2,0,4><<<dim3(512), dim3(512), 0, stream>>>(
            hid, nullptr, W2H, W2L, f2b_l, t1, nullptr, nullptr, nullptr, nullptr,
            MROWS, DMODEL, FDIM);
        ln_k<<<dim3(MROWS), blk, 0, stream>>>(h, t1, ln2g + (size_t)l*DMODEL,
                                              ln2b + (size_t)l*DMODEL, h, hH, hL);
    }

    ln_k<<<dim3(MROWS), blk, 0, stream>>>(h, nullptr, fng, fnb, h, hH, hL);
    pool_k<<<dim3(64), blk, 0, stream>>>(h, part);
    poolsum_k<<<dim3(4), blk, 0, stream>>>(part, pooled);
    cls_k<<<dim3(128), blk, 0, stream>>>(pooled, clsw, clsb, (float*)d_out);
}